// Round 1
// baseline (489.167 us; speedup 1.0000x reference)
//
#include <hip/hip_runtime.h>
#include <hip/hip_bf16.h>
#include <stdint.h>

// ---------------------------------------------------------------------------
// MultiHeadSelfAttention fused block, MI355X/gfx950, bf16 MFMA pipeline.
// B=4 S=2048 E=1024 H=16 D=64.
// Pipeline: cast -> QK gemm (z=0/1) -> Vt gemm (swapped operands) ->
//           flash attention -> WO gemm (+bias+residual, f32) -> in-place LN.
// ---------------------------------------------------------------------------

typedef short bf16x8_t __attribute__((ext_vector_type(8)));
typedef float f32x4_t __attribute__((ext_vector_type(4)));
typedef unsigned short u16x8_t __attribute__((ext_vector_type(8)));

#define DEV static __device__ __forceinline__

DEV unsigned short f2bf(float f) {  // RNE f32->bf16
  union { float f; uint32_t u; } v; v.f = f;
  uint32_t u = v.u;
  return (unsigned short)((u + 0x7fffu + ((u >> 16) & 1u)) >> 16);
}

typedef const __attribute__((address_space(1))) void* gp_t;
typedef __attribute__((address_space(3))) void* lp_t;

DEV void gld16(const void* g, void* l) {  // async global->LDS, 16B/lane
  __builtin_amdgcn_global_load_lds((gp_t)g, (lp_t)l, 16, 0, 0);
}

// ---------------------------------------------------------------------------
__global__ __launch_bounds__(256) void cast_all(
    const float* __restrict__ x,
    const float* __restrict__ wq, const float* __restrict__ wk,
    const float* __restrict__ wv, const float* __restrict__ wo,
    unsigned short* __restrict__ xb,
    unsigned short* __restrict__ wqb, unsigned short* __restrict__ wkb,
    unsigned short* __restrict__ wvb, unsigned short* __restrict__ wob)
{
  const float* src; unsigned short* dst; int n;
  switch (blockIdx.y) {
    case 0:  src = x;  dst = xb;  n = 8192 * 1024; break;
    case 1:  src = wq; dst = wqb; n = 1024 * 1024; break;
    case 2:  src = wk; dst = wkb; n = 1024 * 1024; break;
    case 3:  src = wv; dst = wvb; n = 1024 * 1024; break;
    default: src = wo; dst = wob; n = 1024 * 1024; break;
  }
  int i = (int)(blockIdx.x * 256 + threadIdx.x) * 8;
  if (i >= n) return;
  float4 a = *(const float4*)(src + i);
  float4 b = *(const float4*)(src + i + 4);
  u16x8_t o;
  o[0] = f2bf(a.x); o[1] = f2bf(a.y); o[2] = f2bf(a.z); o[3] = f2bf(a.w);
  o[4] = f2bf(b.x); o[5] = f2bf(b.y); o[6] = f2bf(b.z); o[7] = f2bf(b.w);
  *(u16x8_t*)(dst + i) = o;
}

// ---------------------------------------------------------------------------
// C[m,n] = sum_k A[m,k]*B[n,k]  (both row-major, K contiguous). 128x128 tile,
// BK=32, 4 waves, 16x16x32 bf16 MFMA, global_load_lds width-16 staging.
// MODE 0: QK proj (z picks WQ/WK; Q scaled by 1/8), out bf16 [B,H,S,D]
// MODE 2: Vt (A=Wv rows e, B=X rows (b,s)), out bf16 [B,H,D,S], bias by m(=e)
// MODE 3: WO + bias + residual, out f32 [M,N]
template<int MODE>
__global__ __launch_bounds__(256) void gemm_bt(
    const unsigned short* __restrict__ A,
    const unsigned short* __restrict__ B0, const unsigned short* __restrict__ B1,
    const float* __restrict__ bias0, const float* __restrict__ bias1,
    const float* __restrict__ resid,
    unsigned short* __restrict__ o0, unsigned short* __restrict__ o1,
    float* __restrict__ of,
    int M, int N, int K)
{
  __shared__ unsigned short As[128 * 32];
  __shared__ unsigned short Bs[128 * 32];

  const int z = blockIdx.z;
  const unsigned short* Bw = (MODE == 0 && z == 1) ? B1 : B0;
  const float* bias = (MODE == 0 && z == 1) ? bias1 : bias0;
  unsigned short* obf = (MODE == 0 && z == 1) ? o1 : o0;

  const int tid = threadIdx.x;
  const int lane = tid & 63;
  const int lr = lane & 15, lq = lane >> 4;
  const int wid = tid >> 6;
  const int m0 = blockIdx.x * 128;
  const int n0 = blockIdx.y * 128;
  const int wr = (wid >> 1) * 64, wc = (wid & 1) * 64;

  f32x4_t acc[4][4] = {};

  const int o = tid * 16;
  for (int kt = 0; kt < K; kt += 32) {
#pragma unroll
    for (int r = 0; r < 2; ++r) {
      int oo = o + r * 4096;
      int row = oo >> 6, cb = oo & 63;
      gld16((const char*)(A  + (size_t)(m0 + row) * K + kt) + cb, (char*)As + oo);
      gld16((const char*)(Bw + (size_t)(n0 + row) * K + kt) + cb, (char*)Bs + oo);
    }
    __syncthreads();
    bf16x8_t aF[4], bF[4];
    const int koff = lq * 16;
#pragma unroll
    for (int i = 0; i < 4; ++i) {
      aF[i] = *(const bf16x8_t*)((const char*)As + (wr + i * 16 + lr) * 64 + koff);
      bF[i] = *(const bf16x8_t*)((const char*)Bs + (wc + i * 16 + lr) * 64 + koff);
    }
#pragma unroll
    for (int i = 0; i < 4; ++i)
#pragma unroll
      for (int j = 0; j < 4; ++j)
        acc[i][j] = __builtin_amdgcn_mfma_f32_16x16x32_bf16(aF[i], bF[j], acc[i][j], 0, 0, 0);
    __syncthreads();
  }

  // C layout: col = lane&15, row = (lane>>4)*4 + reg  [m89/m91 verified]
#pragma unroll
  for (int i = 0; i < 4; ++i) {
#pragma unroll
    for (int j = 0; j < 4; ++j) {
      int n = n0 + wc + j * 16 + lr;
#pragma unroll
      for (int r = 0; r < 4; ++r) {
        int m = m0 + wr + i * 16 + lq * 4 + r;
        float v = acc[i][j][r];
        if (MODE == 0) {
          v = (v + bias[n]) * (z == 0 ? 0.125f : 1.0f);  // fold 1/sqrt(64) into Q
          int b = m >> 11, s = m & 2047, h = n >> 6, d = n & 63;
          obf[(size_t)((b * 16 + h) * 2048 + s) * 64 + d] = f2bf(v);
        } else if (MODE == 2) {
          v = v + bias[m];  // bias indexed by output feature e = m
          int b = n >> 11, s = n & 2047;
          obf[(size_t)(b * 1024 + m) * 2048 + s] = f2bf(v);
        } else {
          v = v + bias[n] + resid[(size_t)m * 1024 + n];
          of[(size_t)m * 1024 + n] = v;
        }
      }
    }
  }
}

// ---------------------------------------------------------------------------
// Flash attention. Grid 1024 (= 64 bh * 16 q-tiles), 256 threads (4 waves).
// QBLK=128 (wave owns 32 q rows = 2 groups of 16), KBLK=64, D=64.
// K tile [64][64] and Vt tile [64 d][64 k] staged with XOR swizzle
// (linear LDS dest + inverse-swizzled global source + swizzled read).
__global__ __launch_bounds__(256) void attn_kernel(
    const unsigned short* __restrict__ Qg, const unsigned short* __restrict__ Kg,
    const unsigned short* __restrict__ Vtg, const float* __restrict__ maskg,
    unsigned short* __restrict__ ctx)
{
  __shared__ unsigned short Ks[64 * 64];
  __shared__ unsigned short Vs[64 * 64];
  __shared__ unsigned short Ps[4][16][80];  // per-wave P round-trip, padded rows

  const int id = blockIdx.x;
  const int swz = (id & 7) * 128 + (id >> 3);  // bijective XCD-chunked swizzle
  const int bh = swz >> 4;
  const int qt = swz & 15;
  const int b = bh >> 4, h = bh & 15;

  const int tid = threadIdx.x, lane = tid & 63, wid = tid >> 6;
  const int lr = lane & 15, lq = lane >> 4;
  const int q0 = qt * 128 + wid * 32;
  const size_t head = (size_t)bh * (2048 * 64);
  const float* maskp = maskg + (size_t)b * 2048;

  // hoist Q fragments (A-layout: row = lane&15, k = (lane>>4)*8+j)
  bf16x8_t qA[2][2];
#pragma unroll
  for (int qh = 0; qh < 2; ++qh) {
    const unsigned short* qp = Qg + head + (size_t)(q0 + qh * 16 + lr) * 64 + lq * 8;
    qA[qh][0] = *(const bf16x8_t*)qp;
    qA[qh][1] = *(const bf16x8_t*)(qp + 32);
  }

  float m_run[2][4], l_run[2][4];
  f32x4_t oacc[2][4] = {};
#pragma unroll
  for (int qh = 0; qh < 2; ++qh)
#pragma unroll
    for (int r = 0; r < 4; ++r) { m_run[qh][r] = -3e38f; l_run[qh][r] = 0.f; }

  for (int k0 = 0; k0 < 2048; k0 += 64) {
    __syncthreads();
#pragma unroll
    for (int r = 0; r < 2; ++r) {
      int oo = tid * 16 + r * 4096;
      int row = oo >> 7, cb = oo & 127;
      int scb = cb ^ ((row & 7) << 4);  // inverse swizzle on global source
      gld16((const char*)(Kg + head + (size_t)(k0 + row) * 64) + scb, (char*)Ks + oo);
      gld16((const char*)(Vtg + (size_t)(bh * 64 + row) * 2048 + k0) + scb, (char*)Vs + oo);
    }
    __syncthreads();

    // hoisted K/V B-fragments (col = lane&15, k = (lane>>4)*8+j), swizzled read
    bf16x8_t kB[4][2], vB[4][2];
#pragma unroll
    for (int t = 0; t < 4; ++t) {
      int row = t * 16 + lr;
      const char* bp = (const char*)Ks + row * 128;
      int sw = (row & 7) << 4;
      kB[t][0] = *(const bf16x8_t*)(bp + ((lq * 16) ^ sw));
      kB[t][1] = *(const bf16x8_t*)(bp + ((64 + lq * 16) ^ sw));
    }
#pragma unroll
    for (int t = 0; t < 4; ++t) {
      int row = t * 16 + lr;
      const char* bp = (const char*)Vs + row * 128;
      int sw = (row & 7) << 4;
      vB[t][0] = *(const bf16x8_t*)(bp + ((lq * 16) ^ sw));
      vB[t][1] = *(const bf16x8_t*)(bp + ((64 + lq * 16) ^ sw));
    }
    float mv[4];
#pragma unroll
    for (int t = 0; t < 4; ++t) mv[t] = maskp[k0 + t * 16 + lr];

#pragma unroll
    for (int qh = 0; qh < 2; ++qh) {
      f32x4_t sc[4];
#pragma unroll
      for (int t = 0; t < 4; ++t) {
        f32x4_t zz = {};
        zz = __builtin_amdgcn_mfma_f32_16x16x32_bf16(qA[qh][0], kB[t][0], zz, 0, 0, 0);
        zz = __builtin_amdgcn_mfma_f32_16x16x32_bf16(qA[qh][1], kB[t][1], zz, 0, 0, 0);
        sc[t] = zz;
      }
      float alpha[4];
#pragma unroll
      for (int r = 0; r < 4; ++r) {
        float mx = -3e38f;
#pragma unroll
        for (int t = 0; t < 4; ++t) { sc[t][r] += mv[t]; mx = fmaxf(mx, sc[t][r]); }
        mx = fmaxf(mx, __shfl_xor(mx, 1));
        mx = fmaxf(mx, __shfl_xor(mx, 2));
        mx = fmaxf(mx, __shfl_xor(mx, 4));
        mx = fmaxf(mx, __shfl_xor(mx, 8));
        float mn = fmaxf(m_run[qh][r], mx);
        alpha[r] = exp2f((m_run[qh][r] - mn) * 1.44269504f);
        m_run[qh][r] = mn;
        float s = 0.f;
#pragma unroll
        for (int t = 0; t < 4; ++t) {
          float e = exp2f((sc[t][r] - mn) * 1.44269504f);
          s += e;
          Ps[wid][lq * 4 + r][t * 16 + lr] = f2bf(e);
        }
        s += __shfl_xor(s, 1); s += __shfl_xor(s, 2);
        s += __shfl_xor(s, 4); s += __shfl_xor(s, 8);
        l_run[qh][r] = l_run[qh][r] * alpha[r] + s;
      }
#pragma unroll
      for (int dt = 0; dt < 4; ++dt)
#pragma unroll
        for (int r = 0; r < 4; ++r)
          oacc[qh][dt][r] *= alpha[r];
      bf16x8_t pA0 = *(const bf16x8_t*)&Ps[wid][lr][lq * 8];
      bf16x8_t pA1 = *(const bf16x8_t*)&Ps[wid][lr][32 + lq * 8];
#pragma unroll
      for (int dt = 0; dt < 4; ++dt) {
        oacc[qh][dt] = __builtin_amdgcn_mfma_f32_16x16x32_bf16(pA0, vB[dt][0], oacc[qh][dt], 0, 0, 0);
        oacc[qh][dt] = __builtin_amdgcn_mfma_f32_16x16x32_bf16(pA1, vB[dt][1], oacc[qh][dt], 0, 0, 0);
      }
    }
  }

#pragma unroll
  for (int qh = 0; qh < 2; ++qh)
#pragma unroll
    for (int dt = 0; dt < 4; ++dt)
#pragma unroll
      for (int r = 0; r < 4; ++r) {
        int q = q0 + qh * 16 + lq * 4 + r;
        float v = oacc[qh][dt][r] / l_run[qh][r];
        ctx[(size_t)(b * 2048 + q) * 1024 + h * 64 + dt * 16 + lr] = f2bf(v);
      }
}

// ---------------------------------------------------------------------------
__global__ __launch_bounds__(256) void ln_kernel(
    float* __restrict__ y, const float* __restrict__ g, const float* __restrict__ be)
{
  const int row = blockIdx.x, tid = threadIdx.x;
  float* rp = y + (size_t)row * 1024;
  float4 x = *(const float4*)(rp + tid * 4);
  float s = x.x + x.y + x.z + x.w;
  float sq = x.x * x.x + x.y * x.y + x.z * x.z + x.w * x.w;
#pragma unroll
  for (int msk = 1; msk < 64; msk <<= 1) {
    s  += __shfl_xor(s, msk);
    sq += __shfl_xor(sq, msk);
  }
  __shared__ float red[8];
  const int wid = tid >> 6, lane = tid & 63;
  if (lane == 0) { red[wid] = s; red[4 + wid] = sq; }
  __syncthreads();
  s  = red[0] + red[1] + red[2] + red[3];
  sq = red[4] + red[5] + red[6] + red[7];
  float mu = s * (1.f / 1024.f);
  float var = sq * (1.f / 1024.f) - mu * mu;
  float rs = rsqrtf(var + 1e-12f);
  float4 gw = *(const float4*)(g + tid * 4);
  float4 bw = *(const float4*)(be + tid * 4);
  float4 o2;
  o2.x = (x.x - mu) * rs * gw.x + bw.x;
  o2.y = (x.y - mu) * rs * gw.y + bw.y;
  o2.z = (x.z - mu) * rs * gw.z + bw.z;
  o2.w = (x.w - mu) * rs * gw.w + bw.w;
  *(float4*)(rp + tid * 4) = o2;
}

// ---------------------------------------------------------------------------
extern "C" void kernel_launch(void* const* d_in, const int* in_sizes, int n_in,
                              void* d_out, int out_size, void* d_ws, size_t ws_size,
                              hipStream_t stream)
{
  const float* x    = (const float*)d_in[0];
  const float* mask = (const float*)d_in[1];
  const float* wq   = (const float*)d_in[2];
  const float* bq   = (const float*)d_in[3];
  const float* wk   = (const float*)d_in[4];
  const float* bk   = (const float*)d_in[5];
  const float* wv   = (const float*)d_in[6];
  const float* bv   = (const float*)d_in[7];
  const float* wo   = (const float*)d_in[8];
  const float* bo   = (const float*)d_in[9];
  const float* lnw  = (const float*)d_in[10];
  const float* lnb  = (const float*)d_in[11];
  float* out = (float*)d_out;

  char* ws = (char*)d_ws;
  // ws layout (total 92.3 MB)
  unsigned short* Xb  = (unsigned short*)(ws);                               // 16 MB
  unsigned short* Wqb = (unsigned short*)(ws + 16777216);                    // 2 MB
  unsigned short* Wkb = (unsigned short*)(ws + 16777216 + 2097152);
  unsigned short* Wvb = (unsigned short*)(ws + 16777216 + 2 * 2097152);
  unsigned short* Wob = (unsigned short*)(ws + 16777216 + 3 * 2097152);
  unsigned short* Qg  = (unsigned short*)(ws + 25165824);                    // [B,H,S,D]
  unsigned short* Kg  = (unsigned short*)(ws + 25165824 + 16777216);         // [B,H,S,D]
  unsigned short* Vtg = (unsigned short*)(ws + 25165824 + 2 * 16777216);     // [B,H,D,S]
  unsigned short* CTX = (unsigned short*)(ws + 25165824 + 3 * 16777216);     // [B,S,E]

  cast_all<<<dim3(4096, 5), 256, 0, stream>>>(x, wq, wk, wv, wo, Xb, Wqb, Wkb, Wvb, Wob);
  gemm_bt<0><<<dim3(64, 8, 2), 256, 0, stream>>>(Xb, Wqb, Wkb, bq, bk, nullptr,
                                                 Qg, Kg, nullptr, 8192, 1024, 1024);
  gemm_bt<2><<<dim3(8, 64, 1), 256, 0, stream>>>(Wvb, Xb, nullptr, bv, nullptr, nullptr,
                                                 Vtg, nullptr, nullptr, 1024, 8192, 1024);
  attn_kernel<<<dim3(1024), 256, 0, stream>>>(Qg, Kg, Vtg, mask, CTX);
  gemm_bt<3><<<dim3(64, 8, 1), 256, 0, stream>>>(CTX, Wob, nullptr, bo, nullptr, x,
                                                 nullptr, nullptr, out, 8192, 1024, 1024);
  ln_kernel<<<dim3(8192), 256, 0, stream>>>(out, lnw, lnb);
}

// Round 2
// 292.371 us; speedup vs baseline: 1.6731x; 1.6731x over previous
//
#include <hip/hip_runtime.h>
#include <hip/hip_bf16.h>
#include <stdint.h>

// ---------------------------------------------------------------------------
// MultiHeadSelfAttention fused block, MI355X/gfx950, bf16 MFMA pipeline.
// B=4 S=2048 E=1024 H=16 D=64.
// R1: attention rewritten to swapped-QK^T 32x32 MFMA structure (in-register
// softmax + in-register P via cvt_pk + shfl_xor(32), O^T epilogue transpose).
// ---------------------------------------------------------------------------

typedef short bf16x8_t __attribute__((ext_vector_type(8)));
typedef float f32x4_t __attribute__((ext_vector_type(4)));
typedef float f32x16_t __attribute__((ext_vector_type(16)));
typedef unsigned short u16x8_t __attribute__((ext_vector_type(8)));
typedef uint32_t u32x4_t __attribute__((ext_vector_type(4)));

#define DEV static __device__ __forceinline__

DEV unsigned short f2bf(float f) {  // RNE f32->bf16
  union { float f; uint32_t u; } v; v.f = f;
  uint32_t u = v.u;
  return (unsigned short)((u + 0x7fffu + ((u >> 16) & 1u)) >> 16);
}

DEV uint32_t cvtpk(float a, float b) {  // packed {lo=a, hi=b} bf16, RNE
  uint32_t d;
  asm("v_cvt_pk_bf16_f32 %0, %1, %2" : "=v"(d) : "v"(a), "v"(b));
  return d;
}

typedef const __attribute__((address_space(1))) void* gp_t;
typedef __attribute__((address_space(3))) void* lp_t;

DEV void gld16(const void* g, void* l) {  // async global->LDS, 16B/lane
  __builtin_amdgcn_global_load_lds((gp_t)g, (lp_t)l, 16, 0, 0);
}

// ---------------------------------------------------------------------------
__global__ __launch_bounds__(256) void cast_all(
    const float* __restrict__ x,
    const float* __restrict__ wq, const float* __restrict__ wk,
    const float* __restrict__ wv, const float* __restrict__ wo,
    const float* __restrict__ mask,
    unsigned short* __restrict__ xb,
    unsigned short* __restrict__ wqb, unsigned short* __restrict__ wkb,
    unsigned short* __restrict__ wvb, unsigned short* __restrict__ wob,
    float* __restrict__ msf)
{
  if (blockIdx.y == 5) {  // mask * log2e -> f32
    int i = (int)(blockIdx.x * 256 + threadIdx.x) * 8;
    if (i >= 4 * 2048) return;
    float4 a = *(const float4*)(mask + i);
    float4 b = *(const float4*)(mask + i + 4);
    const float C = 1.44269504f;
    a.x *= C; a.y *= C; a.z *= C; a.w *= C;
    b.x *= C; b.y *= C; b.z *= C; b.w *= C;
    *(float4*)(msf + i) = a;
    *(float4*)(msf + i + 4) = b;
    return;
  }
  const float* src; unsigned short* dst; int n;
  switch (blockIdx.y) {
    case 0:  src = x;  dst = xb;  n = 8192 * 1024; break;
    case 1:  src = wq; dst = wqb; n = 1024 * 1024; break;
    case 2:  src = wk; dst = wkb; n = 1024 * 1024; break;
    case 3:  src = wv; dst = wvb; n = 1024 * 1024; break;
    default: src = wo; dst = wob; n = 1024 * 1024; break;
  }
  int i = (int)(blockIdx.x * 256 + threadIdx.x) * 8;
  if (i >= n) return;
  float4 a = *(const float4*)(src + i);
  float4 b = *(const float4*)(src + i + 4);
  u16x8_t o;
  o[0] = f2bf(a.x); o[1] = f2bf(a.y); o[2] = f2bf(a.z); o[3] = f2bf(a.w);
  o[4] = f2bf(b.x); o[5] = f2bf(b.y); o[6] = f2bf(b.z); o[7] = f2bf(b.w);
  *(u16x8_t*)(dst + i) = o;
}

// ---------------------------------------------------------------------------
// C[m,n] = sum_k A[m,k]*B[n,k]. 128x128 tile, BK=32, 4 waves, 16x16x32 MFMA.
// MODE 0: QK proj (z picks WQ/WK; Q scaled 1/8), out bf16 [B,H,S,D]
// MODE 2: Vt (A=Wv rows e, B=X rows (b,s)), out bf16 [B,H,D,S], bias by m(=e)
// MODE 3: WO + bias + residual, out f32 [M,N]
template<int MODE>
__global__ __launch_bounds__(256) void gemm_bt(
    const unsigned short* __restrict__ A,
    const unsigned short* __restrict__ B0, const unsigned short* __restrict__ B1,
    const float* __restrict__ bias0, const float* __restrict__ bias1,
    const float* __restrict__ resid,
    unsigned short* __restrict__ o0, unsigned short* __restrict__ o1,
    float* __restrict__ of,
    int M, int N, int K)
{
  __shared__ unsigned short As[128 * 32];
  __shared__ unsigned short Bs[128 * 32];

  const int z = blockIdx.z;
  const unsigned short* Bw = (MODE == 0 && z == 1) ? B1 : B0;
  const float* bias = (MODE == 0 && z == 1) ? bias1 : bias0;
  unsigned short* obf = (MODE == 0 && z == 1) ? o1 : o0;

  const int tid = threadIdx.x;
  const int lane = tid & 63;
  const int lr = lane & 15, lq = lane >> 4;
  const int wid = tid >> 6;
  const int m0 = blockIdx.x * 128;
  const int n0 = blockIdx.y * 128;
  const int wr = (wid >> 1) * 64, wc = (wid & 1) * 64;

  f32x4_t acc[4][4] = {};

  const int o = tid * 16;
  for (int kt = 0; kt < K; kt += 32) {
#pragma unroll
    for (int r = 0; r < 2; ++r) {
      int oo = o + r * 4096;
      int row = oo >> 6, cb = oo & 63;
      gld16((const char*)(A  + (size_t)(m0 + row) * K + kt) + cb, (char*)As + oo);
      gld16((const char*)(Bw + (size_t)(n0 + row) * K + kt) + cb, (char*)Bs + oo);
    }
    __syncthreads();
    bf16x8_t aF[4], bF[4];
    const int koff = lq * 16;
#pragma unroll
    for (int i = 0; i < 4; ++i) {
      aF[i] = *(const bf16x8_t*)((const char*)As + (wr + i * 16 + lr) * 64 + koff);
      bF[i] = *(const bf16x8_t*)((const char*)Bs + (wc + i * 16 + lr) * 64 + koff);
    }
#pragma unroll
    for (int i = 0; i < 4; ++i)
#pragma unroll
      for (int j = 0; j < 4; ++j)
        acc[i][j] = __builtin_amdgcn_mfma_f32_16x16x32_bf16(aF[i], bF[j], acc[i][j], 0, 0, 0);
    __syncthreads();
  }

#pragma unroll
  for (int i = 0; i < 4; ++i) {
#pragma unroll
    for (int j = 0; j < 4; ++j) {
      int n = n0 + wc + j * 16 + lr;
#pragma unroll
      for (int r = 0; r < 4; ++r) {
        int m = m0 + wr + i * 16 + lq * 4 + r;
        float v = acc[i][j][r];
        if (MODE == 0) {
          v = (v + bias[n]) * (z == 0 ? 0.125f : 1.0f);
          int b = m >> 11, s = m & 2047, h = n >> 6, d = n & 63;
          obf[(size_t)((b * 16 + h) * 2048 + s) * 64 + d] = f2bf(v);
        } else if (MODE == 2) {
          v = v + bias[m];
          int b = n >> 11, s = n & 2047;
          obf[(size_t)(b * 1024 + m) * 2048 + s] = f2bf(v);
        } else {
          v = v + bias[n] + resid[(size_t)m * 1024 + n];
          of[(size_t)m * 1024 + n] = v;
        }
      }
    }
  }
}

// ---------------------------------------------------------------------------
// Flash attention, swapped-QK^T 32x32 structure.
// Grid 1024 (= 64 bh * 16 q-tiles), 256 threads (4 waves), wave owns 32 q.
// S^T = mfma(K, Q): lane holds P[k-column] for q = lane&31 -> in-lane softmax.
// PV: O^T = Vt * P^T with P fragments assembled in-register (cvt_pk + shfl32).
// K/Vt staged double-buffered with XOR swizzle; O^T transposed via LDS.
__global__ __launch_bounds__(256) void attn_kernel(
    const unsigned short* __restrict__ Qg, const unsigned short* __restrict__ Kg,
    const unsigned short* __restrict__ Vtg, const float* __restrict__ msC,
    unsigned short* __restrict__ ctx)
{
  // smem layout: Ks[2][8192] | Vs[2][8192] | Ms[2][256B]; transpose reuses 0..16K
  __shared__ __align__(16) char smem[33280];

  const int id = blockIdx.x;
  const int swz = (id & 7) * 128 + (id >> 3);  // bijective XCD swizzle
  const int bh = swz >> 4, qt = swz & 15;
  const int b = bh >> 4, h = bh & 15;

  const int tid = threadIdx.x, lane = tid & 63, wid = tid >> 6;
  const int l31 = lane & 31, hi = lane >> 5;
  const int q0 = qt * 128 + wid * 32;
  const size_t head = (size_t)bh * (2048 * 64);
  const unsigned short* Kh = Kg + head;
  const unsigned short* Vh = Vtg + (size_t)bh * 64 * 2048;
  const float* msb = msC + (size_t)b * 2048;

  // Q B-fragments: col q = q0+l31, d = ds*16 + 8*hi + j   (held whole loop)
  bf16x8_t qf[4];
  {
    const unsigned short* qp = Qg + head + (size_t)(q0 + l31) * 64 + 8 * hi;
#pragma unroll
    for (int ds = 0; ds < 4; ++ds) qf[ds] = *(const bf16x8_t*)(qp + ds * 16);
  }

  f32x16_t oacc0 = {}, oacc1 = {};   // O^T[d,q]: dgrp 0 (d 0-31), 1 (d 32-63)
  float m_run = -3e38f, l_run = 0.f;

  const int sw_row = (l31 & 7) << 4;

  // stage tile t into buffer p
  auto STAGE = [&](int t, int p) {
    const int k0 = t * 64;
    char* kd = smem + p * 8192;
    char* vd = smem + 16384 + p * 8192;
#pragma unroll
    for (int r = 0; r < 2; ++r) {
      int oo = tid * 16 + r * 4096;
      int row = oo >> 7, cb = oo & 127;
      int scb = cb ^ ((row & 7) << 4);  // inverse swizzle on global source
      gld16((const char*)(Kh + (size_t)(k0 + row) * 64) + scb, kd + oo);
      gld16((const char*)(Vh + (size_t)row * 2048 + k0) + scb, vd + oo);
    }
    if (tid < 16)
      gld16((const char*)(msb + k0 + tid * 4), smem + 32768 + p * 256 + tid * 16);
  };

  STAGE(0, 0);
  __syncthreads();

  for (int t = 0; t < 32; ++t) {
    const int p = t & 1;
    if (t < 31) STAGE(t + 1, p ^ 1);

    const char* kb = smem + p * 8192;
    const char* vb = smem + 16384 + p * 8192;
    const float* msp = (const float*)(smem + 32768 + p * 256);

    // ---- S^T = K . Q^T : c0 = k-rows 0-31, c1 = k-rows 32-63
    f32x16_t c0 = {}, c1 = {};
    {
      const char* kr0 = kb + l31 * 128;
      const char* kr1 = kb + (32 + l31) * 128;
#pragma unroll
      for (int ds = 0; ds < 4; ++ds) {
        int cc = (ds * 32 + 16 * hi) ^ sw_row;
        bf16x8_t k0f = *(const bf16x8_t*)(kr0 + cc);
        bf16x8_t k1f = *(const bf16x8_t*)(kr1 + cc);
        c0 = __builtin_amdgcn_mfma_f32_32x32x16_bf16(k0f, qf[ds], c0, 0, 0, 0);
        c1 = __builtin_amdgcn_mfma_f32_32x32x16_bf16(k1f, qf[ds], c1, 0, 0, 0);
      }
    }

    // ---- in-lane softmax (log2 domain), mask folded: t = S*log2e + maskC[k]
    float tv[32];
    float mx = -3e38f;
#pragma unroll
    for (int g = 0; g < 8; ++g) {
      float4 mg = *(const float4*)(msp + 8 * g + 4 * hi);  // broadcast read
#pragma unroll
      for (int i = 0; i < 4; ++i) {
        float s = (g < 4) ? c0[4 * g + i] : c1[4 * (g - 4) + i];
        float t2 = fmaf(s, 1.44269504f, (&mg.x)[i]);
        tv[4 * g + i] = t2;
        mx = fmaxf(mx, t2);
      }
    }
    mx = fmaxf(mx, __shfl_xor(mx, 32));
    // defer-max (T13): skip rescale when growth small (8 nats = 11.54 log2)
    if (!__all(mx <= m_run + 11.5416f)) {
      float mnew = fmaxf(m_run, mx);
      float alpha = exp2f(m_run - mnew);
      m_run = mnew;
      l_run *= alpha;
#pragma unroll
      for (int i = 0; i < 16; ++i) { oacc0[i] *= alpha; oacc1[i] *= alpha; }
    }
    float sum = 0.f;
#pragma unroll
    for (int i = 0; i < 32; ++i) { tv[i] = exp2f(tv[i] - m_run); sum += tv[i]; }
    sum += __shfl_xor(sum, 32);
    l_run += sum;

    // ---- pack P to bf16 + partner exchange (T12): frags for PV B-operand
    uint32_t w0[8], w1[8], pw0[8], pw1[8];
#pragma unroll
    for (int g = 0; g < 8; ++g) {
      w0[g] = cvtpk(tv[4 * g], tv[4 * g + 1]);
      w1[g] = cvtpk(tv[4 * g + 2], tv[4 * g + 3]);
      pw0[g] = (uint32_t)__shfl_xor((int)w0[g], 32);
      pw1[g] = (uint32_t)__shfl_xor((int)w1[g], 32);
    }
    bf16x8_t pf[4];
#pragma unroll
    for (int ks = 0; ks < 4; ++ks) {
      const int gg = ((ks >> 1) << 2) + ((ks & 1) << 1);
      union { uint32_t u[4]; bf16x8_t v; } cv;
      cv.u[0] = hi ? pw0[gg + 1] : w0[gg];
      cv.u[1] = hi ? pw1[gg + 1] : w1[gg];
      cv.u[2] = hi ? w0[gg + 1]  : pw0[gg];
      cv.u[3] = hi ? w1[gg + 1]  : pw1[gg];
      pf[ks] = cv.v;
    }

    // ---- PV: O^T += Vt . P^T
    {
      const char* vr0 = vb + l31 * 128;
      const char* vr1 = vb + (32 + l31) * 128;
#pragma unroll
      for (int ks = 0; ks < 4; ++ks) {
        int cc = (ks * 32 + 16 * hi) ^ sw_row;
        bf16x8_t v0f = *(const bf16x8_t*)(vr0 + cc);
        bf16x8_t v1f = *(const bf16x8_t*)(vr1 + cc);
        oacc0 = __builtin_amdgcn_mfma_f32_32x32x16_bf16(v0f, pf[ks], oacc0, 0, 0, 0);
        oacc1 = __builtin_amdgcn_mfma_f32_32x32x16_bf16(v1f, pf[ks], oacc1, 0, 0, 0);
      }
    }
    __syncthreads();
  }

  // ---- epilogue: O^T -> LDS (swizzled) -> coalesced global store
  const float inv = 1.0f / l_run;
  char* tb = smem + wid * 4096;  // per-wave 32q x 128B, reuses K buffers
#pragma unroll
  for (int g2 = 0; g2 < 4; ++g2) {
    uint2 a0, a1;
    a0.x = cvtpk(oacc0[4 * g2] * inv, oacc0[4 * g2 + 1] * inv);
    a0.y = cvtpk(oacc0[4 * g2 + 2] * inv, oacc0[4 * g2 + 3] * inv);
    a1.x = cvtpk(oacc1[4 * g2] * inv, oacc1[4 * g2 + 1] * inv);
    a1.y = cvtpk(oacc1[4 * g2 + 2] * inv, oacc1[4 * g2 + 3] * inv);
    const int swq = (l31 & 7) << 4;
    int d0 = 16 * g2 + 8 * hi;            // byte col of d-base (d = d0/2)
    *(uint2*)(tb + l31 * 128 + ((d0) ^ swq)) = a0;
    *(uint2*)(tb + l31 * 128 + ((d0 + 64) ^ swq)) = a1;
  }
  // wave-local RAW -> lgkmcnt handled by compiler; no barrier needed
  {
    const int qq = lane >> 1, cp = lane & 1;
    const char* trow = tb + qq * 128;
    const int swr = (qq & 7) << 4;
    unsigned short* op = ctx + ((size_t)(b * 2048 + q0 + qq)) * 1024 + h * 64 + cp * 32;
#pragma unroll
    for (int i = 0; i < 4; ++i) {
      int col = cp * 64 + i * 16;
      u32x4_t val = *(const u32x4_t*)(trow + (col ^ swr));
      *(u32x4_t*)(op + i * 8) = val;
    }
  }
}

// ---------------------------------------------------------------------------
__global__ __launch_bounds__(256) void ln_kernel(
    float* __restrict__ y, const float* __restrict__ g, const float* __restrict__ be)
{
  const int row = blockIdx.x, tid = threadIdx.x;
  float* rp = y + (size_t)row * 1024;
  float4 x = *(const float4*)(rp + tid * 4);
  float s = x.x + x.y + x.z + x.w;
  float sq = x.x * x.x + x.y * x.y + x.z * x.z + x.w * x.w;
#pragma unroll
  for (int msk = 1; msk < 64; msk <<= 1) {
    s  += __shfl_xor(s, msk);
    sq += __shfl_xor(sq, msk);
  }
  __shared__ float red[8];
  const int wid = tid >> 6, lane = tid & 63;
  if (lane == 0) { red[wid] = s; red[4 + wid] = sq; }
  __syncthreads();
  s  = red[0] + red[1] + red[2] + red[3];
  sq = red[4] + red[5] + red[6] + red[7];
  float mu = s * (1.f / 1024.f);
  float var = sq * (1.f / 1024.f) - mu * mu;
  float rs = rsqrtf(var + 1e-12f);
  float4 gw = *(const float4*)(g + tid * 4);
  float4 bw = *(const float4*)(be + tid * 4);
  float4 o2;
  o2.x = (x.x - mu) * rs * gw.x + bw.x;
  o2.y = (x.y - mu) * rs * gw.y + bw.y;
  o2.z = (x.z - mu) * rs * gw.z + bw.z;
  o2.w = (x.w - mu) * rs * gw.w + bw.w;
  *(float4*)(rp + tid * 4) = o2;
}

// ---------------------------------------------------------------------------
extern "C" void kernel_launch(void* const* d_in, const int* in_sizes, int n_in,
                              void* d_out, int out_size, void* d_ws, size_t ws_size,
                              hipStream_t stream)
{
  const float* x    = (const float*)d_in[0];
  const float* mask = (const float*)d_in[1];
  const float* wq   = (const float*)d_in[2];
  const float* bq   = (const float*)d_in[3];
  const float* wk   = (const float*)d_in[4];
  const float* bk   = (const float*)d_in[5];
  const float* wv   = (const float*)d_in[6];
  const float* bv   = (const float*)d_in[7];
  const float* wo   = (const float*)d_in[8];
  const float* bo   = (const float*)d_in[9];
  const float* lnw  = (const float*)d_in[10];
  const float* lnb  = (const float*)d_in[11];
  float* out = (float*)d_out;

  char* ws = (char*)d_ws;
  unsigned short* Xb  = (unsigned short*)(ws);                               // 16 MB
  unsigned short* Wqb = (unsigned short*)(ws + 16777216);                    // 2 MB
  unsigned short* Wkb = (unsigned short*)(ws + 16777216 + 2097152);
  unsigned short* Wvb = (unsigned short*)(ws + 16777216 + 2 * 2097152);
  unsigned short* Wob = (unsigned short*)(ws + 16777216 + 3 * 2097152);
  unsigned short* Qg  = (unsigned short*)(ws + 25165824);                    // [B,H,S,D]
  unsigned short* Kg  = (unsigned short*)(ws + 25165824 + 16777216);         // [B,H,S,D]
  unsigned short* Vtg = (unsigned short*)(ws + 25165824 + 2 * 16777216);     // [B,H,D,S]
  unsigned short* CTX = (unsigned short*)(ws + 25165824 + 3 * 16777216);     // [B,S,E]
  float*          MsC = (float*)(ws + 25165824 + 4 * 16777216);              // 32 KB

  cast_all<<<dim3(4096, 6), 256, 0, stream>>>(x, wq, wk, wv, wo, mask,
                                              Xb, Wqb, Wkb, Wvb, Wob, MsC);
  gemm_bt<0><<<dim3(64, 8, 2), 256, 0, stream>>>(Xb, Wqb, Wkb, bq, bk, nullptr,
                                                 Qg, Kg, nullptr, 8192, 1024, 1024);
  gemm_bt<2><<<dim3(8, 64, 1), 256, 0, stream>>>(Wvb, Xb, nullptr, bv, nullptr, nullptr,
                                                 Vtg, nullptr, nullptr, 1024, 8192, 1024);
  attn_kernel<<<dim3(1024), 256, 0, stream>>>(Qg, Kg, Vtg, MsC, CTX);
  gemm_bt<3><<<dim3(64, 8, 1), 256, 0, stream>>>(CTX, Wob, nullptr, bo, nullptr, x,
                                                 nullptr, nullptr, out, 8192, 1024, 1024);
  ln_kernel<<<dim3(8192), 256, 0, stream>>>(out, lnw, lnb);
}

// Round 3
// 254.501 us; speedup vs baseline: 1.9221x; 1.1488x over previous
//
#include <hip/hip_runtime.h>
#include <hip/hip_bf16.h>
#include <stdint.h>

// ---------------------------------------------------------------------------
// MultiHeadSelfAttention fused block, MI355X/gfx950, bf16 MFMA pipeline.
// B=4 S=2048 E=1024 H=16 D=64.
// R2: attn softmax de-VALU-ified: Q pre-scaled by log2e/8 (QK output directly
// in log2 domain), mask folded into EM=exp(mask) (multiplied into Vt + used as
// MFMA A-operand to accumulate the softmax denominator), raw v_exp_f32,
// v_max3_f32 max tree, permlane32_swap (VALU) replaces ds_bpermute shuffles.
// ---------------------------------------------------------------------------

typedef short bf16x8_t __attribute__((ext_vector_type(8)));
typedef float f32x4_t __attribute__((ext_vector_type(4)));
typedef float f32x16_t __attribute__((ext_vector_type(16)));
typedef unsigned short u16x8_t __attribute__((ext_vector_type(8)));
typedef uint32_t u32x4_t __attribute__((ext_vector_type(4)));

#define DEV static __device__ __forceinline__

DEV unsigned short f2bf(float f) {  // RNE f32->bf16
  union { float f; uint32_t u; } v; v.f = f;
  uint32_t u = v.u;
  return (unsigned short)((u + 0x7fffu + ((u >> 16) & 1u)) >> 16);
}

DEV uint32_t cvtpk(float a, float b) {  // packed {lo=a, hi=b} bf16, RNE
  uint32_t d;
  asm("v_cvt_pk_bf16_f32 %0, %1, %2" : "=v"(d) : "v"(a), "v"(b));
  return d;
}

DEV float max3f(float a, float b, float c) {
  float d;
  asm("v_max3_f32 %0, %1, %2, %3" : "=v"(d) : "v"(a), "v"(b), "v"(c));
  return d;
}

// swap: a <- {a.lo_lanes, b.lo_lanes}, b <- {a.hi_lanes, b.hi_lanes}
DEV void plswap(uint32_t& a, uint32_t& b) {
  asm("v_permlane32_swap_b32 %0, %1" : "+v"(a), "+v"(b));
}

typedef const __attribute__((address_space(1))) void* gp_t;
typedef __attribute__((address_space(3))) void* lp_t;

DEV void gld16(const void* g, void* l) {  // async global->LDS, 16B/lane
  __builtin_amdgcn_global_load_lds((gp_t)g, (lp_t)l, 16, 0, 0);
}

// ---------------------------------------------------------------------------
__global__ __launch_bounds__(256) void cast_all(
    const float* __restrict__ x,
    const float* __restrict__ wq, const float* __restrict__ wk,
    const float* __restrict__ wv, const float* __restrict__ wo,
    const float* __restrict__ mask,
    unsigned short* __restrict__ xb,
    unsigned short* __restrict__ wqb, unsigned short* __restrict__ wkb,
    unsigned short* __restrict__ wvb, unsigned short* __restrict__ wob,
    float* __restrict__ emf, unsigned short* __restrict__ emb)
{
  if (blockIdx.y == 5) {  // EM = exp(mask): f32 (for Vt fold) + bf16 (l-MFMA)
    int i = (int)(blockIdx.x * 256 + threadIdx.x) * 8;
    if (i >= 4 * 2048) return;
    float4 a = *(const float4*)(mask + i);
    float4 b = *(const float4*)(mask + i + 4);
    const float C = 1.44269504f;
    float4 ea, eb;
    ea.x = __builtin_amdgcn_exp2f(a.x * C); ea.y = __builtin_amdgcn_exp2f(a.y * C);
    ea.z = __builtin_amdgcn_exp2f(a.z * C); ea.w = __builtin_amdgcn_exp2f(a.w * C);
    eb.x = __builtin_amdgcn_exp2f(b.x * C); eb.y = __builtin_amdgcn_exp2f(b.y * C);
    eb.z = __builtin_amdgcn_exp2f(b.z * C); eb.w = __builtin_amdgcn_exp2f(b.w * C);
    *(float4*)(emf + i) = ea;
    *(float4*)(emf + i + 4) = eb;
    u16x8_t o;
    o[0] = f2bf(ea.x); o[1] = f2bf(ea.y); o[2] = f2bf(ea.z); o[3] = f2bf(ea.w);
    o[4] = f2bf(eb.x); o[5] = f2bf(eb.y); o[6] = f2bf(eb.z); o[7] = f2bf(eb.w);
    *(u16x8_t*)(emb + i) = o;
    return;
  }
  const float* src; unsigned short* dst; int n;
  switch (blockIdx.y) {
    case 0:  src = x;  dst = xb;  n = 8192 * 1024; break;
    case 1:  src = wq; dst = wqb; n = 1024 * 1024; break;
    case 2:  src = wk; dst = wkb; n = 1024 * 1024; break;
    case 3:  src = wv; dst = wvb; n = 1024 * 1024; break;
    default: src = wo; dst = wob; n = 1024 * 1024; break;
  }
  int i = (int)(blockIdx.x * 256 + threadIdx.x) * 8;
  if (i >= n) return;
  float4 a = *(const float4*)(src + i);
  float4 b = *(const float4*)(src + i + 4);
  u16x8_t o;
  o[0] = f2bf(a.x); o[1] = f2bf(a.y); o[2] = f2bf(a.z); o[3] = f2bf(a.w);
  o[4] = f2bf(b.x); o[5] = f2bf(b.y); o[6] = f2bf(b.z); o[7] = f2bf(b.w);
  *(u16x8_t*)(dst + i) = o;
}

// ---------------------------------------------------------------------------
// C[m,n] = sum_k A[m,k]*B[n,k]. 128x128 tile, BK=32, 4 waves, 16x16x32 MFMA.
// MODE 0: QK proj (z=0: Q scaled log2e/8; z=1: K), out bf16 [B,H,S,D]
// MODE 2: Vt (A=Wv rows e, B=X rows (b,s)), out bf16 [B,H,D,S] * EM (resid=EMf)
// MODE 3: WO + bias + residual, out f32 [M,N]
template<int MODE>
__global__ __launch_bounds__(256) void gemm_bt(
    const unsigned short* __restrict__ A,
    const unsigned short* __restrict__ B0, const unsigned short* __restrict__ B1,
    const float* __restrict__ bias0, const float* __restrict__ bias1,
    const float* __restrict__ resid,
    unsigned short* __restrict__ o0, unsigned short* __restrict__ o1,
    float* __restrict__ of,
    int M, int N, int K)
{
  __shared__ unsigned short As[128 * 32];
  __shared__ unsigned short Bs[128 * 32];

  const int z = blockIdx.z;
  const unsigned short* Bw = (MODE == 0 && z == 1) ? B1 : B0;
  const float* bias = (MODE == 0 && z == 1) ? bias1 : bias0;
  unsigned short* obf = (MODE == 0 && z == 1) ? o1 : o0;

  const int tid = threadIdx.x;
  const int lane = tid & 63;
  const int lr = lane & 15, lq = lane >> 4;
  const int wid = tid >> 6;
  const int m0 = blockIdx.x * 128;
  const int n0 = blockIdx.y * 128;
  const int wr = (wid >> 1) * 64, wc = (wid & 1) * 64;

  f32x4_t acc[4][4] = {};

  const int o = tid * 16;
  for (int kt = 0; kt < K; kt += 32) {
#pragma unroll
    for (int r = 0; r < 2; ++r) {
      int oo = o + r * 4096;
      int row = oo >> 6, cb = oo & 63;
      gld16((const char*)(A  + (size_t)(m0 + row) * K + kt) + cb, (char*)As + oo);
      gld16((const char*)(Bw + (size_t)(n0 + row) * K + kt) + cb, (char*)Bs + oo);
    }
    __syncthreads();
    bf16x8_t aF[4], bF[4];
    const int koff = lq * 16;
#pragma unroll
    for (int i = 0; i < 4; ++i) {
      aF[i] = *(const bf16x8_t*)((const char*)As + (wr + i * 16 + lr) * 64 + koff);
      bF[i] = *(const bf16x8_t*)((const char*)Bs + (wc + i * 16 + lr) * 64 + koff);
    }
#pragma unroll
    for (int i = 0; i < 4; ++i)
#pragma unroll
      for (int j = 0; j < 4; ++j)
        acc[i][j] = __builtin_amdgcn_mfma_f32_16x16x32_bf16(aF[i], bF[j], acc[i][j], 0, 0, 0);
    __syncthreads();
  }

#pragma unroll
  for (int i = 0; i < 4; ++i) {
#pragma unroll
    for (int j = 0; j < 4; ++j) {
      int n = n0 + wc + j * 16 + lr;
#pragma unroll
      for (int r = 0; r < 4; ++r) {
        int m = m0 + wr + i * 16 + lq * 4 + r;
        float v = acc[i][j][r];
        if (MODE == 0) {
          // z=0 (Q): fold 1/sqrt(64) AND log2e so QK^T lands in log2 domain
          v = (v + bias[n]) * (z == 0 ? 0.18033688f : 1.0f);
          int b = m >> 11, s = m & 2047, h = n >> 6, d = n & 63;
          obf[(size_t)((b * 16 + h) * 2048 + s) * 64 + d] = f2bf(v);
        } else if (MODE == 2) {
          v = (v + bias[m]) * resid[n];  // resid = EMf, n = b*2048+s
          int b = n >> 11, s = n & 2047;
          obf[(size_t)(b * 1024 + m) * 2048 + s] = f2bf(v);
        } else {
          v = v + bias[n] + resid[(size_t)m * 1024 + n];
          of[(size_t)m * 1024 + n] = v;
        }
      }
    }
  }
}

// ---------------------------------------------------------------------------
// Flash attention, swapped-QK^T 32x32 structure (R2 lean-softmax).
// Grid 1024 (= 64 bh * 16 q-tiles), 256 threads (4 waves), wave owns 32 q.
// S^T = mfma(K, Q) directly in log2 domain (Q pre-scaled by log2e/8).
// l accumulated by MFMA with A = EM fragment (all rows identical).
__global__ __launch_bounds__(256) void attn_kernel(
    const unsigned short* __restrict__ Qg, const unsigned short* __restrict__ Kg,
    const unsigned short* __restrict__ Vtg, const unsigned short* __restrict__ EMb,
    unsigned short* __restrict__ ctx)
{
  // smem: Ks[2][8192] | Vs[2][8192] | Es[2][128]; epilogue reuses 0..16K
  __shared__ __align__(16) char smem[33280];

  const int id = blockIdx.x;
  const int swz = (id & 7) * 128 + (id >> 3);  // bijective XCD swizzle
  const int bh = swz >> 4, qt = swz & 15;
  const int b = bh >> 4, h = bh & 15;

  const int tid = threadIdx.x, lane = tid & 63, wid = tid >> 6;
  const int l31 = lane & 31, hi = lane >> 5;
  const int q0 = qt * 128 + wid * 32;
  const size_t head = (size_t)bh * (2048 * 64);
  const unsigned short* Kh = Kg + head;
  const unsigned short* Vh = Vtg + (size_t)bh * 64 * 2048;
  const unsigned short* emrow = EMb + (size_t)b * 2048;

  // Q B-fragments: col q = q0+l31, d = ds*16 + 8*hi + j
  bf16x8_t qf[4];
  {
    const unsigned short* qp = Qg + head + (size_t)(q0 + l31) * 64 + 8 * hi;
#pragma unroll
    for (int ds = 0; ds < 4; ++ds) qf[ds] = *(const bf16x8_t*)(qp + ds * 16);
  }

  f32x16_t oacc0 = {}, oacc1 = {};   // O^T[d,q]: d 0-31 / 32-63
  f32x16_t lacc = {};                // denominator: all regs equal; read [0]
  float m_run = -3e38f;

  const int sw_row = (l31 & 7) << 4;

  auto STAGE = [&](int t, int p) {
    const int k0 = t * 64;
    char* kd = smem + p * 8192;
    char* vd = smem + 16384 + p * 8192;
#pragma unroll
    for (int r = 0; r < 2; ++r) {
      int oo = tid * 16 + r * 4096;
      int row = oo >> 7, cb = oo & 127;
      int scb = cb ^ ((row & 7) << 4);  // inverse swizzle on global source
      gld16((const char*)(Kh + (size_t)(k0 + row) * 64) + scb, kd + oo);
      gld16((const char*)(Vh + (size_t)row * 2048 + k0) + scb, vd + oo);
    }
    if (tid < 8)
      gld16((const char*)(emrow + k0 + tid * 8), smem + 32768 + p * 128 + tid * 16);
  };

  STAGE(0, 0);
  __syncthreads();

  for (int t = 0; t < 32; ++t) {
    const int p = t & 1;
    if (t < 31) STAGE(t + 1, p ^ 1);

    const char* kb = smem + p * 8192;
    const char* vb = smem + 16384 + p * 8192;
    const char* eb = smem + 32768 + p * 128;

    // ---- S^T = K . Q^T (log2 domain): c0 = k 0-31, c1 = k 32-63
    f32x16_t c0 = {}, c1 = {};
    {
      const char* kr0 = kb + l31 * 128;
      const char* kr1 = kb + (32 + l31) * 128;
#pragma unroll
      for (int ds = 0; ds < 4; ++ds) {
        int cc = (ds * 32 + 16 * hi) ^ sw_row;
        bf16x8_t k0f = *(const bf16x8_t*)(kr0 + cc);
        bf16x8_t k1f = *(const bf16x8_t*)(kr1 + cc);
        c0 = __builtin_amdgcn_mfma_f32_32x32x16_bf16(k0f, qf[ds], c0, 0, 0, 0);
        c1 = __builtin_amdgcn_mfma_f32_32x32x16_bf16(k1f, qf[ds], c1, 0, 0, 0);
      }
    }

    // ---- max via v_max3 tree + permlane cross
    float mx;
    {
      float m0 = fmaxf(c0[0], c0[1]);
      float m1 = fmaxf(c0[8], c0[9]);
      float m2 = fmaxf(c1[0], c1[1]);
      float m3 = fmaxf(c1[8], c1[9]);
#pragma unroll
      for (int i = 2; i < 8; i += 2) {
        m0 = max3f(m0, c0[i], c0[i + 1]);
        m1 = max3f(m1, c0[8 + i], c0[8 + i + 1]);
        m2 = max3f(m2, c1[i], c1[i + 1]);
        m3 = max3f(m3, c1[8 + i], c1[8 + i + 1]);
      }
      mx = fmaxf(max3f(m0, m1, m2), m3);
      uint32_t ax = __float_as_uint(mx), bx = ax;
      plswap(ax, bx);
      mx = fmaxf(__uint_as_float(ax), __uint_as_float(bx));
    }
    // defer-max (T13): 8 nats = 11.54 in log2 domain
    if (!__all(mx <= m_run + 11.5416f)) {
      float mnew = fmaxf(m_run, mx);
      float alpha = __builtin_amdgcn_exp2f(m_run - mnew);
      m_run = mnew;
      lacc[0] *= alpha;
#pragma unroll
      for (int i = 0; i < 16; ++i) { oacc0[i] *= alpha; oacc1[i] *= alpha; }
    }

    // ---- P = exp2(c - m), pack to bf16, permlane partner exchange
    float pp[32];
#pragma unroll
    for (int i = 0; i < 16; ++i) {
      pp[i]      = __builtin_amdgcn_exp2f(c0[i] - m_run);
      pp[16 + i] = __builtin_amdgcn_exp2f(c1[i] - m_run);
    }
    uint32_t w0[8], w1[8];
#pragma unroll
    for (int g = 0; g < 8; ++g) {
      w0[g] = cvtpk(pp[4 * g], pp[4 * g + 1]);
      w1[g] = cvtpk(pp[4 * g + 2], pp[4 * g + 3]);
    }
    bf16x8_t pf[4];
#pragma unroll
    for (int ks = 0; ks < 4; ++ks) {
      const int gg = ((ks >> 1) << 2) + ((ks & 1) << 1);
      uint32_t a0 = w0[gg], b0 = w0[gg + 1];
      uint32_t a1 = w1[gg], b1 = w1[gg + 1];
      plswap(a0, b0);
      plswap(a1, b1);
      union { uint32_t u[4]; bf16x8_t v; } cv;
      cv.u[0] = a0; cv.u[1] = a1; cv.u[2] = b0; cv.u[3] = b1;
      pf[ks] = cv.v;
    }

    // ---- PV (O^T += Vt.P^T) and l (lacc += EM.P^T) on MFMA pipe
    {
      const char* vr0 = vb + l31 * 128;
      const char* vr1 = vb + (32 + l31) * 128;
#pragma unroll
      for (int ks = 0; ks < 4; ++ks) {
        bf16x8_t ef = *(const bf16x8_t*)(eb + ks * 32 + 16 * hi);
        int cc = (ks * 32 + 16 * hi) ^ sw_row;
        bf16x8_t v0f = *(const bf16x8_t*)(vr0 + cc);
        bf16x8_t v1f = *(const bf16x8_t*)(vr1 + cc);
        oacc0 = __builtin_amdgcn_mfma_f32_32x32x16_bf16(v0f, pf[ks], oacc0, 0, 0, 0);
        oacc1 = __builtin_amdgcn_mfma_f32_32x32x16_bf16(v1f, pf[ks], oacc1, 0, 0, 0);
        lacc  = __builtin_amdgcn_mfma_f32_32x32x16_bf16(ef,  pf[ks], lacc,  0, 0, 0);
      }
    }
    __syncthreads();
  }

  // ---- epilogue: O^T -> LDS (swizzled) -> coalesced global store
  const float inv = 1.0f / lacc[0];
  char* tb = smem + wid * 4096;  // per-wave 32q x 128B, reuses K buffers
#pragma unroll
  for (int g2 = 0; g2 < 4; ++g2) {
    uint2 a0, a1;
    a0.x = cvtpk(oacc0[4 * g2] * inv, oacc0[4 * g2 + 1] * inv);
    a0.y = cvtpk(oacc0[4 * g2 + 2] * inv, oacc0[4 * g2 + 3] * inv);
    a1.x = cvtpk(oacc1[4 * g2] * inv, oacc1[4 * g2 + 1] * inv);
    a1.y = cvtpk(oacc1[4 * g2 + 2] * inv, oacc1[4 * g2 + 3] * inv);
    const int swq = (l31 & 7) << 4;
    int d0 = 16 * g2 + 8 * hi;
    *(uint2*)(tb + l31 * 128 + ((d0) ^ swq)) = a0;
    *(uint2*)(tb + l31 * 128 + ((d0 + 64) ^ swq)) = a1;
  }
  {
    const int qq = lane >> 1, cp = lane & 1;
    const char* trow = tb + qq * 128;
    const int swr = (qq & 7) << 4;
    unsigned short* op = ctx + ((size_t)(b * 2048 + q0 + qq)) * 1024 + h * 64 + cp * 32;
#pragma unroll
    for (int i = 0; i < 4; ++i) {
      int col = cp * 64 + i * 16;
      u32x4_t val = *(const u32x4_t*)(trow + (col ^ swr));
      *(u32x4_t*)(op + i * 8) = val;
    }
  }
}

// ---------------------------------------------------------------------------
__global__ __launch_bounds__(256) void ln_kernel(
    float* __restrict__ y, const float* __restrict__ g, const float* __restrict__ be)
{
  const int row = blockIdx.x, tid = threadIdx.x;
  float* rp = y + (size_t)row * 1024;
  float4 x = *(const float4*)(rp + tid * 4);
  float s = x.x + x.y + x.z + x.w;
  float sq = x.x * x.x + x.y * x.y + x.z * x.z + x.w * x.w;
#pragma unroll
  for (int msk = 1; msk < 64; msk <<= 1) {
    s  += __shfl_xor(s, msk);
    sq += __shfl_xor(sq, msk);
  }
  __shared__ float red[8];
  const int wid = tid >> 6, lane = tid & 63;
  if (lane == 0) { red[wid] = s; red[4 + wid] = sq; }
  __syncthreads();
  s  = red[0] + red[1] + red[2] + red[3];
  sq = red[4] + red[5] + red[6] + red[7];
  float mu = s * (1.f / 1024.f);
  float var = sq * (1.f / 1024.f) - mu * mu;
  float rs = rsqrtf(var + 1e-12f);
  float4 gw = *(const float4*)(g + tid * 4);
  float4 bw = *(const float4*)(be + tid * 4);
  float4 o2;
  o2.x = (x.x - mu) * rs * gw.x + bw.x;
  o2.y = (x.y - mu) * rs * gw.y + bw.y;
  o2.z = (x.z - mu) * rs * gw.z + bw.z;
  o2.w = (x.w - mu) * rs * gw.w + bw.w;
  *(float4*)(rp + tid * 4) = o2;
}

// ---------------------------------------------------------------------------
extern "C" void kernel_launch(void* const* d_in, const int* in_sizes, int n_in,
                              void* d_out, int out_size, void* d_ws, size_t ws_size,
                              hipStream_t stream)
{
  const float* x    = (const float*)d_in[0];
  const float* mask = (const float*)d_in[1];
  const float* wq   = (const float*)d_in[2];
  const float* bq   = (const float*)d_in[3];
  const float* wk   = (const float*)d_in[4];
  const float* bk   = (const float*)d_in[5];
  const float* wv   = (const float*)d_in[6];
  const float* bv   = (const float*)d_in[7];
  const float* wo   = (const float*)d_in[8];
  const float* bo   = (const float*)d_in[9];
  const float* lnw  = (const float*)d_in[10];
  const float* lnb  = (const float*)d_in[11];
  float* out = (float*)d_out;

  char* ws = (char*)d_ws;
  unsigned short* Xb  = (unsigned short*)(ws);                               // 16 MB
  unsigned short* Wqb = (unsigned short*)(ws + 16777216);                    // 2 MB
  unsigned short* Wkb = (unsigned short*)(ws + 16777216 + 2097152);
  unsigned short* Wvb = (unsigned short*)(ws + 16777216 + 2 * 2097152);
  unsigned short* Wob = (unsigned short*)(ws + 16777216 + 3 * 2097152);
  unsigned short* Qg  = (unsigned short*)(ws + 25165824);                    // [B,H,S,D]
  unsigned short* Kg  = (unsigned short*)(ws + 25165824 + 16777216);         // [B,H,S,D]
  unsigned short* Vtg = (unsigned short*)(ws + 25165824 + 2 * 16777216);     // [B,H,D,S]
  unsigned short* CTX = (unsigned short*)(ws + 25165824 + 3 * 16777216);     // [B,S,E]
  float*          EMf = (float*)(ws + 92274688);                             // 32 KB
  unsigned short* EMb = (unsigned short*)(ws + 92274688 + 32768);            // 16 KB

  cast_all<<<dim3(4096, 6), 256, 0, stream>>>(x, wq, wk, wv, wo, mask,
                                              Xb, Wqb, Wkb, Wvb, Wob, EMf, EMb);
  gemm_bt<0><<<dim3(64, 8, 2), 256, 0, stream>>>(Xb, Wqb, Wkb, bq, bk, nullptr,
                                                 Qg, Kg, nullptr, 8192, 1024, 1024);
  gemm_bt<2><<<dim3(8, 64, 1), 256, 0, stream>>>(Wvb, Xb, nullptr, bv, nullptr, EMf,
                                                 Vtg, nullptr, nullptr, 1024, 8192, 1024);
  attn_kernel<<<dim3(1024), 256, 0, stream>>>(Qg, Kg, Vtg, EMb, CTX);
  gemm_bt<3><<<dim3(64, 8, 1), 256, 0, stream>>>(CTX, Wob, nullptr, bo, nullptr, x,
                                                 nullptr, nullptr, out, 8192, 1024, 1024);
  ln_kernel<<<dim3(8192), 256, 0, stream>>>(out, lnw, lnb);
}

// Round 4
// 240.128 us; speedup vs baseline: 2.0371x; 1.0599x over previous
//
#include <hip/hip_runtime.h>
#include <hip/hip_bf16.h>
#include <stdint.h>

// ---------------------------------------------------------------------------
// MultiHeadSelfAttention fused block, MI355X/gfx950, bf16 MFMA pipeline.
// B=4 S=2048 E=1024 H=16 D=64.
// R3: attn softmax max-free (P = exp2(c) raw; 2^m cancels in O/l; scores are
// O(1) so no overflow risk at 100+ sigma), setprio around MFMA clusters,
// exact cast grid. SQ_LDS_BANK_CONFLICT identified as global_load_lds
// write-port artifact (2^23 constant) - not a target.
// ---------------------------------------------------------------------------

typedef short bf16x8_t __attribute__((ext_vector_type(8)));
typedef float f32x4_t __attribute__((ext_vector_type(4)));
typedef float f32x16_t __attribute__((ext_vector_type(16)));
typedef unsigned short u16x8_t __attribute__((ext_vector_type(8)));
typedef uint32_t u32x4_t __attribute__((ext_vector_type(4)));

#define DEV static __device__ __forceinline__

DEV unsigned short f2bf(float f) {  // RNE f32->bf16
  union { float f; uint32_t u; } v; v.f = f;
  uint32_t u = v.u;
  return (unsigned short)((u + 0x7fffu + ((u >> 16) & 1u)) >> 16);
}

DEV uint32_t cvtpk(float a, float b) {  // packed {lo=a, hi=b} bf16, RNE
  uint32_t d;
  asm("v_cvt_pk_bf16_f32 %0, %1, %2" : "=v"(d) : "v"(a), "v"(b));
  return d;
}

// swap: a <- {a.lo_lanes, b.lo_lanes}, b <- {a.hi_lanes, b.hi_lanes}
DEV void plswap(uint32_t& a, uint32_t& b) {
  asm("v_permlane32_swap_b32 %0, %1" : "+v"(a), "+v"(b));
}

DEV float ex2(float x) { return __builtin_amdgcn_exp2f(x); }

typedef const __attribute__((address_space(1))) void* gp_t;
typedef __attribute__((address_space(3))) void* lp_t;

DEV void gld16(const void* g, void* l) {  // async global->LDS, 16B/lane
  __builtin_amdgcn_global_load_lds((gp_t)g, (lp_t)l, 16, 0, 0);
}

// ---------------------------------------------------------------------------
// Flat exact grid: X 4096 | Wq 512 | Wk 512 | Wv 512 | Wo 512 | mask 4 = 6148
__global__ __launch_bounds__(256) void cast_all(
    const float* __restrict__ x,
    const float* __restrict__ wq, const float* __restrict__ wk,
    const float* __restrict__ wv, const float* __restrict__ wo,
    const float* __restrict__ mask,
    unsigned short* __restrict__ xb,
    unsigned short* __restrict__ wqb, unsigned short* __restrict__ wkb,
    unsigned short* __restrict__ wvb, unsigned short* __restrict__ wob,
    float* __restrict__ emf, unsigned short* __restrict__ emb)
{
  const int cid = blockIdx.x;
  if (cid >= 6144) {  // EM = exp(mask): f32 (Vt fold) + bf16 (l-MFMA A-op)
    int i = ((cid - 6144) * 256 + (int)threadIdx.x) * 8;
    float4 a = *(const float4*)(mask + i);
    float4 b = *(const float4*)(mask + i + 4);
    const float C = 1.44269504f;
    float4 ea, eb;
    ea.x = ex2(a.x * C); ea.y = ex2(a.y * C); ea.z = ex2(a.z * C); ea.w = ex2(a.w * C);
    eb.x = ex2(b.x * C); eb.y = ex2(b.y * C); eb.z = ex2(b.z * C); eb.w = ex2(b.w * C);
    *(float4*)(emf + i) = ea;
    *(float4*)(emf + i + 4) = eb;
    u16x8_t o;
    o[0] = f2bf(ea.x); o[1] = f2bf(ea.y); o[2] = f2bf(ea.z); o[3] = f2bf(ea.w);
    o[4] = f2bf(eb.x); o[5] = f2bf(eb.y); o[6] = f2bf(eb.z); o[7] = f2bf(eb.w);
    *(u16x8_t*)(emb + i) = o;
    return;
  }
  const float* src; unsigned short* dst; int base;
  if (cid < 4096)      { src = x;  dst = xb;  base = cid; }
  else if (cid < 4608) { src = wq; dst = wqb; base = cid - 4096; }
  else if (cid < 5120) { src = wk; dst = wkb; base = cid - 4608; }
  else if (cid < 5632) { src = wv; dst = wvb; base = cid - 5120; }
  else                 { src = wo; dst = wob; base = cid - 5632; }
  int i = (base * 256 + (int)threadIdx.x) * 8;
  float4 a = *(const float4*)(src + i);
  float4 b = *(const float4*)(src + i + 4);
  u16x8_t o;
  o[0] = f2bf(a.x); o[1] = f2bf(a.y); o[2] = f2bf(a.z); o[3] = f2bf(a.w);
  o[4] = f2bf(b.x); o[5] = f2bf(b.y); o[6] = f2bf(b.z); o[7] = f2bf(b.w);
  *(u16x8_t*)(dst + i) = o;
}

// ---------------------------------------------------------------------------
// C[m,n] = sum_k A[m,k]*B[n,k]. 128x128 tile, BK=32, 4 waves, 16x16x32 MFMA.
// MODE 0: QK proj (z=0: Q scaled log2e/8; z=1: K), out bf16 [B,H,S,D]
// MODE 2: Vt (A=Wv rows e, B=X rows (b,s)), out bf16 [B,H,D,S] * EM (resid=EMf)
// MODE 3: WO + bias + residual, out f32 [M,N]
template<int MODE>
__global__ __launch_bounds__(256) void gemm_bt(
    const unsigned short* __restrict__ A,
    const unsigned short* __restrict__ B0, const unsigned short* __restrict__ B1,
    const float* __restrict__ bias0, const float* __restrict__ bias1,
    const float* __restrict__ resid,
    unsigned short* __restrict__ o0, unsigned short* __restrict__ o1,
    float* __restrict__ of,
    int M, int N, int K)
{
  __shared__ unsigned short As[128 * 32];
  __shared__ unsigned short Bs[128 * 32];

  const int z = blockIdx.z;
  const unsigned short* Bw = (MODE == 0 && z == 1) ? B1 : B0;
  const float* bias = (MODE == 0 && z == 1) ? bias1 : bias0;
  unsigned short* obf = (MODE == 0 && z == 1) ? o1 : o0;

  const int tid = threadIdx.x;
  const int lane = tid & 63;
  const int lr = lane & 15, lq = lane >> 4;
  const int wid = tid >> 6;
  const int m0 = blockIdx.x * 128;
  const int n0 = blockIdx.y * 128;
  const int wr = (wid >> 1) * 64, wc = (wid & 1) * 64;

  f32x4_t acc[4][4] = {};

  const int o = tid * 16;
  for (int kt = 0; kt < K; kt += 32) {
#pragma unroll
    for (int r = 0; r < 2; ++r) {
      int oo = o + r * 4096;
      int row = oo >> 6, cb = oo & 63;
      gld16((const char*)(A  + (size_t)(m0 + row) * K + kt) + cb, (char*)As + oo);
      gld16((const char*)(Bw + (size_t)(n0 + row) * K + kt) + cb, (char*)Bs + oo);
    }
    __syncthreads();
    bf16x8_t aF[4], bF[4];
    const int koff = lq * 16;
#pragma unroll
    for (int i = 0; i < 4; ++i) {
      aF[i] = *(const bf16x8_t*)((const char*)As + (wr + i * 16 + lr) * 64 + koff);
      bF[i] = *(const bf16x8_t*)((const char*)Bs + (wc + i * 16 + lr) * 64 + koff);
    }
    __builtin_amdgcn_s_setprio(1);
#pragma unroll
    for (int i = 0; i < 4; ++i)
#pragma unroll
      for (int j = 0; j < 4; ++j)
        acc[i][j] = __builtin_amdgcn_mfma_f32_16x16x32_bf16(aF[i], bF[j], acc[i][j], 0, 0, 0);
    __builtin_amdgcn_s_setprio(0);
    __syncthreads();
  }

#pragma unroll
  for (int i = 0; i < 4; ++i) {
#pragma unroll
    for (int j = 0; j < 4; ++j) {
      int n = n0 + wc + j * 16 + lr;
#pragma unroll
      for (int r = 0; r < 4; ++r) {
        int m = m0 + wr + i * 16 + lq * 4 + r;
        float v = acc[i][j][r];
        if (MODE == 0) {
          // z=0 (Q): fold 1/sqrt(64) AND log2e so QK^T lands in log2 domain
          v = (v + bias[n]) * (z == 0 ? 0.18033688f : 1.0f);
          int b = m >> 11, s = m & 2047, h = n >> 6, d = n & 63;
          obf[(size_t)((b * 16 + h) * 2048 + s) * 64 + d] = f2bf(v);
        } else if (MODE == 2) {
          v = (v + bias[m]) * resid[n];  // resid = EMf, n = b*2048+s
          int b = n >> 11, s = n & 2047;
          obf[(size_t)(b * 1024 + m) * 2048 + s] = f2bf(v);
        } else {
          v = v + bias[n] + resid[(size_t)m * 1024 + n];
          of[(size_t)m * 1024 + n] = v;
        }
      }
    }
  }
}

// ---------------------------------------------------------------------------
// Flash attention, swapped-QK^T 32x32, max-free softmax.
// Grid 1024 (= 64 bh * 16 q-tiles), 256 threads (4 waves), wave owns 32 q.
// S^T = mfma(K, Q) in log2 domain (Q pre-scaled log2e/8). P = exp2(c) raw;
// the implicit 2^m factor cancels in O/l. l accumulated on the MFMA pipe
// with A = EM fragment (mask folded; EM also folded into Vt).
__global__ __launch_bounds__(256) void attn_kernel(
    const unsigned short* __restrict__ Qg, const unsigned short* __restrict__ Kg,
    const unsigned short* __restrict__ Vtg, const unsigned short* __restrict__ EMb,
    unsigned short* __restrict__ ctx)
{
  // smem: Ks[2][8192] | Vs[2][8192] | Es[2][128]; epilogue reuses 0..16K
  __shared__ __align__(16) char smem[33280];

  const int id = blockIdx.x;
  const int swz = (id & 7) * 128 + (id >> 3);  // bijective XCD swizzle
  const int bh = swz >> 4, qt = swz & 15;
  const int b = bh >> 4, h = bh & 15;

  const int tid = threadIdx.x, lane = tid & 63, wid = tid >> 6;
  const int l31 = lane & 31, hi = lane >> 5;
  const int q0 = qt * 128 + wid * 32;
  const size_t head = (size_t)bh * (2048 * 64);
  const unsigned short* Kh = Kg + head;
  const unsigned short* Vh = Vtg + (size_t)bh * 64 * 2048;
  const unsigned short* emrow = EMb + (size_t)b * 2048;

  // Q B-fragments: col q = q0+l31, d = ds*16 + 8*hi + j
  bf16x8_t qf[4];
  {
    const unsigned short* qp = Qg + head + (size_t)(q0 + l31) * 64 + 8 * hi;
#pragma unroll
    for (int ds = 0; ds < 4; ++ds) qf[ds] = *(const bf16x8_t*)(qp + ds * 16);
  }

  f32x16_t oacc0 = {}, oacc1 = {};   // O^T[d,q]: d 0-31 / 32-63
  f32x16_t lacc = {};                // denominator; read [0] at end

  const int sw_row = (l31 & 7) << 4;

  auto STAGE = [&](int t, int p) {
    const int k0 = t * 64;
    char* kd = smem + p * 8192;
    char* vd = smem + 16384 + p * 8192;
#pragma unroll
    for (int r = 0; r < 2; ++r) {
      int oo = tid * 16 + r * 4096;
      int row = oo >> 7, cb = oo & 127;
      int scb = cb ^ ((row & 7) << 4);  // inverse swizzle on global source
      gld16((const char*)(Kh + (size_t)(k0 + row) * 64) + scb, kd + oo);
      gld16((const char*)(Vh + (size_t)row * 2048 + k0) + scb, vd + oo);
    }
    if (tid < 8)
      gld16((const char*)(emrow + k0 + tid * 8), smem + 32768 + p * 128 + tid * 16);
  };

  STAGE(0, 0);
  __syncthreads();

  for (int t = 0; t < 32; ++t) {
    const int p = t & 1;
    if (t < 31) STAGE(t + 1, p ^ 1);

    const char* kb = smem + p * 8192;
    const char* vb = smem + 16384 + p * 8192;
    const char* eb = smem + 32768 + p * 128;

    // ---- S^T = K . Q^T (log2 domain): c0 = k 0-31, c1 = k 32-63
    f32x16_t c0 = {}, c1 = {};
    {
      const char* kr0 = kb + l31 * 128;
      const char* kr1 = kb + (32 + l31) * 128;
      __builtin_amdgcn_s_setprio(1);
#pragma unroll
      for (int ds = 0; ds < 4; ++ds) {
        int cc = (ds * 32 + 16 * hi) ^ sw_row;
        bf16x8_t k0f = *(const bf16x8_t*)(kr0 + cc);
        bf16x8_t k1f = *(const bf16x8_t*)(kr1 + cc);
        c0 = __builtin_amdgcn_mfma_f32_32x32x16_bf16(k0f, qf[ds], c0, 0, 0, 0);
        c1 = __builtin_amdgcn_mfma_f32_32x32x16_bf16(k1f, qf[ds], c1, 0, 0, 0);
      }
      __builtin_amdgcn_s_setprio(0);
    }

    // ---- P = exp2(c) raw (max-free), pack bf16, permlane partner exchange
    uint32_t w0[8], w1[8];
#pragma unroll
    for (int g = 0; g < 8; ++g) {
      const int i4 = (g & 3) * 4;
      if (g < 4) {
        w0[g] = cvtpk(ex2(c0[i4]), ex2(c0[i4 + 1]));
        w1[g] = cvtpk(ex2(c0[i4 + 2]), ex2(c0[i4 + 3]));
      } else {
        w0[g] = cvtpk(ex2(c1[i4]), ex2(c1[i4 + 1]));
        w1[g] = cvtpk(ex2(c1[i4 + 2]), ex2(c1[i4 + 3]));
      }
    }
    bf16x8_t pf[4];
#pragma unroll
    for (int ks = 0; ks < 4; ++ks) {
      const int gg = ((ks >> 1) << 2) + ((ks & 1) << 1);
      uint32_t a0 = w0[gg], b0 = w0[gg + 1];
      uint32_t a1 = w1[gg], b1 = w1[gg + 1];
      plswap(a0, b0);
      plswap(a1, b1);
      union { uint32_t u[4]; bf16x8_t v; } cv;
      cv.u[0] = a0; cv.u[1] = a1; cv.u[2] = b0; cv.u[3] = b1;
      pf[ks] = cv.v;
    }

    // ---- PV (O^T += Vt.P^T) and l (lacc += EM.P^T) on MFMA pipe
    {
      const char* vr0 = vb + l31 * 128;
      const char* vr1 = vb + (32 + l31) * 128;
      __builtin_amdgcn_s_setprio(1);
#pragma unroll
      for (int ks = 0; ks < 4; ++ks) {
        bf16x8_t ef = *(const bf16x8_t*)(eb + ks * 32 + 16 * hi);
        int cc = (ks * 32 + 16 * hi) ^ sw_row;
        bf16x8_t v0f = *(const bf16x8_t*)(vr0 + cc);
        bf16x8_t v1f = *(const bf16x8_t*)(vr1 + cc);
        oacc0 = __builtin_amdgcn_mfma_f32_32x32x16_bf16(v0f, pf[ks], oacc0, 0, 0, 0);
        oacc1 = __builtin_amdgcn_mfma_f32_32x32x16_bf16(v1f, pf[ks], oacc1, 0, 0, 0);
        lacc  = __builtin_amdgcn_mfma_f32_32x32x16_bf16(ef,  pf[ks], lacc,  0, 0, 0);
      }
      __builtin_amdgcn_s_setprio(0);
    }
    __syncthreads();
  }

  // ---- epilogue: O^T -> LDS (swizzled) -> coalesced global store
  const float inv = 1.0f / lacc[0];
  char* tb = smem + wid * 4096;  // per-wave 32q x 128B, reuses K buffers
#pragma unroll
  for (int g2 = 0; g2 < 4; ++g2) {
    uint2 a0, a1;
    a0.x = cvtpk(oacc0[4 * g2] * inv, oacc0[4 * g2 + 1] * inv);
    a0.y = cvtpk(oacc0[4 * g2 + 2] * inv, oacc0[4 * g2 + 3] * inv);
    a1.x = cvtpk(oacc1[4 * g2] * inv, oacc1[4 * g2 + 1] * inv);
    a1.y = cvtpk(oacc1[4 * g2 + 2] * inv, oacc1[4 * g2 + 3] * inv);
    const int swq = (l31 & 7) << 4;
    int d0 = 16 * g2 + 8 * hi;
    *(uint2*)(tb + l31 * 128 + ((d0) ^ swq)) = a0;
    *(uint2*)(tb + l31 * 128 + ((d0 + 64) ^ swq)) = a1;
  }
  {
    const int qq = lane >> 1, cp = lane & 1;
    const char* trow = tb + qq * 128;
    const int swr = (qq & 7) << 4;
    unsigned short* op = ctx + ((size_t)(b * 2048 + q0 + qq)) * 1024 + h * 64 + cp * 32;
#pragma unroll
    for (int i = 0; i < 4; ++i) {
      int col = cp * 64 + i * 16;
      u32x4_t val = *(const u32x4_t*)(trow + (col ^ swr));
      *(u32x4_t*)(op + i * 8) = val;
    }
  }
}

// ---------------------------------------------------------------------------
__global__ __launch_bounds__(256) void ln_kernel(
    float* __restrict__ y, const float* __restrict__ g, const float* __restrict__ be)
{
  const int row = blockIdx.x, tid = threadIdx.x;
  float* rp = y + (size_t)row * 1024;
  float4 x = *(const float4*)(rp + tid * 4);
  float s = x.x + x.y + x.z + x.w;
  float sq = x.x * x.x + x.y * x.y + x.z * x.z + x.w * x.w;
#pragma unroll
  for (int msk = 1; msk < 64; msk <<= 1) {
    s  += __shfl_xor(s, msk);
    sq += __shfl_xor(sq, msk);
  }
  __shared__ float red[8];
  const int wid = tid >> 6, lane = tid & 63;
  if (lane == 0) { red[wid] = s; red[4 + wid] = sq; }
  __syncthreads();
  s  = red[0] + red[1] + red[2] + red[3];
  sq = red[4] + red[5] + red[6] + red[7];
  float mu = s * (1.f / 1024.f);
  float var = sq * (1.f / 1024.f) - mu * mu;
  float rs = rsqrtf(var + 1e-12f);
  float4 gw = *(const float4*)(g + tid * 4);
  float4 bw = *(const float4*)(be + tid * 4);
  float4 o2;
  o2.x = (x.x - mu) * rs * gw.x + bw.x;
  o2.y = (x.y - mu) * rs * gw.y + bw.y;
  o2.z = (x.z - mu) * rs * gw.z + bw.z;
  o2.w = (x.w - mu) * rs * gw.w + bw.w;
  *(float4*)(rp + tid * 4) = o2;
}

// ---------------------------------------------------------------------------
extern "C" void kernel_launch(void* const* d_in, const int* in_sizes, int n_in,
                              void* d_out, int out_size, void* d_ws, size_t ws_size,
                              hipStream_t stream)
{
  const float* x    = (const float*)d_in[0];
  const float* mask = (const float*)d_in[1];
  const float* wq   = (const float*)d_in[2];
  const float* bq   = (const float*)d_in[3];
  const float* wk   = (const float*)d_in[4];
  const float* bk   = (const float*)d_in[5];
  const float* wv   = (const float*)d_in[6];
  const float* bv   = (const float*)d_in[7];
  const float* wo   = (const float*)d_in[8];
  const float* bo   = (const float*)d_in[9];
  const float* lnw  = (const float*)d_in[10];
  const float* lnb  = (const float*)d_in[11];
  float* out = (float*)d_out;

  char* ws = (char*)d_ws;
  unsigned short* Xb  = (unsigned short*)(ws);                               // 16 MB
  unsigned short* Wqb = (unsigned short*)(ws + 16777216);                    // 2 MB
  unsigned short* Wkb = (unsigned short*)(ws + 16777216 + 2097152);
  unsigned short* Wvb = (unsigned short*)(ws + 16777216 + 2 * 2097152);
  unsigned short* Wob = (unsigned short*)(ws + 16777216 + 3 * 2097152);
  unsigned short* Qg  = (unsigned short*)(ws + 25165824);                    // [B,H,S,D]
  unsigned short* Kg  = (unsigned short*)(ws + 25165824 + 16777216);         // [B,H,S,D]
  unsigned short* Vtg = (unsigned short*)(ws + 25165824 + 2 * 16777216);     // [B,H,D,S]
  unsigned short* CTX = (unsigned short*)(ws + 25165824 + 3 * 16777216);     // [B,S,E]
  float*          EMf = (float*)(ws + 92274688);                             // 32 KB
  unsigned short* EMb = (unsigned short*)(ws + 92274688 + 32768);            // 16 KB

  cast_all<<<dim3(6148), 256, 0, stream>>>(x, wq, wk, wv, wo, mask,
                                           Xb, Wqb, Wkb, Wvb, Wob, EMf, EMb);
  gemm_bt<0><<<dim3(64, 8, 2), 256, 0, stream>>>(Xb, Wqb, Wkb, bq, bk, nullptr,
                                                 Qg, Kg, nullptr, 8192, 1024, 1024);
  gemm_bt<2><<<dim3(8, 64, 1), 256, 0, stream>>>(Wvb, Xb, nullptr, bv, nullptr, EMf,
                                                 Vtg, nullptr, nullptr, 1024, 8192, 1024);
  attn_kernel<<<dim3(1024), 256, 0, stream>>>(Qg, Kg, Vtg, EMb, CTX);
  gemm_bt<3><<<dim3(64, 8, 1), 256, 0, stream>>>(CTX, Wob, nullptr, bo, nullptr, x,
                                                 nullptr, nullptr, out, 8192, 1024, 1024);
  ln_kernel<<<dim3(8192), 256, 0, stream>>>(out, lnw, lnb);
}

// Round 5
// 230.503 us; speedup vs baseline: 2.1222x; 1.0418x over previous
//
#include <hip/hip_runtime.h>
#include <hip/hip_bf16.h>
#include <stdint.h>

// ---------------------------------------------------------------------------
// MultiHeadSelfAttention fused block, MI355X/gfx950, bf16 MFMA pipeline.
// B=4 S=2048 E=1024 H=16 D=64.
// R4: attn QBLK 128->256 (wave owns 64 q as 2 q-groups): K/V/E LDS fragments
// read once per tile feed both q-groups -> LDS bytes per FLOP halved.
// Grid 512, 2 blocks/CU. gemm setprio reverted (m190: null/neg on lockstep).
// ---------------------------------------------------------------------------

typedef short bf16x8_t __attribute__((ext_vector_type(8)));
typedef float f32x4_t __attribute__((ext_vector_type(4)));
typedef float f32x16_t __attribute__((ext_vector_type(16)));
typedef unsigned short u16x8_t __attribute__((ext_vector_type(8)));
typedef uint32_t u32x4_t __attribute__((ext_vector_type(4)));

#define DEV static __device__ __forceinline__

DEV unsigned short f2bf(float f) {  // RNE f32->bf16
  union { float f; uint32_t u; } v; v.f = f;
  uint32_t u = v.u;
  return (unsigned short)((u + 0x7fffu + ((u >> 16) & 1u)) >> 16);
}

DEV uint32_t cvtpk(float a, float b) {  // packed {lo=a, hi=b} bf16, RNE
  uint32_t d;
  asm("v_cvt_pk_bf16_f32 %0, %1, %2" : "=v"(d) : "v"(a), "v"(b));
  return d;
}

// swap: a <- {a.lo_lanes, b.lo_lanes}, b <- {a.hi_lanes, b.hi_lanes}
DEV void plswap(uint32_t& a, uint32_t& b) {
  asm("v_permlane32_swap_b32 %0, %1" : "+v"(a), "+v"(b));
}

DEV float ex2(float x) { return __builtin_amdgcn_exp2f(x); }

typedef const __attribute__((address_space(1))) void* gp_t;
typedef __attribute__((address_space(3))) void* lp_t;

DEV void gld16(const void* g, void* l) {  // async global->LDS, 16B/lane
  __builtin_amdgcn_global_load_lds((gp_t)g, (lp_t)l, 16, 0, 0);
}

// ---------------------------------------------------------------------------
// Flat exact grid: X 4096 | Wq 512 | Wk 512 | Wv 512 | Wo 512 | mask 4 = 6148
__global__ __launch_bounds__(256) void cast_all(
    const float* __restrict__ x,
    const float* __restrict__ wq, const float* __restrict__ wk,
    const float* __restrict__ wv, const float* __restrict__ wo,
    const float* __restrict__ mask,
    unsigned short* __restrict__ xb,
    unsigned short* __restrict__ wqb, unsigned short* __restrict__ wkb,
    unsigned short* __restrict__ wvb, unsigned short* __restrict__ wob,
    float* __restrict__ emf, unsigned short* __restrict__ emb)
{
  const int cid = blockIdx.x;
  if (cid >= 6144) {  // EM = exp(mask): f32 (Vt fold) + bf16 (l-MFMA A-op)
    int i = ((cid - 6144) * 256 + (int)threadIdx.x) * 8;
    float4 a = *(const float4*)(mask + i);
    float4 b = *(const float4*)(mask + i + 4);
    const float C = 1.44269504f;
    float4 ea, eb;
    ea.x = ex2(a.x * C); ea.y = ex2(a.y * C); ea.z = ex2(a.z * C); ea.w = ex2(a.w * C);
    eb.x = ex2(b.x * C); eb.y = ex2(b.y * C); eb.z = ex2(b.z * C); eb.w = ex2(b.w * C);
    *(float4*)(emf + i) = ea;
    *(float4*)(emf + i + 4) = eb;
    u16x8_t o;
    o[0] = f2bf(ea.x); o[1] = f2bf(ea.y); o[2] = f2bf(ea.z); o[3] = f2bf(ea.w);
    o[4] = f2bf(eb.x); o[5] = f2bf(eb.y); o[6] = f2bf(eb.z); o[7] = f2bf(eb.w);
    *(u16x8_t*)(emb + i) = o;
    return;
  }
  const float* src; unsigned short* dst; int base;
  if (cid < 4096)      { src = x;  dst = xb;  base = cid; }
  else if (cid < 4608) { src = wq; dst = wqb; base = cid - 4096; }
  else if (cid < 5120) { src = wk; dst = wkb; base = cid - 4608; }
  else if (cid < 5632) { src = wv; dst = wvb; base = cid - 5120; }
  else                 { src = wo; dst = wob; base = cid - 5632; }
  int i = (base * 256 + (int)threadIdx.x) * 8;
  float4 a = *(const float4*)(src + i);
  float4 b = *(const float4*)(src + i + 4);
  u16x8_t o;
  o[0] = f2bf(a.x); o[1] = f2bf(a.y); o[2] = f2bf(a.z); o[3] = f2bf(a.w);
  o[4] = f2bf(b.x); o[5] = f2bf(b.y); o[6] = f2bf(b.z); o[7] = f2bf(b.w);
  *(u16x8_t*)(dst + i) = o;
}

// ---------------------------------------------------------------------------
// C[m,n] = sum_k A[m,k]*B[n,k]. 128x128 tile, BK=32, 4 waves, 16x16x32 MFMA.
// MODE 0: QK proj (z=0: Q scaled log2e/8; z=1: K), out bf16 [B,H,S,D]
// MODE 2: Vt (A=Wv rows e, B=X rows (b,s)), out bf16 [B,H,D,S] * EM (resid=EMf)
// MODE 3: WO + bias + residual, out f32 [M,N]
template<int MODE>
__global__ __launch_bounds__(256) void gemm_bt(
    const unsigned short* __restrict__ A,
    const unsigned short* __restrict__ B0, const unsigned short* __restrict__ B1,
    const float* __restrict__ bias0, const float* __restrict__ bias1,
    const float* __restrict__ resid,
    unsigned short* __restrict__ o0, unsigned short* __restrict__ o1,
    float* __restrict__ of,
    int M, int N, int K)
{
  __shared__ unsigned short As[128 * 32];
  __shared__ unsigned short Bs[128 * 32];

  const int z = blockIdx.z;
  const unsigned short* Bw = (MODE == 0 && z == 1) ? B1 : B0;
  const float* bias = (MODE == 0 && z == 1) ? bias1 : bias0;
  unsigned short* obf = (MODE == 0 && z == 1) ? o1 : o0;

  const int tid = threadIdx.x;
  const int lane = tid & 63;
  const int lr = lane & 15, lq = lane >> 4;
  const int wid = tid >> 6;
  const int m0 = blockIdx.x * 128;
  const int n0 = blockIdx.y * 128;
  const int wr = (wid >> 1) * 64, wc = (wid & 1) * 64;

  f32x4_t acc[4][4] = {};

  const int o = tid * 16;
  for (int kt = 0; kt < K; kt += 32) {
#pragma unroll
    for (int r = 0; r < 2; ++r) {
      int oo = o + r * 4096;
      int row = oo >> 6, cb = oo & 63;
      gld16((const char*)(A  + (size_t)(m0 + row) * K + kt) + cb, (char*)As + oo);
      gld16((const char*)(Bw + (size_t)(n0 + row) * K + kt) + cb, (char*)Bs + oo);
    }
    __syncthreads();
    bf16x8_t aF[4], bF[4];
    const int koff = lq * 16;
#pragma unroll
    for (int i = 0; i < 4; ++i) {
      aF[i] = *(const bf16x8_t*)((const char*)As + (wr + i * 16 + lr) * 64 + koff);
      bF[i] = *(const bf16x8_t*)((const char*)Bs + (wc + i * 16 + lr) * 64 + koff);
    }
#pragma unroll
    for (int i = 0; i < 4; ++i)
#pragma unroll
      for (int j = 0; j < 4; ++j)
        acc[i][j] = __builtin_amdgcn_mfma_f32_16x16x32_bf16(aF[i], bF[j], acc[i][j], 0, 0, 0);
    __syncthreads();
  }

#pragma unroll
  for (int i = 0; i < 4; ++i) {
#pragma unroll
    for (int j = 0; j < 4; ++j) {
      int n = n0 + wc + j * 16 + lr;
#pragma unroll
      for (int r = 0; r < 4; ++r) {
        int m = m0 + wr + i * 16 + lq * 4 + r;
        float v = acc[i][j][r];
        if (MODE == 0) {
          // z=0 (Q): fold 1/sqrt(64) AND log2e so QK^T lands in log2 domain
          v = (v + bias[n]) * (z == 0 ? 0.18033688f : 1.0f);
          int b = m >> 11, s = m & 2047, h = n >> 6, d = n & 63;
          obf[(size_t)((b * 16 + h) * 2048 + s) * 64 + d] = f2bf(v);
        } else if (MODE == 2) {
          v = (v + bias[m]) * resid[n];  // resid = EMf, n = b*2048+s
          int b = n >> 11, s = n & 2047;
          obf[(size_t)(b * 1024 + m) * 2048 + s] = f2bf(v);
        } else {
          v = v + bias[n] + resid[(size_t)m * 1024 + n];
          of[(size_t)m * 1024 + n] = v;
        }
      }
    }
  }
}

// ---------------------------------------------------------------------------
// Flash attention, swapped-QK^T 32x32, max-free softmax, QBLK=256.
// Grid 512 (= 64 bh * 8 q-tiles), 256 threads (4 waves), wave owns 64 q
// (2 q-groups of 32). K/V/E fragments read once per tile, feed both q-groups.
__global__ __launch_bounds__(256, 2) void attn_kernel(
    const unsigned short* __restrict__ Qg, const unsigned short* __restrict__ Kg,
    const unsigned short* __restrict__ Vtg, const unsigned short* __restrict__ EMb,
    unsigned short* __restrict__ ctx)
{
  // smem: Ks[2][8192] | Vs[2][8192] | Es[2][128]; epilogue reuses 0..32K
  __shared__ __align__(16) char smem[33280];

  const int id = blockIdx.x;
  const int swz = (id & 7) * 64 + (id >> 3);  // bijective XCD swizzle (512/8)
  const int bh = swz >> 3, qt = swz & 7;
  const int b = bh >> 4, h = bh & 15;

  const int tid = threadIdx.x, lane = tid & 63, wid = tid >> 6;
  const int l31 = lane & 31, hi = lane >> 5;
  const int q0 = qt * 256 + wid * 64;
  const size_t head = (size_t)bh * (2048 * 64);
  const unsigned short* Kh = Kg + head;
  const unsigned short* Vh = Vtg + (size_t)bh * 64 * 2048;
  const unsigned short* emrow = EMb + (size_t)b * 2048;

  // Q B-fragments: col q = q0 + qg*32 + l31, d = ds*16 + 8*hi + j
  bf16x8_t qf[2][4];
#pragma unroll
  for (int qg = 0; qg < 2; ++qg) {
    const unsigned short* qp = Qg + head + (size_t)(q0 + qg * 32 + l31) * 64 + 8 * hi;
#pragma unroll
    for (int ds = 0; ds < 4; ++ds) qf[qg][ds] = *(const bf16x8_t*)(qp + ds * 16);
  }

  f32x16_t oaccA[2] = {}, oaccB[2] = {};  // O^T[d,q]: d 0-31 / 32-63 per qg
  f32x16_t lacc[2] = {};                  // denominators; read [0] at end

  const int sw_row = (l31 & 7) << 4;

  auto STAGE = [&](int t, int p) {
    const int k0 = t * 64;
    char* kd = smem + p * 8192;
    char* vd = smem + 16384 + p * 8192;
#pragma unroll
    for (int r = 0; r < 2; ++r) {
      int oo = tid * 16 + r * 4096;
      int row = oo >> 7, cb = oo & 127;
      int scb = cb ^ ((row & 7) << 4);  // inverse swizzle on global source
      gld16((const char*)(Kh + (size_t)(k0 + row) * 64) + scb, kd + oo);
      gld16((const char*)(Vh + (size_t)row * 2048 + k0) + scb, vd + oo);
    }
    if (tid < 8)
      gld16((const char*)(emrow + k0 + tid * 8), smem + 32768 + p * 128 + tid * 16);
  };

  STAGE(0, 0);
  __syncthreads();

  for (int t = 0; t < 32; ++t) {
    const int p = t & 1;
    if (t < 31) STAGE(t + 1, p ^ 1);

    const char* kb = smem + p * 8192;
    const char* vb = smem + 16384 + p * 8192;
    const char* eb = smem + 32768 + p * 128;

    // ---- S^T = K . Q^T (log2 domain): c0 = k 0-31, c1 = k 32-63, per qg
    f32x16_t c0[2] = {}, c1[2] = {};
    {
      const char* kr0 = kb + l31 * 128;
      const char* kr1 = kb + (32 + l31) * 128;
      __builtin_amdgcn_s_setprio(1);
#pragma unroll
      for (int ds = 0; ds < 4; ++ds) {
        int cc = (ds * 32 + 16 * hi) ^ sw_row;
        bf16x8_t k0f = *(const bf16x8_t*)(kr0 + cc);
        bf16x8_t k1f = *(const bf16x8_t*)(kr1 + cc);
#pragma unroll
        for (int qg = 0; qg < 2; ++qg) {
          c0[qg] = __builtin_amdgcn_mfma_f32_32x32x16_bf16(k0f, qf[qg][ds], c0[qg], 0, 0, 0);
          c1[qg] = __builtin_amdgcn_mfma_f32_32x32x16_bf16(k1f, qf[qg][ds], c1[qg], 0, 0, 0);
        }
      }
      __builtin_amdgcn_s_setprio(0);
    }

    // ---- P = exp2(c) raw (max-free), pack bf16, permlane partner exchange
    bf16x8_t pf[2][4];
#pragma unroll
    for (int qg = 0; qg < 2; ++qg) {
      uint32_t w0[8], w1[8];
#pragma unroll
      for (int g = 0; g < 8; ++g) {
        const int i4 = (g & 3) * 4;
        if (g < 4) {
          w0[g] = cvtpk(ex2(c0[qg][i4]), ex2(c0[qg][i4 + 1]));
          w1[g] = cvtpk(ex2(c0[qg][i4 + 2]), ex2(c0[qg][i4 + 3]));
        } else {
          w0[g] = cvtpk(ex2(c1[qg][i4]), ex2(c1[qg][i4 + 1]));
          w1[g] = cvtpk(ex2(c1[qg][i4 + 2]), ex2(c1[qg][i4 + 3]));
        }
      }
#pragma unroll
      for (int ks = 0; ks < 4; ++ks) {
        const int gg = ((ks >> 1) << 2) + ((ks & 1) << 1);
        uint32_t a0 = w0[gg], b0 = w0[gg + 1];
        uint32_t a1 = w1[gg], b1 = w1[gg + 1];
        plswap(a0, b0);
        plswap(a1, b1);
        union { uint32_t u[4]; bf16x8_t v; } cv;
        cv.u[0] = a0; cv.u[1] = a1; cv.u[2] = b0; cv.u[3] = b1;
        pf[qg][ks] = cv.v;
      }
    }

    // ---- PV (O^T += Vt.P^T) and l (lacc += EM.P^T), frags shared across qg
    {
      const char* vr0 = vb + l31 * 128;
      const char* vr1 = vb + (32 + l31) * 128;
      __builtin_amdgcn_s_setprio(1);
#pragma unroll
      for (int ks = 0; ks < 4; ++ks) {
        bf16x8_t ef = *(const bf16x8_t*)(eb + ks * 32 + 16 * hi);
        int cc = (ks * 32 + 16 * hi) ^ sw_row;
        bf16x8_t v0f = *(const bf16x8_t*)(vr0 + cc);
        bf16x8_t v1f = *(const bf16x8_t*)(vr1 + cc);
#pragma unroll
        for (int qg = 0; qg < 2; ++qg) {
          oaccA[qg] = __builtin_amdgcn_mfma_f32_32x32x16_bf16(v0f, pf[qg][ks], oaccA[qg], 0, 0, 0);
          oaccB[qg] = __builtin_amdgcn_mfma_f32_32x32x16_bf16(v1f, pf[qg][ks], oaccB[qg], 0, 0, 0);
          lacc[qg]  = __builtin_amdgcn_mfma_f32_32x32x16_bf16(ef,  pf[qg][ks], lacc[qg],  0, 0, 0);
        }
      }
      __builtin_amdgcn_s_setprio(0);
    }
    __syncthreads();
  }

  // ---- epilogue: O^T -> LDS (swizzled) -> coalesced global store
  char* tb = smem + wid * 8192;  // per-wave 64q x 128B, reuses K/V buffers
#pragma unroll
  for (int qg = 0; qg < 2; ++qg) {
    const float inv = 1.0f / lacc[qg][0];
    char* trow = tb + qg * 4096 + l31 * 128;
    const int swq = (l31 & 7) << 4;
#pragma unroll
    for (int g2 = 0; g2 < 4; ++g2) {
      uint2 a0, a1;
      a0.x = cvtpk(oaccA[qg][4 * g2] * inv, oaccA[qg][4 * g2 + 1] * inv);
      a0.y = cvtpk(oaccA[qg][4 * g2 + 2] * inv, oaccA[qg][4 * g2 + 3] * inv);
      a1.x = cvtpk(oaccB[qg][4 * g2] * inv, oaccB[qg][4 * g2 + 1] * inv);
      a1.y = cvtpk(oaccB[qg][4 * g2 + 2] * inv, oaccB[qg][4 * g2 + 3] * inv);
      int d0 = 16 * g2 + 8 * hi;
      *(uint2*)(trow + ((d0) ^ swq)) = a0;
      *(uint2*)(trow + ((d0 + 64) ^ swq)) = a1;
    }
  }
#pragma unroll
  for (int half = 0; half < 2; ++half) {
    const int qq = half * 32 + (lane >> 1), cp = lane & 1;
    const char* trow = tb + qq * 128;
    const int swr = (qq & 7) << 4;
    unsigned short* op = ctx + ((size_t)(b * 2048 + q0 + qq)) * 1024 + h * 64 + cp * 32;
#pragma unroll
    for (int i = 0; i < 4; ++i) {
      int col = cp * 64 + i * 16;
      u32x4_t val = *(const u32x4_t*)(trow + (col ^ swr));
      *(u32x4_t*)(op + i * 8) = val;
    }
  }
}

// ---------------------------------------------------------------------------
__global__ __launch_bounds__(256) void ln_kernel(
    float* __restrict__ y, const float* __restrict__ g, const float* __restrict__ be)
{
  const int row = blockIdx.x, tid = threadIdx.x;
  float* rp = y + (size_t)row * 1024;
  float4 x = *(const float4*)(rp + tid * 4);
  float s = x.x + x.y + x.z + x.w;
  float sq = x.x * x.x + x.y * x.y + x.z * x.z + x.w * x.w;
#pragma unroll
  for (int msk = 1; msk < 64; msk <<= 1) {
    s  += __shfl_xor(s, msk);
    sq += __shfl_xor(sq, msk);
  }
  __shared__ float red[8];
  const int wid = tid >> 6, lane = tid & 63;
  if (lane == 0) { red[wid] = s; red[4 + wid] = sq; }
  __syncthreads();
  s  = red[0] + red[1] + red[2] + red[3];
  sq = red[4] + red[5] + red[6] + red[7];
  float mu = s * (1.f / 1024.f);
  float var = sq * (1.f / 1024.f) - mu * mu;
  float rs = rsqrtf(var + 1e-12f);
  float4 gw = *(const float4*)(g + tid * 4);
  float4 bw = *(const float4*)(be + tid * 4);
  float4 o2;
  o2.x = (x.x - mu) * rs * gw.x + bw.x;
  o2.y = (x.y - mu) * rs * gw.y + bw.y;
  o2.z = (x.z - mu) * rs * gw.z + bw.z;
  o2.w = (x.w - mu) * rs * gw.w + bw.w;
  *(float4*)(rp + tid * 4) = o2;
}

// ---------------------------------------------------------------------------
extern "C" void kernel_launch(void* const* d_in, const int* in_sizes, int n_in,
                              void* d_out, int out_size, void* d_ws, size_t ws_size,
                              hipStream_t stream)
{
  const float* x    = (const float*)d_in[0];
  const float* mask = (const float*)d_in[1];
  const float* wq   = (const float*)d_in[2];
  const float* bq   = (const float*)d_in[3];
  const float* wk   = (const float*)d_in[4];
  const float* bk   = (const float*)d_in[5];
  const float* wv   = (const float*)d_in[6];
  const float* bv   = (const float*)d_in[7];
  const float* wo   = (const float*)d_in[8];
  const float* bo   = (const float*)d_in[9];
  const float* lnw  = (const float*)d_in[10];
  const float* lnb  = (const float*)d_in[11];
  float* out = (float*)d_out;

  char* ws = (char*)d_ws;
  unsigned short* Xb  = (unsigned short*)(ws);                               // 16 MB
  unsigned short* Wqb = (unsigned short*)(ws + 16777216);                    // 2 MB
  unsigned short* Wkb = (unsigned short*)(ws + 16777216 + 2097152);
  unsigned short* Wvb = (unsigned short*)(ws + 16777216 + 2 * 2097152);
  unsigned short* Wob = (unsigned short*)(ws + 16777216 + 3 * 2097152);
  unsigned short* Qg  = (unsigned short*)(ws + 25165824);                    // [B,H,S,D]
  unsigned short* Kg  = (unsigned short*)(ws + 25165824 + 16777216);         // [B,H,S,D]
  unsigned short* Vtg = (unsigned short*)(ws + 25165824 + 2 * 16777216);     // [B,H,D,S]
  unsigned short* CTX = (unsigned short*)(ws + 25165824 + 3 * 16777216);     // [B,S,E]
  float*          EMf = (float*)(ws + 92274688);                             // 32 KB
  unsigned short* EMb = (unsigned short*)(ws + 92274688 + 32768);            // 16 KB

  cast_all<<<dim3(6148), 256, 0, stream>>>(x, wq, wk, wv, wo, mask,
                                           Xb, Wqb, Wkb, Wvb, Wob, EMf, EMb);
  gemm_bt<0><<<dim3(64, 8, 2), 256, 0, stream>>>(Xb, Wqb, Wkb, bq, bk, nullptr,
                                                 Qg, Kg, nullptr, 8192, 1024, 1024);
  gemm_bt<2><<<dim3(8, 64, 1), 256, 0, stream>>>(Wvb, Xb, nullptr, bv, nullptr, EMf,
                                                 Vtg, nullptr, nullptr, 1024, 8192, 1024);
  attn_kernel<<<dim3(512), 256, 0, stream>>>(Qg, Kg, Vtg, EMb, CTX);
  gemm_bt<3><<<dim3(64, 8, 1), 256, 0, stream>>>(CTX, Wob, nullptr, bo, nullptr, x,
                                                 nullptr, nullptr, out, 8192, 1024, 1024);
  ln_kernel<<<dim3(8192), 256, 0, stream>>>(out, lnw, lnb);
}

// Round 6
// 227.807 us; speedup vs baseline: 2.1473x; 1.0118x over previous
//
#include <hip/hip_runtime.h>
#include <hip/hip_bf16.h>
#include <stdint.h>

// ---------------------------------------------------------------------------
// MultiHeadSelfAttention fused block, MI355X/gfx950, bf16 MFMA pipeline.
// B=4 S=2048 E=1024 H=16 D=64.
// R5: attn KBLK 64->128 (two independent sub-tile bodies per staged chunk:
// sub1 QK (MFMA pipe) overlaps sub0 softmax (VALU pipe); barriers 32->16).
// Attn was latency/barrier-bound: all pipes <=23us of an 88.5us wall.
// ---------------------------------------------------------------------------

typedef short bf16x8_t __attribute__((ext_vector_type(8)));
typedef float f32x4_t __attribute__((ext_vector_type(4)));
typedef float f32x16_t __attribute__((ext_vector_type(16)));
typedef unsigned short u16x8_t __attribute__((ext_vector_type(8)));
typedef uint32_t u32x4_t __attribute__((ext_vector_type(4)));

#define DEV static __device__ __forceinline__

DEV unsigned short f2bf(float f) {  // RNE f32->bf16
  union { float f; uint32_t u; } v; v.f = f;
  uint32_t u = v.u;
  return (unsigned short)((u + 0x7fffu + ((u >> 16) & 1u)) >> 16);
}

DEV uint32_t cvtpk(float a, float b) {  // packed {lo=a, hi=b} bf16, RNE
  uint32_t d;
  asm("v_cvt_pk_bf16_f32 %0, %1, %2" : "=v"(d) : "v"(a), "v"(b));
  return d;
}

// swap: a <- {a.lo_lanes, b.lo_lanes}, b <- {a.hi_lanes, b.hi_lanes}
DEV void plswap(uint32_t& a, uint32_t& b) {
  asm("v_permlane32_swap_b32 %0, %1" : "+v"(a), "+v"(b));
}

DEV float ex2(float x) { return __builtin_amdgcn_exp2f(x); }

typedef const __attribute__((address_space(1))) void* gp_t;
typedef __attribute__((address_space(3))) void* lp_t;

DEV void gld16(const void* g, void* l) {  // async global->LDS, 16B/lane
  __builtin_amdgcn_global_load_lds((gp_t)g, (lp_t)l, 16, 0, 0);
}

// ---------------------------------------------------------------------------
// Flat exact grid: X 4096 | Wq 512 | Wk 512 | Wv 512 | Wo 512 | mask 4 = 6148
__global__ __launch_bounds__(256) void cast_all(
    const float* __restrict__ x,
    const float* __restrict__ wq, const float* __restrict__ wk,
    const float* __restrict__ wv, const float* __restrict__ wo,
    const float* __restrict__ mask,
    unsigned short* __restrict__ xb,
    unsigned short* __restrict__ wqb, unsigned short* __restrict__ wkb,
    unsigned short* __restrict__ wvb, unsigned short* __restrict__ wob,
    float* __restrict__ emf, unsigned short* __restrict__ emb)
{
  const int cid = blockIdx.x;
  if (cid >= 6144) {  // EM = exp(mask): f32 (Vt fold) + bf16 (l-MFMA A-op)
    int i = ((cid - 6144) * 256 + (int)threadIdx.x) * 8;
    float4 a = *(const float4*)(mask + i);
    float4 b = *(const float4*)(mask + i + 4);
    const float C = 1.44269504f;
    float4 ea, eb;
    ea.x = ex2(a.x * C); ea.y = ex2(a.y * C); ea.z = ex2(a.z * C); ea.w = ex2(a.w * C);
    eb.x = ex2(b.x * C); eb.y = ex2(b.y * C); eb.z = ex2(b.z * C); eb.w = ex2(b.w * C);
    *(float4*)(emf + i) = ea;
    *(float4*)(emf + i + 4) = eb;
    u16x8_t o;
    o[0] = f2bf(ea.x); o[1] = f2bf(ea.y); o[2] = f2bf(ea.z); o[3] = f2bf(ea.w);
    o[4] = f2bf(eb.x); o[5] = f2bf(eb.y); o[6] = f2bf(eb.z); o[7] = f2bf(eb.w);
    *(u16x8_t*)(emb + i) = o;
    return;
  }
  const float* src; unsigned short* dst; int base;
  if (cid < 4096)      { src = x;  dst = xb;  base = cid; }
  else if (cid < 4608) { src = wq; dst = wqb; base = cid - 4096; }
  else if (cid < 5120) { src = wk; dst = wkb; base = cid - 4608; }
  else if (cid < 5632) { src = wv; dst = wvb; base = cid - 5120; }
  else                 { src = wo; dst = wob; base = cid - 5632; }
  int i = (base * 256 + (int)threadIdx.x) * 8;
  float4 a = *(const float4*)(src + i);
  float4 b = *(const float4*)(src + i + 4);
  u16x8_t o;
  o[0] = f2bf(a.x); o[1] = f2bf(a.y); o[2] = f2bf(a.z); o[3] = f2bf(a.w);
  o[4] = f2bf(b.x); o[5] = f2bf(b.y); o[6] = f2bf(b.z); o[7] = f2bf(b.w);
  *(u16x8_t*)(dst + i) = o;
}

// ---------------------------------------------------------------------------
// C[m,n] = sum_k A[m,k]*B[n,k]. 128x128 tile, BK=32, 4 waves, 16x16x32 MFMA.
// MODE 0: QK proj (z=0: Q scaled log2e/8; z=1: K), out bf16 [B,H,S,D]
// MODE 2: Vt (A=Wv rows e, B=X rows (b,s)), out bf16 [B,H,D,S] * EM (resid=EMf)
// MODE 3: WO + bias + residual, out f32 [M,N]
template<int MODE>
__global__ __launch_bounds__(256) void gemm_bt(
    const unsigned short* __restrict__ A,
    const unsigned short* __restrict__ B0, const unsigned short* __restrict__ B1,
    const float* __restrict__ bias0, const float* __restrict__ bias1,
    const float* __restrict__ resid,
    unsigned short* __restrict__ o0, unsigned short* __restrict__ o1,
    float* __restrict__ of,
    int M, int N, int K)
{
  __shared__ unsigned short As[128 * 32];
  __shared__ unsigned short Bs[128 * 32];

  const int z = blockIdx.z;
  const unsigned short* Bw = (MODE == 0 && z == 1) ? B1 : B0;
  const float* bias = (MODE == 0 && z == 1) ? bias1 : bias0;
  unsigned short* obf = (MODE == 0 && z == 1) ? o1 : o0;

  const int tid = threadIdx.x;
  const int lane = tid & 63;
  const int lr = lane & 15, lq = lane >> 4;
  const int wid = tid >> 6;
  const int m0 = blockIdx.x * 128;
  const int n0 = blockIdx.y * 128;
  const int wr = (wid >> 1) * 64, wc = (wid & 1) * 64;

  f32x4_t acc[4][4] = {};

  const int o = tid * 16;
  for (int kt = 0; kt < K; kt += 32) {
#pragma unroll
    for (int r = 0; r < 2; ++r) {
      int oo = o + r * 4096;
      int row = oo >> 6, cb = oo & 63;
      gld16((const char*)(A  + (size_t)(m0 + row) * K + kt) + cb, (char*)As + oo);
      gld16((const char*)(Bw + (size_t)(n0 + row) * K + kt) + cb, (char*)Bs + oo);
    }
    __syncthreads();
    bf16x8_t aF[4], bF[4];
    const int koff = lq * 16;
#pragma unroll
    for (int i = 0; i < 4; ++i) {
      aF[i] = *(const bf16x8_t*)((const char*)As + (wr + i * 16 + lr) * 64 + koff);
      bF[i] = *(const bf16x8_t*)((const char*)Bs + (wc + i * 16 + lr) * 64 + koff);
    }
#pragma unroll
    for (int i = 0; i < 4; ++i)
#pragma unroll
      for (int j = 0; j < 4; ++j)
        acc[i][j] = __builtin_amdgcn_mfma_f32_16x16x32_bf16(aF[i], bF[j], acc[i][j], 0, 0, 0);
    __syncthreads();
  }

#pragma unroll
  for (int i = 0; i < 4; ++i) {
#pragma unroll
    for (int j = 0; j < 4; ++j) {
      int n = n0 + wc + j * 16 + lr;
#pragma unroll
      for (int r = 0; r < 4; ++r) {
        int m = m0 + wr + i * 16 + lq * 4 + r;
        float v = acc[i][j][r];
        if (MODE == 0) {
          // z=0 (Q): fold 1/sqrt(64) AND log2e so QK^T lands in log2 domain
          v = (v + bias[n]) * (z == 0 ? 0.18033688f : 1.0f);
          int b = m >> 11, s = m & 2047, h = n >> 6, d = n & 63;
          obf[(size_t)((b * 16 + h) * 2048 + s) * 64 + d] = f2bf(v);
        } else if (MODE == 2) {
          v = (v + bias[m]) * resid[n];  // resid = EMf, n = b*2048+s
          int b = n >> 11, s = n & 2047;
          obf[(size_t)(b * 1024 + m) * 2048 + s] = f2bf(v);
        } else {
          v = v + bias[n] + resid[(size_t)m * 1024 + n];
          of[(size_t)m * 1024 + n] = v;
        }
      }
    }
  }
}

// ---------------------------------------------------------------------------
// Flash attention, swapped-QK^T 32x32, max-free softmax, QBLK=256, KBLK=128.
// Grid 512 (= 64 bh * 8 q-tiles), 256 threads (4 waves), wave owns 64 q
// (2 q-groups of 32). Each iteration stages a 128-k chunk and runs TWO
// independent sub-tile bodies (QK/softmax/PV) -> cross-sub MFMA/VALU overlap,
// half the barriers.
__global__ __launch_bounds__(256, 2) void attn_kernel(
    const unsigned short* __restrict__ Qg, const unsigned short* __restrict__ Kg,
    const unsigned short* __restrict__ Vtg, const unsigned short* __restrict__ EMb,
    unsigned short* __restrict__ ctx)
{
  // smem: K[2][16384] | V[2][16384] | E[2][256]; epilogue reuses 0..32K
  __shared__ __align__(16) char smem[66048];

  const int id = blockIdx.x;
  const int swz = (id & 7) * 64 + (id >> 3);  // bijective XCD swizzle (512/8)
  const int bh = swz >> 3, qt = swz & 7;
  const int b = bh >> 4, h = bh & 15;

  const int tid = threadIdx.x, lane = tid & 63, wid = tid >> 6;
  const int l31 = lane & 31, hi = lane >> 5;
  const int q0 = qt * 256 + wid * 64;
  const size_t head = (size_t)bh * (2048 * 64);
  const unsigned short* Kh = Kg + head;
  const unsigned short* Vh = Vtg + (size_t)bh * 64 * 2048;
  const unsigned short* emrow = EMb + (size_t)b * 2048;

  // Q B-fragments: col q = q0 + qg*32 + l31, d = ds*16 + 8*hi + j
  bf16x8_t qf[2][4];
#pragma unroll
  for (int qg = 0; qg < 2; ++qg) {
    const unsigned short* qp = Qg + head + (size_t)(q0 + qg * 32 + l31) * 64 + 8 * hi;
#pragma unroll
    for (int ds = 0; ds < 4; ++ds) qf[qg][ds] = *(const bf16x8_t*)(qp + ds * 16);
  }

  f32x16_t oaccA[2] = {}, oaccB[2] = {};  // O^T[d,q]: d 0-31 / 32-63 per qg
  f32x16_t lacc[2] = {};                  // denominators; read [0] at end

  const int sw_row = (l31 & 7) << 4;

  // stage 128-k chunk t into buffer p: K[128 rows][128B], V[64 rows][256B]
  auto STAGE = [&](int t, int p) {
    const int k0 = t * 128;
    char* kd = smem + p * 16384;
    char* vd = smem + 32768 + p * 16384;
#pragma unroll
    for (int r = 0; r < 4; ++r) {
      int oo = tid * 16 + r * 4096;
      {  // K: row = k (stride 128B), inverse swizzle on source
        int row = oo >> 7, cb = oo & 127;
        int scb = cb ^ ((row & 7) << 4);
        gld16((const char*)(Kh + (size_t)(k0 + row) * 64) + scb, kd + oo);
      }
      {  // V: row = d (stride 256B), inverse swizzle on source
        int row = oo >> 8, cb = oo & 255;
        int scb = cb ^ ((row & 7) << 4);
        gld16((const char*)(Vh + (size_t)row * 2048 + k0) + scb, vd + oo);
      }
    }
    if (tid < 16)
      gld16((const char*)(emrow + k0 + tid * 8), smem + 65536 + p * 256 + tid * 16);
  };

  STAGE(0, 0);
  __syncthreads();

  for (int t = 0; t < 16; ++t) {
    const int p = t & 1;
    if (t < 15) STAGE(t + 1, p ^ 1);

    const char* kb = smem + p * 16384;
    const char* vb = smem + 32768 + p * 16384;
    const char* eb = smem + 65536 + p * 256;

#pragma unroll
    for (int s = 0; s < 2; ++s) {  // two independent 64-k sub-tiles
      // ---- S^T = K . Q^T (log2 domain): c0 = k 0-31, c1 = k 32-63, per qg
      f32x16_t c0[2] = {}, c1[2] = {};
      {
        const char* kr0 = kb + s * 8192 + l31 * 128;
        const char* kr1 = kb + s * 8192 + (32 + l31) * 128;
        __builtin_amdgcn_s_setprio(1);
#pragma unroll
        for (int ds = 0; ds < 4; ++ds) {
          int cc = (ds * 32 + 16 * hi) ^ sw_row;
          bf16x8_t k0f = *(const bf16x8_t*)(kr0 + cc);
          bf16x8_t k1f = *(const bf16x8_t*)(kr1 + cc);
#pragma unroll
          for (int qg = 0; qg < 2; ++qg) {
            c0[qg] = __builtin_amdgcn_mfma_f32_32x32x16_bf16(k0f, qf[qg][ds], c0[qg], 0, 0, 0);
            c1[qg] = __builtin_amdgcn_mfma_f32_32x32x16_bf16(k1f, qf[qg][ds], c1[qg], 0, 0, 0);
          }
        }
        __builtin_amdgcn_s_setprio(0);
      }

      // ---- P = exp2(c) raw (max-free), pack bf16, permlane partner exchange
      bf16x8_t pf[2][4];
#pragma unroll
      for (int qg = 0; qg < 2; ++qg) {
        uint32_t w0[8], w1[8];
#pragma unroll
        for (int g = 0; g < 8; ++g) {
          const int i4 = (g & 3) * 4;
          if (g < 4) {
            w0[g] = cvtpk(ex2(c0[qg][i4]), ex2(c0[qg][i4 + 1]));
            w1[g] = cvtpk(ex2(c0[qg][i4 + 2]), ex2(c0[qg][i4 + 3]));
          } else {
            w0[g] = cvtpk(ex2(c1[qg][i4]), ex2(c1[qg][i4 + 1]));
            w1[g] = cvtpk(ex2(c1[qg][i4 + 2]), ex2(c1[qg][i4 + 3]));
          }
        }
#pragma unroll
        for (int ks = 0; ks < 4; ++ks) {
          const int gg = ((ks >> 1) << 2) + ((ks & 1) << 1);
          uint32_t a0 = w0[gg], b0 = w0[gg + 1];
          uint32_t a1 = w1[gg], b1 = w1[gg + 1];
          plswap(a0, b0);
          plswap(a1, b1);
          union { uint32_t u[4]; bf16x8_t v; } cv;
          cv.u[0] = a0; cv.u[1] = a1; cv.u[2] = b0; cv.u[3] = b1;
          pf[qg][ks] = cv.v;
        }
      }

      // ---- PV (O^T += Vt.P^T) and l (lacc += EM.P^T), frags shared across qg
      {
        const char* vr0 = vb + l31 * 256 + s * 128;
        const char* vr1 = vb + (32 + l31) * 256 + s * 128;
        const char* ebs = eb + s * 128;
        __builtin_amdgcn_s_setprio(1);
#pragma unroll
        for (int ks = 0; ks < 4; ++ks) {
          bf16x8_t ef = *(const bf16x8_t*)(ebs + ks * 32 + 16 * hi);
          int cc = (ks * 32 + 16 * hi) ^ sw_row;
          bf16x8_t v0f = *(const bf16x8_t*)(vr0 + cc);
          bf16x8_t v1f = *(const bf16x8_t*)(vr1 + cc);
#pragma unroll
          for (int qg = 0; qg < 2; ++qg) {
            oaccA[qg] = __builtin_amdgcn_mfma_f32_32x32x16_bf16(v0f, pf[qg][ks], oaccA[qg], 0, 0, 0);
            oaccB[qg] = __builtin_amdgcn_mfma_f32_32x32x16_bf16(v1f, pf[qg][ks], oaccB[qg], 0, 0, 0);
            lacc[qg]  = __builtin_amdgcn_mfma_f32_32x32x16_bf16(ef,  pf[qg][ks], lacc[qg],  0, 0, 0);
          }
        }
        __builtin_amdgcn_s_setprio(0);
      }
    }
    __syncthreads();
  }

  // ---- epilogue: O^T -> LDS (swizzled) -> coalesced global store
  char* tb = smem + wid * 8192;  // per-wave 64q x 128B, reuses K buffers
#pragma unroll
  for (int qg = 0; qg < 2; ++qg) {
    const float inv = 1.0f / lacc[qg][0];
    char* trow = tb + qg * 4096 + l31 * 128;
    const int swq = (l31 & 7) << 4;
#pragma unroll
    for (int g2 = 0; g2 < 4; ++g2) {
      uint2 a0, a1;
      a0.x = cvtpk(oaccA[qg][4 * g2] * inv, oaccA[qg][4 * g2 + 1] * inv);
      a0.y = cvtpk(oaccA[qg][4 * g2 + 2] * inv, oaccA[qg][4 * g2 + 3] * inv);
      a1.x = cvtpk(oaccB[qg][4 * g2] * inv, oaccB[qg][4 * g2 + 1] * inv);
      a1.y = cvtpk(oaccB[qg][4 * g2 + 2] * inv, oaccB[qg][4 * g2 + 3] * inv);
      int d0 = 16 * g2 + 8 * hi;
      *(uint2*)(trow + ((d0) ^ swq)) = a0;
      *(uint2*)(trow + ((d0 + 64) ^ swq)) = a1;
    }
  }
#pragma unroll
  for (int half = 0; half < 2; ++half) {
    const int qq = half * 32 + (lane >> 1), cp = lane & 1;
    const char* trow = tb + qq * 128;
    const int swr = (qq & 7) << 4;
    unsigned short* op = ctx + ((size_t)(b * 2048 + q0 + qq)) * 1024 + h * 64 + cp * 32;
#pragma unroll
    for (int i = 0; i < 4; ++i) {
      int col = cp * 64 + i * 16;
      u32x4_t val = *(const u32x4_t*)(trow + (col ^ swr));
      *(u32x4_t*)(op + i * 8) = val;
    }
  }
}

// ---------------------------------------------------------------------------
__global__ __launch_bounds__(256) void ln_kernel(
    float* __restrict__ y, const float* __restrict__ g, const float* __restrict__ be)
{
  const int row = blockIdx.x, tid = threadIdx.x;
  float* rp = y + (size_t)row * 1024;
  float4 x = *(const float4*)(rp + tid * 4);
  float s = x.x + x.y + x.z + x.w;
  float sq = x.x * x.x + x.y * x.y + x.z * x.z + x.w * x.w;
#pragma unroll
  for (int msk = 1; msk < 64; msk <<= 1) {
    s  += __shfl_xor(s, msk);
    sq += __shfl_xor(sq, msk);
  }
  __shared__ float red[8];
  const int wid = tid >> 6, lane = tid & 63;
  if (lane == 0) { red[wid] = s; red[4 + wid] = sq; }
  __syncthreads();
  s  = red[0] + red[1] + red[2] + red[3];
  sq = red[4] + red[5] + red[6] + red[7];
  float mu = s * (1.f / 1024.f);
  float var = sq * (1.f / 1024.f) - mu * mu;
  float rs = rsqrtf(var + 1e-12f);
  float4 gw = *(const float4*)(g + tid * 4);
  float4 bw = *(const float4*)(be + tid * 4);
  float4 o2;
  o2.x = (x.x - mu) * rs * gw.x + bw.x;
  o2.y = (x.y - mu) * rs * gw.y + bw.y;
  o2.z = (x.z - mu) * rs * gw.z + bw.z;
  o2.w = (x.w - mu) * rs * gw.w + bw.w;
  *(float4*)(rp + tid * 4) = o2;
}

// ---------------------------------------------------------------------------
extern "C" void kernel_launch(void* const* d_in, const int* in_sizes, int n_in,
                              void* d_out, int out_size, void* d_ws, size_t ws_size,
                              hipStream_t stream)
{
  const float* x    = (const float*)d_in[0];
  const float* mask = (const float*)d_in[1];
  const float* wq   = (const float*)d_in[2];
  const float* bq   = (const float*)d_in[3];
  const float* wk   = (const float*)d_in[4];
  const float* bk   = (const float*)d_in[5];
  const float* wv   = (const float*)d_in[6];
  const float* bv   = (const float*)d_in[7];
  const float* wo   = (const float*)d_in[8];
  const float* bo   = (const float*)d_in[9];
  const float* lnw  = (const float*)d_in[10];
  const float* lnb  = (const float*)d_in[11];
  float* out = (float*)d_out;

  char* ws = (char*)d_ws;
  unsigned short* Xb  = (unsigned short*)(ws);                               // 16 MB
  unsigned short* Wqb = (unsigned short*)(ws + 16777216);                    // 2 MB
  unsigned short* Wkb = (unsigned short*)(ws + 16777216 + 2097152);
  unsigned short* Wvb = (unsigned short*)(ws + 16777216 + 2 * 2097152);
  unsigned short* Wob = (unsigned short*)(ws + 16777216 + 3 * 2097152);
  unsigned short* Qg  = (unsigned short*)(ws + 25165824);                    // [B,H,S,D]
  unsigned short* Kg  = (unsigned short*)(ws + 25165824 + 16777216);         // [B,H,S,D]
  unsigned short* Vtg = (unsigned short*)(ws + 25165824 + 2 * 16777216);     // [B,H,D,S]
  unsigned short* CTX = (unsigned short*)(ws + 25165824 + 3 * 16777216);     // [B,S,E]
  float*          EMf = (float*)(ws + 92274688);                             // 32 KB
  unsigned short* EMb = (unsigned short*)(ws + 92274688 + 32768);            // 16 KB

  cast_all<<<dim3(6148), 256, 0, stream>>>(x, wq, wk, wv, wo, mask,
                                           Xb, Wqb, Wkb, Wvb, Wob, EMf, EMb);
  gemm_bt<0><<<dim3(64, 8, 2), 256, 0, stream>>>(Xb, Wqb, Wkb, bq, bk, nullptr,
                                                 Qg, Kg, nullptr, 8192, 1024, 1024);
  gemm_bt<2><<<dim3(8, 64, 1), 256, 0, stream>>>(Wvb, Xb, nullptr, bv, nullptr, EMf,
                                                 Vtg, nullptr, nullptr, 1024, 8192, 1024);
  attn_kernel<<<dim3(512), 256, 0, stream>>>(Qg, Kg, Vtg, EMb, CTX);
  gemm_bt<3><<<dim3(64, 8, 1), 256, 0, stream>>>(CTX, Wob, nullptr, bo, nullptr, x,
                                                 nullptr, nullptr, out, 8192, 1024, 1024);
  ln_kernel<<<dim3(8192), 256, 0, stream>>>(out, lnw, lnb);
}

// Round 7
// 216.679 us; speedup vs baseline: 2.2576x; 1.0514x over previous
//
#include <hip/hip_runtime.h>
#include <hip/hip_bf16.h>
#include <stdint.h>

// ---------------------------------------------------------------------------
// MultiHeadSelfAttention fused block, MI355X/gfx950, bf16 MFMA pipeline.
// B=4 S=2048 E=1024 H=16 D=64.
// R6: GEMMs upgraded to T3-minimum 2-phase: double-buffered LDS, STAGE(t+1)
// issued BEFORE compute(t), ONE barrier/iter (its vmcnt(0) drain now sits a
// full compute-phase after load issue -> HBM latency hidden in-wave).
// Attn untouched (MFMA pipe 44% busy; latency-bound at 2 waves/SIMD).
// ---------------------------------------------------------------------------

typedef short bf16x8_t __attribute__((ext_vector_type(8)));
typedef float f32x4_t __attribute__((ext_vector_type(4)));
typedef float f32x16_t __attribute__((ext_vector_type(16)));
typedef unsigned short u16x8_t __attribute__((ext_vector_type(8)));
typedef uint32_t u32x4_t __attribute__((ext_vector_type(4)));

#define DEV static __device__ __forceinline__

DEV unsigned short f2bf(float f) {  // RNE f32->bf16
  union { float f; uint32_t u; } v; v.f = f;
  uint32_t u = v.u;
  return (unsigned short)((u + 0x7fffu + ((u >> 16) & 1u)) >> 16);
}

DEV uint32_t cvtpk(float a, float b) {  // packed {lo=a, hi=b} bf16, RNE
  uint32_t d;
  asm("v_cvt_pk_bf16_f32 %0, %1, %2" : "=v"(d) : "v"(a), "v"(b));
  return d;
}

// swap: a <- {a.lo_lanes, b.lo_lanes}, b <- {a.hi_lanes, b.hi_lanes}
DEV void plswap(uint32_t& a, uint32_t& b) {
  asm("v_permlane32_swap_b32 %0, %1" : "+v"(a), "+v"(b));
}

DEV float ex2(float x) { return __builtin_amdgcn_exp2f(x); }

typedef const __attribute__((address_space(1))) void* gp_t;
typedef __attribute__((address_space(3))) void* lp_t;

DEV void gld16(const void* g, void* l) {  // async global->LDS, 16B/lane
  __builtin_amdgcn_global_load_lds((gp_t)g, (lp_t)l, 16, 0, 0);
}

// ---------------------------------------------------------------------------
// Flat exact grid: X 4096 | Wq 512 | Wk 512 | Wv 512 | Wo 512 | mask 4 = 6148
__global__ __launch_bounds__(256) void cast_all(
    const float* __restrict__ x,
    const float* __restrict__ wq, const float* __restrict__ wk,
    const float* __restrict__ wv, const float* __restrict__ wo,
    const float* __restrict__ mask,
    unsigned short* __restrict__ xb,
    unsigned short* __restrict__ wqb, unsigned short* __restrict__ wkb,
    unsigned short* __restrict__ wvb, unsigned short* __restrict__ wob,
    float* __restrict__ emf, unsigned short* __restrict__ emb)
{
  const int cid = blockIdx.x;
  if (cid >= 6144) {  // EM = exp(mask): f32 (Vt fold) + bf16 (l-MFMA A-op)
    int i = ((cid - 6144) * 256 + (int)threadIdx.x) * 8;
    float4 a = *(const float4*)(mask + i);
    float4 b = *(const float4*)(mask + i + 4);
    const float C = 1.44269504f;
    float4 ea, eb;
    ea.x = ex2(a.x * C); ea.y = ex2(a.y * C); ea.z = ex2(a.z * C); ea.w = ex2(a.w * C);
    eb.x = ex2(b.x * C); eb.y = ex2(b.y * C); eb.z = ex2(b.z * C); eb.w = ex2(b.w * C);
    *(float4*)(emf + i) = ea;
    *(float4*)(emf + i + 4) = eb;
    u16x8_t o;
    o[0] = f2bf(ea.x); o[1] = f2bf(ea.y); o[2] = f2bf(ea.z); o[3] = f2bf(ea.w);
    o[4] = f2bf(eb.x); o[5] = f2bf(eb.y); o[6] = f2bf(eb.z); o[7] = f2bf(eb.w);
    *(u16x8_t*)(emb + i) = o;
    return;
  }
  const float* src; unsigned short* dst; int base;
  if (cid < 4096)      { src = x;  dst = xb;  base = cid; }
  else if (cid < 4608) { src = wq; dst = wqb; base = cid - 4096; }
  else if (cid < 5120) { src = wk; dst = wkb; base = cid - 4608; }
  else if (cid < 5632) { src = wv; dst = wvb; base = cid - 5120; }
  else                 { src = wo; dst = wob; base = cid - 5632; }
  int i = (base * 256 + (int)threadIdx.x) * 8;
  float4 a = *(const float4*)(src + i);
  float4 b = *(const float4*)(src + i + 4);
  u16x8_t o;
  o[0] = f2bf(a.x); o[1] = f2bf(a.y); o[2] = f2bf(a.z); o[3] = f2bf(a.w);
  o[4] = f2bf(b.x); o[5] = f2bf(b.y); o[6] = f2bf(b.z); o[7] = f2bf(b.w);
  *(u16x8_t*)(dst + i) = o;
}

// ---------------------------------------------------------------------------
// C[m,n] = sum_k A[m,k]*B[n,k]. 128x128 tile, BK=32, 4 waves, 16x16x32 MFMA.
// 2-phase double-buffered: STAGE(t+1) issued before compute(t), one barrier.
// MODE 0: QK proj (z=0: Q scaled log2e/8; z=1: K), out bf16 [B,H,S,D]
// MODE 2: Vt (A=Wv rows e, B=X rows (b,s)), out bf16 [B,H,D,S] * EM (resid=EMf)
// MODE 3: WO + bias + residual, out f32 [M,N]
template<int MODE>
__global__ __launch_bounds__(256) void gemm_bt(
    const unsigned short* __restrict__ A,
    const unsigned short* __restrict__ B0, const unsigned short* __restrict__ B1,
    const float* __restrict__ bias0, const float* __restrict__ bias1,
    const float* __restrict__ resid,
    unsigned short* __restrict__ o0, unsigned short* __restrict__ o1,
    float* __restrict__ of,
    int M, int N, int K)
{
  __shared__ unsigned short As[2][128 * 32];
  __shared__ unsigned short Bs[2][128 * 32];

  const int z = blockIdx.z;
  const unsigned short* Bw = (MODE == 0 && z == 1) ? B1 : B0;
  const float* bias = (MODE == 0 && z == 1) ? bias1 : bias0;
  unsigned short* obf = (MODE == 0 && z == 1) ? o1 : o0;

  const int tid = threadIdx.x;
  const int lane = tid & 63;
  const int lr = lane & 15, lq = lane >> 4;
  const int wid = tid >> 6;
  const int m0 = blockIdx.x * 128;
  const int n0 = blockIdx.y * 128;
  const int wr = (wid >> 1) * 64, wc = (wid & 1) * 64;

  f32x4_t acc[4][4] = {};

  const int o = tid * 16;
  const int srow = o >> 6, scb = o & 63;   // this thread's stage row/col-byte

  // stage K-chunk at element offset kt into buffer p
  auto STAGE = [&](int kt, int p) {
#pragma unroll
    for (int r = 0; r < 2; ++r) {
      int row = srow + r * 64;
      int oo = o + r * 4096;
      gld16((const char*)(A  + (size_t)(m0 + row) * K + kt) + scb, (char*)As[p] + oo);
      gld16((const char*)(Bw + (size_t)(n0 + row) * K + kt) + scb, (char*)Bs[p] + oo);
    }
  };

  STAGE(0, 0);
  __syncthreads();   // drains vmcnt -> buf0 ready

  int cur = 0;
  for (int kt = 32; kt <= K; kt += 32) {
    if (kt < K) STAGE(kt, cur ^ 1);   // issue next tile BEFORE compute

    bf16x8_t aF[4], bF[4];
    const int koff = lq * 16;
#pragma unroll
    for (int i = 0; i < 4; ++i) {
      aF[i] = *(const bf16x8_t*)((const char*)As[cur] + (wr + i * 16 + lr) * 64 + koff);
      bF[i] = *(const bf16x8_t*)((const char*)Bs[cur] + (wc + i * 16 + lr) * 64 + koff);
    }
#pragma unroll
    for (int i = 0; i < 4; ++i)
#pragma unroll
      for (int j = 0; j < 4; ++j)
        acc[i][j] = __builtin_amdgcn_mfma_f32_16x16x32_bf16(aF[i], bF[j], acc[i][j], 0, 0, 0);

    __syncthreads();   // one barrier/iter: drains this iter's stage (covered by compute)
    cur ^= 1;
  }

#pragma unroll
  for (int i = 0; i < 4; ++i) {
#pragma unroll
    for (int j = 0; j < 4; ++j) {
      int n = n0 + wc + j * 16 + lr;
#pragma unroll
      for (int r = 0; r < 4; ++r) {
        int m = m0 + wr + i * 16 + lq * 4 + r;
        float v = acc[i][j][r];
        if (MODE == 0) {
          // z=0 (Q): fold 1/sqrt(64) AND log2e so QK^T lands in log2 domain
          v = (v + bias[n]) * (z == 0 ? 0.18033688f : 1.0f);
          int b = m >> 11, s = m & 2047, h = n >> 6, d = n & 63;
          obf[(size_t)((b * 16 + h) * 2048 + s) * 64 + d] = f2bf(v);
        } else if (MODE == 2) {
          v = (v + bias[m]) * resid[n];  // resid = EMf, n = b*2048+s
          int b = n >> 11, s = n & 2047;
          obf[(size_t)(b * 1024 + m) * 2048 + s] = f2bf(v);
        } else {
          v = v + bias[n] + resid[(size_t)m * 1024 + n];
          of[(size_t)m * 1024 + n] = v;
        }
      }
    }
  }
}

// ---------------------------------------------------------------------------
// Flash attention, swapped-QK^T 32x32, max-free softmax, QBLK=256, KBLK=128.
// Grid 512 (= 64 bh * 8 q-tiles), 256 threads (4 waves), wave owns 64 q
// (2 q-groups of 32). Each iteration stages a 128-k chunk and runs TWO
// independent sub-tile bodies (QK/softmax/PV).
__global__ __launch_bounds__(256, 2) void attn_kernel(
    const unsigned short* __restrict__ Qg, const unsigned short* __restrict__ Kg,
    const unsigned short* __restrict__ Vtg, const unsigned short* __restrict__ EMb,
    unsigned short* __restrict__ ctx)
{
  // smem: K[2][16384] | V[2][16384] | E[2][256]; epilogue reuses 0..32K
  __shared__ __align__(16) char smem[66048];

  const int id = blockIdx.x;
  const int swz = (id & 7) * 64 + (id >> 3);  // bijective XCD swizzle (512/8)
  const int bh = swz >> 3, qt = swz & 7;
  const int b = bh >> 4, h = bh & 15;

  const int tid = threadIdx.x, lane = tid & 63, wid = tid >> 6;
  const int l31 = lane & 31, hi = lane >> 5;
  const int q0 = qt * 256 + wid * 64;
  const size_t head = (size_t)bh * (2048 * 64);
  const unsigned short* Kh = Kg + head;
  const unsigned short* Vh = Vtg + (size_t)bh * 64 * 2048;
  const unsigned short* emrow = EMb + (size_t)b * 2048;

  // Q B-fragments: col q = q0 + qg*32 + l31, d = ds*16 + 8*hi + j
  bf16x8_t qf[2][4];
#pragma unroll
  for (int qg = 0; qg < 2; ++qg) {
    const unsigned short* qp = Qg + head + (size_t)(q0 + qg * 32 + l31) * 64 + 8 * hi;
#pragma unroll
    for (int ds = 0; ds < 4; ++ds) qf[qg][ds] = *(const bf16x8_t*)(qp + ds * 16);
  }

  f32x16_t oaccA[2] = {}, oaccB[2] = {};  // O^T[d,q]: d 0-31 / 32-63 per qg
  f32x16_t lacc[2] = {};                  // denominators; read [0] at end

  const int sw_row = (l31 & 7) << 4;

  // stage 128-k chunk t into buffer p: K[128 rows][128B], V[64 rows][256B]
  auto STAGE = [&](int t, int p) {
    const int k0 = t * 128;
    char* kd = smem + p * 16384;
    char* vd = smem + 32768 + p * 16384;
#pragma unroll
    for (int r = 0; r < 4; ++r) {
      int oo = tid * 16 + r * 4096;
      {  // K: row = k (stride 128B), inverse swizzle on source
        int row = oo >> 7, cb = oo & 127;
        int scb = cb ^ ((row & 7) << 4);
        gld16((const char*)(Kh + (size_t)(k0 + row) * 64) + scb, kd + oo);
      }
      {  // V: row = d (stride 256B), inverse swizzle on source
        int row = oo >> 8, cb = oo & 255;
        int scb = cb ^ ((row & 7) << 4);
        gld16((const char*)(Vh + (size_t)row * 2048 + k0) + scb, vd + oo);
      }
    }
    if (tid < 16)
      gld16((const char*)(emrow + k0 + tid * 8), smem + 65536 + p * 256 + tid * 16);
  };

  STAGE(0, 0);
  __syncthreads();

  for (int t = 0; t < 16; ++t) {
    const int p = t & 1;
    if (t < 15) STAGE(t + 1, p ^ 1);

    const char* kb = smem + p * 16384;
    const char* vb = smem + 32768 + p * 16384;
    const char* eb = smem + 65536 + p * 256;

#pragma unroll
    for (int s = 0; s < 2; ++s) {  // two independent 64-k sub-tiles
      // ---- S^T = K . Q^T (log2 domain): c0 = k 0-31, c1 = k 32-63, per qg
      f32x16_t c0[2] = {}, c1[2] = {};
      {
        const char* kr0 = kb + s * 8192 + l31 * 128;
        const char* kr1 = kb + s * 8192 + (32 + l31) * 128;
        __builtin_amdgcn_s_setprio(1);
#pragma unroll
        for (int ds = 0; ds < 4; ++ds) {
          int cc = (ds * 32 + 16 * hi) ^ sw_row;
          bf16x8_t k0f = *(const bf16x8_t*)(kr0 + cc);
          bf16x8_t k1f = *(const bf16x8_t*)(kr1 + cc);
#pragma unroll
          for (int qg = 0; qg < 2; ++qg) {
            c0[qg] = __builtin_amdgcn_mfma_f32_32x32x16_bf16(k0f, qf[qg][ds], c0[qg], 0, 0, 0);
            c1[qg] = __builtin_amdgcn_mfma_f32_32x32x16_bf16(k1f, qf[qg][ds], c1[qg], 0, 0, 0);
          }
        }
        __builtin_amdgcn_s_setprio(0);
      }

      // ---- P = exp2(c) raw (max-free), pack bf16, permlane partner exchange
      bf16x8_t pf[2][4];
#pragma unroll
      for (int qg = 0; qg < 2; ++qg) {
        uint32_t w0[8], w1[8];
#pragma unroll
        for (int g = 0; g < 8; ++g) {
          const int i4 = (g & 3) * 4;
          if (g < 4) {
            w0[g] = cvtpk(ex2(c0[qg][i4]), ex2(c0[qg][i4 + 1]));
            w1[g] = cvtpk(ex2(c0[qg][i4 + 2]), ex2(c0[qg][i4 + 3]));
          } else {
            w0[g] = cvtpk(ex2(c1[qg][i4]), ex2(c1[qg][i4 + 1]));
            w1[g] = cvtpk(ex2(c1[qg][i4 + 2]), ex2(c1[qg][i4 + 3]));
          }
        }
#pragma unroll
        for (int ks = 0; ks < 4; ++ks) {
          const int gg = ((ks >> 1) << 2) + ((ks & 1) << 1);
          uint32_t a0 = w0[gg], b0 = w0[gg + 1];
          uint32_t a1 = w1[gg], b1 = w1[gg + 1];
          plswap(a0, b0);
          plswap(a1, b1);
          union { uint32_t u[4]; bf16x8_t v; } cv;
          cv.u[0] = a0; cv.u[1] = a1; cv.u[2] = b0; cv.u[3] = b1;
          pf[qg][ks] = cv.v;
        }
      }

      // ---- PV (O^T += Vt.P^T) and l (lacc += EM.P^T), frags shared across qg
      {
        const char* vr0 = vb + l31 * 256 + s * 128;
        const char* vr1 = vb + (32 + l31) * 256 + s * 128;
        const char* ebs = eb + s * 128;
        __builtin_amdgcn_s_setprio(1);
#pragma unroll
        for (int ks = 0; ks < 4; ++ks) {
          bf16x8_t ef = *(const bf16x8_t*)(ebs + ks * 32 + 16 * hi);
          int cc = (ks * 32 + 16 * hi) ^ sw_row;
          bf16x8_t v0f = *(const bf16x8_t*)(vr0 + cc);
          bf16x8_t v1f = *(const bf16x8_t*)(vr1 + cc);
#pragma unroll
          for (int qg = 0; qg < 2; ++qg) {
            oaccA[qg] = __builtin_amdgcn_mfma_f32_32x32x16_bf16(v0f, pf[qg][ks], oaccA[qg], 0, 0, 0);
            oaccB[qg] = __builtin_amdgcn_mfma_f32_32x32x16_bf16(v1f, pf[qg][ks], oaccB[qg], 0, 0, 0);
            lacc[qg]  = __builtin_amdgcn_mfma_f32_32x32x16_bf16(ef,  pf[qg][ks], lacc[qg],  0, 0, 0);
          }
        }
        __builtin_amdgcn_s_setprio(0);
      }
    }
    __syncthreads();
  }

  // ---- epilogue: O^T -> LDS (swizzled) -> coalesced global store
  char* tb = smem + wid * 8192;  // per-wave 64q x 128B, reuses K buffers
#pragma unroll
  for (int qg = 0; qg < 2; ++qg) {
    const float inv = 1.0f / lacc[qg][0];
    char* trow = tb + qg * 4096 + l31 * 128;
    const int swq = (l31 & 7) << 4;
#pragma unroll
    for (int g2 = 0; g2 < 4; ++g2) {
      uint2 a0, a1;
      a0.x = cvtpk(oaccA[qg][4 * g2] * inv, oaccA[qg][4 * g2 + 1] * inv);
      a0.y = cvtpk(oaccA[qg][4 * g2 + 2] * inv, oaccA[qg][4 * g2 + 3] * inv);
      a1.x = cvtpk(oaccB[qg][4 * g2] * inv, oaccB[qg][4 * g2 + 1] * inv);
      a1.y = cvtpk(oaccB[qg][4 * g2 + 2] * inv, oaccB[qg][4 * g2 + 3] * inv);
      int d0 = 16 * g2 + 8 * hi;
      *(uint2*)(trow + ((d0) ^ swq)) = a0;
      *(uint2*)(trow + ((d0 + 64) ^ swq)) = a1;
    }
  }
#pragma unroll
  for (int half = 0; half < 2; ++half) {
    const int qq = half * 32 + (lane >> 1), cp = lane & 1;
    const char* trow = tb + qq * 128;
    const int swr = (qq & 7) << 4;
    unsigned short* op = ctx + ((size_t)(b * 2048 + q0 + qq)) * 1024 + h * 64 + cp * 32;
#pragma unroll
    for (int i = 0; i < 4; ++i) {
      int col = cp * 64 + i * 16;
      u32x4_t val = *(const u32x4_t*)(trow + (col ^ swr));
      *(u32x4_t*)(op + i * 8) = val;
    }
  }
}

// ---------------------------------------------------------------------------
__global__ __launch_bounds__(256) void ln_kernel(
    float* __restrict__ y, const float* __restrict__ g, const float* __restrict__ be)
{
  const int row = blockIdx.x, tid = threadIdx.x;
  float* rp = y + (size_t)row * 1024;
  float4 x = *(const float4*)(rp + tid * 4);
  float s = x.x + x.y + x.z + x.w;
  float sq = x.x * x.x + x.y * x.y + x.z * x.z + x.w * x.w;
#pragma unroll
  for (int msk = 1; msk < 64; msk <<= 1) {
    s  += __shfl_xor(s, msk);
    sq += __shfl_xor(sq, msk);
  }
  __shared__ float red[8];
  const int wid = tid >> 6, lane = tid & 63;
  if (lane == 0) { red[wid] = s; red[4 + wid] = sq; }
  __syncthreads();
  s  = red[0] + red[1] + red[2] + red[3];
  sq = red[4] + red[5] + red[6] + red[7];
  float mu = s * (1.f / 1024.f);
  float var = sq * (1.f / 1024.f) - mu * mu;
  float rs = rsqrtf(var + 1e-12f);
  float4 gw = *(const float4*)(g + tid * 4);
  float4 bw = *(const float4*)(be + tid * 4);
  float4 o2;
  o2.x = (x.x - mu) * rs * gw.x + bw.x;
  o2.y = (x.y - mu) * rs * gw.y + bw.y;
  o2.z = (x.z - mu) * rs * gw.z + bw.z;
  o2.w = (x.w - mu) * rs * gw.w + bw.w;
  *(float4*)(rp + tid * 4) = o2;
}

// ---------------------------------------------------------------------------
extern "C" void kernel_launch(void* const* d_in, const int* in_sizes, int n_in,
                              void* d_out, int out_size, void* d_ws, size_t ws_size,
                              hipStream_t stream)
{
  const float* x    = (const float*)d_in[0];
  const float* mask = (const float*)d_in[1];
  const float* wq   = (const float*)d_in[2];
  const float* bq   = (const float*)d_in[3];
  const float* wk   = (const float*)d_in[4];
  const float* bk   = (const float*)d_in[5];
  const float* wv   = (const float*)d_in[6];
  const float* bv   = (const float*)d_in[7];
  const float* wo   = (const float*)d_in[8];
  const float* bo   = (const float*)d_in[9];
  const float* lnw  = (const float*)d_in[10];
  const float* lnb  = (const float*)d_in[11];
  float* out = (float*)d_out;

  char* ws = (char*)d_ws;
  unsigned short* Xb  = (unsigned short*)(ws);                               // 16 MB
  unsigned short* Wqb = (unsigned short*)(ws + 16777216);                    // 2 MB
  unsigned short* Wkb = (unsigned short*)(ws + 16777216 + 2097152);
  unsigned short* Wvb = (unsigned short*)(ws + 16777216 + 2 * 2097152);
  unsigned short* Wob = (unsigned short*)(ws + 16777216 + 3 * 2097152);
  unsigned short* Qg  = (unsigned short*)(ws + 25165824);                    // [B,H,S,D]
  unsigned short* Kg  = (unsigned short*)(ws + 25165824 + 16777216);         // [B,H,S,D]
  unsigned short* Vtg = (unsigned short*)(ws + 25165824 + 2 * 16777216);     // [B,H,D,S]
  unsigned short* CTX = (unsigned short*)(ws + 25165824 + 3 * 16777216);     // [B,S,E]
  float*          EMf = (float*)(ws + 92274688);                             // 32 KB
  unsigned short* EMb = (unsigned short*)(ws + 92274688 + 32768);            // 16 KB

  cast_all<<<dim3(6148), 256, 0, stream>>>(x, wq, wk, wv, wo, mask,
                                           Xb, Wqb, Wkb, Wvb, Wob, EMf, EMb);
  gemm_bt<0><<<dim3(64, 8, 2), 256, 0, stream>>>(Xb, Wqb, Wkb, bq, bk, nullptr,
                                                 Qg, Kg, nullptr, 8192, 1024, 1024);
  gemm_bt<2><<<dim3(8, 64, 1), 256, 0, stream>>>(Wvb, Xb, nullptr, bv, nullptr, EMf,
                                                 Vtg, nullptr, nullptr, 1024, 8192, 1024);
  attn_kernel<<<dim3(512), 256, 0, stream>>>(Qg, Kg, Vtg, EMb, CTX);
  gemm_bt<3><<<dim3(64, 8, 1), 256, 0, stream>>>(CTX, Wob, nullptr, bo, nullptr, x,
                                                 nullptr, nullptr, out, 8192, 1024, 1024);
  ln_kernel<<<dim3(8192), 256, 0, stream>>>(out, lnw, lnb);
}

// Round 8
// 215.407 us; speedup vs baseline: 2.2709x; 1.0059x over previous
//
#include <hip/hip_runtime.h>
#include <hip/hip_bf16.h>
#include <stdint.h>

// ---------------------------------------------------------------------------
// MultiHeadSelfAttention fused block, MI355X/gfx950, bf16 MFMA pipeline.
// B=4 S=2048 E=1024 H=16 D=64.
// R7: T4 counted-vmcnt pipelines in GEMM + attn: raw s_barrier (no vmcnt(0)
// drain), s_waitcnt vmcnt(N) keeps next-tile global_load_lds in flight
// across barriers. Attn EM row staged once in prologue (wave-uniform vmcnt).
// ---------------------------------------------------------------------------

typedef short bf16x8_t __attribute__((ext_vector_type(8)));
typedef float f32x4_t __attribute__((ext_vector_type(4)));
typedef float f32x16_t __attribute__((ext_vector_type(16)));
typedef unsigned short u16x8_t __attribute__((ext_vector_type(8)));
typedef uint32_t u32x4_t __attribute__((ext_vector_type(4)));

#define DEV static __device__ __forceinline__

DEV unsigned short f2bf(float f) {  // RNE f32->bf16
  union { float f; uint32_t u; } v; v.f = f;
  uint32_t u = v.u;
  return (unsigned short)((u + 0x7fffu + ((u >> 16) & 1u)) >> 16);
}

DEV uint32_t cvtpk(float a, float b) {  // packed {lo=a, hi=b} bf16, RNE
  uint32_t d;
  asm("v_cvt_pk_bf16_f32 %0, %1, %2" : "=v"(d) : "v"(a), "v"(b));
  return d;
}

// swap: a <- {a.lo_lanes, b.lo_lanes}, b <- {a.hi_lanes, b.hi_lanes}
DEV void plswap(uint32_t& a, uint32_t& b) {
  asm("v_permlane32_swap_b32 %0, %1" : "+v"(a), "+v"(b));
}

DEV float ex2(float x) { return __builtin_amdgcn_exp2f(x); }

template<int N> DEV void wait_vm() {  // counted vmem wait (T4)
  asm volatile("s_waitcnt vmcnt(%0)" :: "n"(N) : "memory");
}
DEV void bar() { __builtin_amdgcn_s_barrier(); }
DEV void sbar0() { __builtin_amdgcn_sched_barrier(0); }

typedef const __attribute__((address_space(1))) void* gp_t;
typedef __attribute__((address_space(3))) void* lp_t;

DEV void gld16(const void* g, void* l) {  // async global->LDS, 16B/lane
  __builtin_amdgcn_global_load_lds((gp_t)g, (lp_t)l, 16, 0, 0);
}

// ---------------------------------------------------------------------------
// Flat exact grid: X 4096 | Wq 512 | Wk 512 | Wv 512 | Wo 512 | mask 4 = 6148
__global__ __launch_bounds__(256) void cast_all(
    const float* __restrict__ x,
    const float* __restrict__ wq, const float* __restrict__ wk,
    const float* __restrict__ wv, const float* __restrict__ wo,
    const float* __restrict__ mask,
    unsigned short* __restrict__ xb,
    unsigned short* __restrict__ wqb, unsigned short* __restrict__ wkb,
    unsigned short* __restrict__ wvb, unsigned short* __restrict__ wob,
    float* __restrict__ emf, unsigned short* __restrict__ emb)
{
  const int cid = blockIdx.x;
  if (cid >= 6144) {  // EM = exp(mask): f32 (Vt fold) + bf16 (l-MFMA A-op)
    int i = ((cid - 6144) * 256 + (int)threadIdx.x) * 8;
    float4 a = *(const float4*)(mask + i);
    float4 b = *(const float4*)(mask + i + 4);
    const float C = 1.44269504f;
    float4 ea, eb;
    ea.x = ex2(a.x * C); ea.y = ex2(a.y * C); ea.z = ex2(a.z * C); ea.w = ex2(a.w * C);
    eb.x = ex2(b.x * C); eb.y = ex2(b.y * C); eb.z = ex2(b.z * C); eb.w = ex2(b.w * C);
    *(float4*)(emf + i) = ea;
    *(float4*)(emf + i + 4) = eb;
    u16x8_t o;
    o[0] = f2bf(ea.x); o[1] = f2bf(ea.y); o[2] = f2bf(ea.z); o[3] = f2bf(ea.w);
    o[4] = f2bf(eb.x); o[5] = f2bf(eb.y); o[6] = f2bf(eb.z); o[7] = f2bf(eb.w);
    *(u16x8_t*)(emb + i) = o;
    return;
  }
  const float* src; unsigned short* dst; int base;
  if (cid < 4096)      { src = x;  dst = xb;  base = cid; }
  else if (cid < 4608) { src = wq; dst = wqb; base = cid - 4096; }
  else if (cid < 5120) { src = wk; dst = wkb; base = cid - 4608; }
  else if (cid < 5632) { src = wv; dst = wvb; base = cid - 5120; }
  else                 { src = wo; dst = wob; base = cid - 5632; }
  int i = (base * 256 + (int)threadIdx.x) * 8;
  float4 a = *(const float4*)(src + i);
  float4 b = *(const float4*)(src + i + 4);
  u16x8_t o;
  o[0] = f2bf(a.x); o[1] = f2bf(a.y); o[2] = f2bf(a.z); o[3] = f2bf(a.w);
  o[4] = f2bf(b.x); o[5] = f2bf(b.y); o[6] = f2bf(b.z); o[7] = f2bf(b.w);
  *(u16x8_t*)(dst + i) = o;
}

// ---------------------------------------------------------------------------
// C[m,n] = sum_k A[m,k]*B[n,k]. 128x128 tile, BK=32, 4 waves, 16x16x32 MFMA.
// Counted-vmcnt 2-phase: STAGE(t+1) stays in flight across raw barriers;
// vmcnt(4) guarantees tile t's loads landed (T3+T4 minimum recipe).
// MODE 0: QK proj (z=0: Q scaled log2e/8; z=1: K), out bf16 [B,H,S,D]
// MODE 2: Vt (A=Wv rows e, B=X rows (b,s)), out bf16 [B,H,D,S] * EM (resid=EMf)
// MODE 3: WO + bias + residual, out f32 [M,N]
template<int MODE>
__global__ __launch_bounds__(256) void gemm_bt(
    const unsigned short* __restrict__ A,
    const unsigned short* __restrict__ B0, const unsigned short* __restrict__ B1,
    const float* __restrict__ bias0, const float* __restrict__ bias1,
    const float* __restrict__ resid,
    unsigned short* __restrict__ o0, unsigned short* __restrict__ o1,
    float* __restrict__ of,
    int M, int N, int K)
{
  __shared__ unsigned short As[2][128 * 32];
  __shared__ unsigned short Bs[2][128 * 32];

  const int z = blockIdx.z;
  const unsigned short* Bw = (MODE == 0 && z == 1) ? B1 : B0;
  const float* bias = (MODE == 0 && z == 1) ? bias1 : bias0;
  unsigned short* obf = (MODE == 0 && z == 1) ? o1 : o0;

  const int tid = threadIdx.x;
  const int lane = tid & 63;
  const int lr = lane & 15, lq = lane >> 4;
  const int wid = tid >> 6;
  const int m0 = blockIdx.x * 128;
  const int n0 = blockIdx.y * 128;
  const int wr = (wid >> 1) * 64, wc = (wid & 1) * 64;

  f32x4_t acc[4][4] = {};

  const int o = tid * 16;
  const int srow = o >> 6, scb = o & 63;   // this thread's stage row/col-byte

  // stage K-chunk at element offset kt into buffer p: 4 gloads/thread
  auto STAGE = [&](int kt, int p) {
#pragma unroll
    for (int r = 0; r < 2; ++r) {
      int row = srow + r * 64;
      int oo = o + r * 4096;
      gld16((const char*)(A  + (size_t)(m0 + row) * K + kt) + scb, (char*)As[p] + oo);
      gld16((const char*)(Bw + (size_t)(n0 + row) * K + kt) + scb, (char*)Bs[p] + oo);
    }
  };

  STAGE(0, 0);
  wait_vm<0>();
  bar(); sbar0();

  int cur = 0;
  for (int kt = 32; kt <= K; kt += 32) {
    if (kt < K) {
      STAGE(kt, cur ^ 1);   // 4 loads in flight across the barrier
      wait_vm<4>();         // tile (kt-32)'s loads complete
    } else {
      wait_vm<0>();
    }
    bar(); sbar0();

    bf16x8_t aF[4], bF[4];
    const int koff = lq * 16;
#pragma unroll
    for (int i = 0; i < 4; ++i) {
      aF[i] = *(const bf16x8_t*)((const char*)As[cur] + (wr + i * 16 + lr) * 64 + koff);
      bF[i] = *(const bf16x8_t*)((const char*)Bs[cur] + (wc + i * 16 + lr) * 64 + koff);
    }
#pragma unroll
    for (int i = 0; i < 4; ++i)
#pragma unroll
      for (int j = 0; j < 4; ++j)
        acc[i][j] = __builtin_amdgcn_mfma_f32_16x16x32_bf16(aF[i], bF[j], acc[i][j], 0, 0, 0);

    bar();   // all waves done reading buf[cur] before next STAGE overwrites it
    cur ^= 1;
  }

#pragma unroll
  for (int i = 0; i < 4; ++i) {
#pragma unroll
    for (int j = 0; j < 4; ++j) {
      int n = n0 + wc + j * 16 + lr;
#pragma unroll
      for (int r = 0; r < 4; ++r) {
        int m = m0 + wr + i * 16 + lq * 4 + r;
        float v = acc[i][j][r];
        if (MODE == 0) {
          // z=0 (Q): fold 1/sqrt(64) AND log2e so QK^T lands in log2 domain
          v = (v + bias[n]) * (z == 0 ? 0.18033688f : 1.0f);
          int b = m >> 11, s = m & 2047, h = n >> 6, d = n & 63;
          obf[(size_t)((b * 16 + h) * 2048 + s) * 64 + d] = f2bf(v);
        } else if (MODE == 2) {
          v = (v + bias[m]) * resid[n];  // resid = EMf, n = b*2048+s
          int b = n >> 11, s = n & 2047;
          obf[(size_t)(b * 1024 + m) * 2048 + s] = f2bf(v);
        } else {
          v = v + bias[n] + resid[(size_t)m * 1024 + n];
          of[(size_t)m * 1024 + n] = v;
        }
      }
    }
  }
}

// ---------------------------------------------------------------------------
// Flash attention, swapped-QK^T 32x32, max-free softmax, QBLK=256, KBLK=128.
// Grid 512, 256 threads (4 waves), wave owns 64 q (2 q-groups of 32).
// Counted-vmcnt pipeline: per-iter STAGE = exactly 8 gloads/thread; EM row
// (4KB) staged once in prologue.
__global__ __launch_bounds__(256, 2) void attn_kernel(
    const unsigned short* __restrict__ Qg, const unsigned short* __restrict__ Kg,
    const unsigned short* __restrict__ Vtg, const unsigned short* __restrict__ EMb,
    unsigned short* __restrict__ ctx)
{
  // smem: K[2][16384] | V[2][16384] | E[4096]; epilogue reuses 0..32K
  __shared__ __align__(16) char smem[69632];

  const int id = blockIdx.x;
  const int swz = (id & 7) * 64 + (id >> 3);  // bijective XCD swizzle (512/8)
  const int bh = swz >> 3, qt = swz & 7;
  const int b = bh >> 4, h = bh & 15;

  const int tid = threadIdx.x, lane = tid & 63, wid = tid >> 6;
  const int l31 = lane & 31, hi = lane >> 5;
  const int q0 = qt * 256 + wid * 64;
  const size_t head = (size_t)bh * (2048 * 64);
  const unsigned short* Kh = Kg + head;
  const unsigned short* Vh = Vtg + (size_t)bh * 64 * 2048;
  const unsigned short* emrow = EMb + (size_t)b * 2048;

  // Q B-fragments: col q = q0 + qg*32 + l31, d = ds*16 + 8*hi + j
  bf16x8_t qf[2][4];
#pragma unroll
  for (int qg = 0; qg < 2; ++qg) {
    const unsigned short* qp = Qg + head + (size_t)(q0 + qg * 32 + l31) * 64 + 8 * hi;
#pragma unroll
    for (int ds = 0; ds < 4; ++ds) qf[qg][ds] = *(const bf16x8_t*)(qp + ds * 16);
  }

  f32x16_t oaccA[2] = {}, oaccB[2] = {};  // O^T[d,q]: d 0-31 / 32-63 per qg
  f32x16_t lacc[2] = {};                  // denominators; read [0] at end

  const int sw_row = (l31 & 7) << 4;

  // stage 128-k chunk t into buffer p: exactly 8 gloads/thread (4 K + 4 V)
  auto STAGE = [&](int t, int p) {
    const int k0 = t * 128;
    char* kd = smem + p * 16384;
    char* vd = smem + 32768 + p * 16384;
#pragma unroll
    for (int r = 0; r < 4; ++r) {
      int oo = tid * 16 + r * 4096;
      {  // K: row = k (stride 128B), inverse swizzle on source
        int row = oo >> 7, cb = oo & 127;
        int scb = cb ^ ((row & 7) << 4);
        gld16((const char*)(Kh + (size_t)(k0 + row) * 64) + scb, kd + oo);
      }
      {  // V: row = d (stride 256B), inverse swizzle on source
        int row = oo >> 8, cb = oo & 255;
        int scb = cb ^ ((row & 7) << 4);
        gld16((const char*)(Vh + (size_t)row * 2048 + k0) + scb, vd + oo);
      }
    }
  };

  // prologue: whole EM row (4KB) + tile 0; full drain once
  gld16((const char*)(emrow + tid * 8), smem + 65536 + tid * 16);
  STAGE(0, 0);
  wait_vm<0>();
  bar(); sbar0();

  for (int t = 0; t < 16; ++t) {
    const int p = t & 1;
    if (t < 15) {
      STAGE(t + 1, p ^ 1);   // 8 loads in flight across the barrier
      wait_vm<8>();          // tile t's loads complete
    } else {
      wait_vm<0>();
    }
    bar(); sbar0();

    const char* kb = smem + p * 16384;
    const char* vb = smem + 32768 + p * 16384;
    const char* eb = smem + 65536 + t * 256;

#pragma unroll
    for (int s = 0; s < 2; ++s) {  // two independent 64-k sub-tiles
      // ---- S^T = K . Q^T (log2 domain): c0 = k 0-31, c1 = k 32-63, per qg
      f32x16_t c0[2] = {}, c1[2] = {};
      {
        const char* kr0 = kb + s * 8192 + l31 * 128;
        const char* kr1 = kb + s * 8192 + (32 + l31) * 128;
        __builtin_amdgcn_s_setprio(1);
#pragma unroll
        for (int ds = 0; ds < 4; ++ds) {
          int cc = (ds * 32 + 16 * hi) ^ sw_row;
          bf16x8_t k0f = *(const bf16x8_t*)(kr0 + cc);
          bf16x8_t k1f = *(const bf16x8_t*)(kr1 + cc);
#pragma unroll
          for (int qg = 0; qg < 2; ++qg) {
            c0[qg] = __builtin_amdgcn_mfma_f32_32x32x16_bf16(k0f, qf[qg][ds], c0[qg], 0, 0, 0);
            c1[qg] = __builtin_amdgcn_mfma_f32_32x32x16_bf16(k1f, qf[qg][ds], c1[qg], 0, 0, 0);
          }
        }
        __builtin_amdgcn_s_setprio(0);
      }

      // ---- P = exp2(c) raw (max-free), pack bf16, permlane partner exchange
      bf16x8_t pf[2][4];
#pragma unroll
      for (int qg = 0; qg < 2; ++qg) {
        uint32_t w0[8], w1[8];
#pragma unroll
        for (int g = 0; g < 8; ++g) {
          const int i4 = (g & 3) * 4;
          if (g < 4) {
            w0[g] = cvtpk(ex2(c0[qg][i4]), ex2(c0[qg][i4 + 1]));
            w1[g] = cvtpk(ex2(c0[qg][i4 + 2]), ex2(c0[qg][i4 + 3]));
          } else {
            w0[g] = cvtpk(ex2(c1[qg][i4]), ex2(c1[qg][i4 + 1]));
            w1[g] = cvtpk(ex2(c1[qg][i4 + 2]), ex2(c1[qg][i4 + 3]));
          }
        }
#pragma unroll
        for (int ks = 0; ks < 4; ++ks) {
          const int gg = ((ks >> 1) << 2) + ((ks & 1) << 1);
          uint32_t a0 = w0[gg], b0 = w0[gg + 1];
          uint32_t a1 = w1[gg], b1 = w1[gg + 1];
          plswap(a0, b0);
          plswap(a1, b1);
          union { uint32_t u[4]; bf16x8_t v; } cv;
          cv.u[0] = a0; cv.u[1] = a1; cv.u[2] = b0; cv.u[3] = b1;
          pf[qg][ks] = cv.v;
        }
      }

      // ---- PV (O^T += Vt.P^T) and l (lacc += EM.P^T), frags shared across qg
      {
        const char* vr0 = vb + l31 * 256 + s * 128;
        const char* vr1 = vb + (32 + l31) * 256 + s * 128;
        const char* ebs = eb + s * 128;
        __builtin_amdgcn_s_setprio(1);
#pragma unroll
        for (int ks = 0; ks < 4; ++ks) {
          bf16x8_t ef = *(const bf16x8_t*)(ebs + ks * 32 + 16 * hi);
          int cc = (ks * 32 + 16 * hi) ^ sw_row;
          bf16x8_t v0f = *(const bf16x8_t*)(vr0 + cc);
          bf16x8_t v1f = *(const bf16x8_t*)(vr1 + cc);
#pragma unroll
          for (int qg = 0; qg < 2; ++qg) {
            oaccA[qg] = __builtin_amdgcn_mfma_f32_32x32x16_bf16(v0f, pf[qg][ks], oaccA[qg], 0, 0, 0);
            oaccB[qg] = __builtin_amdgcn_mfma_f32_32x32x16_bf16(v1f, pf[qg][ks], oaccB[qg], 0, 0, 0);
            lacc[qg]  = __builtin_amdgcn_mfma_f32_32x32x16_bf16(ef,  pf[qg][ks], lacc[qg],  0, 0, 0);
          }
        }
        __builtin_amdgcn_s_setprio(0);
      }
    }
    bar();   // all waves done reading buf p before next STAGE overwrites it
  }

  // ---- epilogue: O^T -> LDS (swizzled) -> coalesced global store
  char* tb = smem + wid * 8192;  // per-wave 64q x 128B, reuses K buffers
#pragma unroll
  for (int qg = 0; qg < 2; ++qg) {
    const float inv = 1.0f / lacc[qg][0];
    char* trow = tb + qg * 4096 + l31 * 128;
    const int swq = (l31 & 7) << 4;
#pragma unroll
    for (int g2 = 0; g2 < 4; ++g2) {
      uint2 a0, a1;
      a0.x = cvtpk(oaccA[qg][4 * g2] * inv, oaccA[qg][4 * g2 + 1] * inv);
      a0.y = cvtpk(oaccA[qg][4 * g2 + 2] * inv, oaccA[qg][4 * g2 + 3] * inv);
      a1.x = cvtpk(oaccB[qg][4 * g2] * inv, oaccB[qg][4 * g2 + 1] * inv);
      a1.y = cvtpk(oaccB[qg][4 * g2 + 2] * inv, oaccB[qg][4 * g2 + 3] * inv);
      int d0 = 16 * g2 + 8 * hi;
      *(uint2*)(trow + ((d0) ^ swq)) = a0;
      *(uint2*)(trow + ((d0 + 64) ^ swq)) = a1;
    }
  }
#pragma unroll
  for (int half = 0; half < 2; ++half) {
    const int qq = half * 32 + (lane >> 1), cp = lane & 1;
    const char* trow = tb + qq * 128;
    const int swr = (qq & 7) << 4;
    unsigned short* op = ctx + ((size_t)(b * 2048 + q0 + qq)) * 1024 + h * 64 + cp * 32;
#pragma unroll
    for (int i = 0; i < 4; ++i) {
      int col = cp * 64 + i * 16;
      u32x4_t val = *(const u32x4_t*)(trow + (col ^ swr));
      *(u32x4_t*)(op + i * 8) = val;
    }
  }
}

// ---------------------------------------------------------------------------
__global__ __launch_bounds__(256) void ln_kernel(
    float* __restrict__ y, const float* __restrict__ g, const float* __restrict__ be)
{
  const int row = blockIdx.x, tid = threadIdx.x;
  float* rp = y + (size_t)row * 1024;
  float4 x = *(const float4*)(rp + tid * 4);
  float s = x.x + x.y + x.z + x.w;
  float sq = x.x * x.x + x.y * x.y + x.z * x.z + x.w * x.w;
#pragma unroll
  for (int msk = 1; msk < 64; msk <<= 1) {
    s  += __shfl_xor(s, msk);
    sq += __shfl_xor(sq, msk);
  }
  __shared__ float red[8];
  const int wid = tid >> 6, lane = tid & 63;
  if (lane == 0) { red[wid] = s; red[4 + wid] = sq; }
  __syncthreads();
  s  = red[0] + red[1] + red[2] + red[3];
  sq = red[4] + red[5] + red[6] + red[7];
  float mu = s * (1.f / 1024.f);
  float var = sq * (1.f / 1024.f) - mu * mu;
  float rs = rsqrtf(var + 1e-12f);
  float4 gw = *(const float4*)(g + tid * 4);
  float4 bw = *(const float4*)(be + tid * 4);
  float4 o2;
  o2.x = (x.x - mu) * rs * gw.x + bw.x;
  o2.y = (x.y - mu) * rs * gw.y + bw.y;
  o2.z = (x.z - mu) * rs * gw.z + bw.z;
  o2.w = (x.w - mu) * rs * gw.w + bw.w;
  *(float4*)(rp + tid * 4) = o2;
}

// ---------------------------------------------------------------------------
extern "C" void kernel_launch(void* const* d_in, const int* in_sizes, int n_in,
                              void* d_out, int out_size, void* d_ws, size_t ws_size,
                              hipStream_t stream)
{
  const float* x    = (const float*)d_in[0];
  const float* mask = (const float*)d_in[1];
  const float* wq   = (const float*)d_in[2];
  const float* bq   = (const float*)d_in[3];
  const float* wk   = (const float*)d_in[4];
  const float* bk   = (const float*)d_in[5];
  const float* wv   = (const float*)d_in[6];
  const float* bv   = (const float*)d_in[7];
  const float* wo   = (const float*)d_in[8];
  const float* bo   = (const float*)d_in[9];
  const float* lnw  = (const float*)d_in[10];
  const float* lnb  = (const float*)d_in[11];
  float* out = (float*)d_out;

  char* ws = (char*)d_ws;
  unsigned short* Xb  = (unsigned short*)(ws);                               // 16 MB
  unsigned short* Wqb = (unsigned short*)(ws + 16777216);                    // 2 MB
  unsigned short* Wkb = (unsigned short*)(ws + 16777216 + 2097152);
  unsigned short* Wvb = (unsigned short*)(ws + 16777216 + 2 * 2097152);
  unsigned short* Wob = (unsigned short*)(ws + 16777216 + 3 * 2097152);
  unsigned short* Qg  = (unsigned short*)(ws + 25165824);                    // [B,H,S,D]
  unsigned short* Kg  = (unsigned short*)(ws + 25165824 + 16777216);         // [B,H,S,D]
  unsigned short* Vtg = (unsigned short*)(ws + 25165824 + 2 * 16777216);     // [B,H,D,S]
  unsigned short* CTX = (unsigned short*)(ws + 25165824 + 3 * 16777216);     // [B,S,E]
  float*          EMf = (float*)(ws + 92274688);                             // 32 KB
  unsigned short* EMb = (unsigned short*)(ws + 92274688 + 32768);            // 16 KB

  cast_all<<<dim3(6148), 256, 0, stream>>>(x, wq, wk, wv, wo, mask,
                                           Xb, Wqb, Wkb, Wvb, Wob, EMf, EMb);
  gemm_bt<0><<<dim3(64, 8, 2), 256, 0, stream>>>(Xb, Wqb, Wkb, bq, bk, nullptr,
                                                 Qg, Kg, nullptr, 8192, 1024, 1024);
  gemm_bt<2><<<dim3(8, 64, 1), 256, 0, stream>>>(Wvb, Xb, nullptr, bv, nullptr, EMf,
                                                 Vtg, nullptr, nullptr, 1024, 8192, 1024);
  attn_kernel<<<dim3(512), 256, 0, stream>>>(Qg, Kg, Vtg, EMb, CTX);
  gemm_bt<3><<<dim3(64, 8, 1), 256, 0, stream>>>(CTX, Wob, nullptr, bo, nullptr, x,
                                                 nullptr, nullptr, out, 8192, 1024, 1024);
  ln_kernel<<<dim3(8192), 256, 0, stream>>>(out, lnw, lnb);
}

// Round 9
// 215.005 us; speedup vs baseline: 2.2751x; 1.0019x over previous
//
#include <hip/hip_runtime.h>
#include <hip/hip_bf16.h>
#include <stdint.h>

// ---------------------------------------------------------------------------
// MultiHeadSelfAttention fused block, MI355X/gfx950, bf16 MFMA pipeline.
// B=4 S=2048 E=1024 H=16 D=64.
// R8: T2 XOR-swizzle on GEMM LDS tiles (col ^= ((row>>1)&3)<<4 for 64B rows).
// Unswizzled reads were an 8-way bank conflict (banks 16*lr+4*lq mod 32 ->
// 8 lanes/bank, half the banks idle) - the hidden reason scheduling changes
// (R6/R7) were ~neutral. Swizzle applied rule-21 both-sides: pre-swizzled
// global source + linear gld16 dest + swizzled frag reads.
// ---------------------------------------------------------------------------

typedef short bf16x8_t __attribute__((ext_vector_type(8)));
typedef float f32x4_t __attribute__((ext_vector_type(4)));
typedef float f32x16_t __attribute__((ext_vector_type(16)));
typedef unsigned short u16x8_t __attribute__((ext_vector_type(8)));
typedef uint32_t u32x4_t __attribute__((ext_vector_type(4)));

#define DEV static __device__ __forceinline__

DEV unsigned short f2bf(float f) {  // RNE f32->bf16
  union { float f; uint32_t u; } v; v.f = f;
  uint32_t u = v.u;
  return (unsigned short)((u + 0x7fffu + ((u >> 16) & 1u)) >> 16);
}

DEV uint32_t cvtpk(float a, float b) {  // packed {lo=a, hi=b} bf16, RNE
  uint32_t d;
  asm("v_cvt_pk_bf16_f32 %0, %1, %2" : "=v"(d) : "v"(a), "v"(b));
  return d;
}

// swap: a <- {a.lo_lanes, b.lo_lanes}, b <- {a.hi_lanes, b.hi_lanes}
DEV void plswap(uint32_t& a, uint32_t& b) {
  asm("v_permlane32_swap_b32 %0, %1" : "+v"(a), "+v"(b));
}

DEV float ex2(float x) { return __builtin_amdgcn_exp2f(x); }

template<int N> DEV void wait_vm() {  // counted vmem wait (T4)
  asm volatile("s_waitcnt vmcnt(%0)" :: "n"(N) : "memory");
}
DEV void bar() { __builtin_amdgcn_s_barrier(); }
DEV void sbar0() { __builtin_amdgcn_sched_barrier(0); }

typedef const __attribute__((address_space(1))) void* gp_t;
typedef __attribute__((address_space(3))) void* lp_t;

DEV void gld16(const void* g, void* l) {  // async global->LDS, 16B/lane
  __builtin_amdgcn_global_load_lds((gp_t)g, (lp_t)l, 16, 0, 0);
}

// ---------------------------------------------------------------------------
// Flat exact grid: X 4096 | Wq 512 | Wk 512 | Wv 512 | Wo 512 | mask 4 = 6148
__global__ __launch_bounds__(256) void cast_all(
    const float* __restrict__ x,
    const float* __restrict__ wq, const float* __restrict__ wk,
    const float* __restrict__ wv, const float* __restrict__ wo,
    const float* __restrict__ mask,
    unsigned short* __restrict__ xb,
    unsigned short* __restrict__ wqb, unsigned short* __restrict__ wkb,
    unsigned short* __restrict__ wvb, unsigned short* __restrict__ wob,
    float* __restrict__ emf, unsigned short* __restrict__ emb)
{
  const int cid = blockIdx.x;
  if (cid >= 6144) {  // EM = exp(mask): f32 (Vt fold) + bf16 (l-MFMA A-op)
    int i = ((cid - 6144) * 256 + (int)threadIdx.x) * 8;
    float4 a = *(const float4*)(mask + i);
    float4 b = *(const float4*)(mask + i + 4);
    const float C = 1.44269504f;
    float4 ea, eb;
    ea.x = ex2(a.x * C); ea.y = ex2(a.y * C); ea.z = ex2(a.z * C); ea.w = ex2(a.w * C);
    eb.x = ex2(b.x * C); eb.y = ex2(b.y * C); eb.z = ex2(b.z * C); eb.w = ex2(b.w * C);
    *(float4*)(emf + i) = ea;
    *(float4*)(emf + i + 4) = eb;
    u16x8_t o;
    o[0] = f2bf(ea.x); o[1] = f2bf(ea.y); o[2] = f2bf(ea.z); o[3] = f2bf(ea.w);
    o[4] = f2bf(eb.x); o[5] = f2bf(eb.y); o[6] = f2bf(eb.z); o[7] = f2bf(eb.w);
    *(u16x8_t*)(emb + i) = o;
    return;
  }
  const float* src; unsigned short* dst; int base;
  if (cid < 4096)      { src = x;  dst = xb;  base = cid; }
  else if (cid < 4608) { src = wq; dst = wqb; base = cid - 4096; }
  else if (cid < 5120) { src = wk; dst = wkb; base = cid - 4608; }
  else if (cid < 5632) { src = wv; dst = wvb; base = cid - 5120; }
  else                 { src = wo; dst = wob; base = cid - 5632; }
  int i = (base * 256 + (int)threadIdx.x) * 8;
  float4 a = *(const float4*)(src + i);
  float4 b = *(const float4*)(src + i + 4);
  u16x8_t o;
  o[0] = f2bf(a.x); o[1] = f2bf(a.y); o[2] = f2bf(a.z); o[3] = f2bf(a.w);
  o[4] = f2bf(b.x); o[5] = f2bf(b.y); o[6] = f2bf(b.z); o[7] = f2bf(b.w);
  *(u16x8_t*)(dst + i) = o;
}

// ---------------------------------------------------------------------------
// C[m,n] = sum_k A[m,k]*B[n,k]. 128x128 tile, BK=32, 4 waves, 16x16x32 MFMA.
// Counted-vmcnt 2-phase + T2 swizzle (col ^= ((row>>1)&3)<<4 within 64B rows).
// MODE 0: QK proj (z=0: Q scaled log2e/8; z=1: K), out bf16 [B,H,S,D]
// MODE 2: Vt (A=Wv rows e, B=X rows (b,s)), out bf16 [B,H,D,S] * EM (resid=EMf)
// MODE 3: WO + bias + residual, out f32 [M,N]
template<int MODE>
__global__ __launch_bounds__(256) void gemm_bt(
    const unsigned short* __restrict__ A,
    const unsigned short* __restrict__ B0, const unsigned short* __restrict__ B1,
    const float* __restrict__ bias0, const float* __restrict__ bias1,
    const float* __restrict__ resid,
    unsigned short* __restrict__ o0, unsigned short* __restrict__ o1,
    float* __restrict__ of,
    int M, int N, int K)
{
  __shared__ unsigned short As[2][128 * 32];
  __shared__ unsigned short Bs[2][128 * 32];

  const int z = blockIdx.z;
  const unsigned short* Bw = (MODE == 0 && z == 1) ? B1 : B0;
  const float* bias = (MODE == 0 && z == 1) ? bias1 : bias0;
  unsigned short* obf = (MODE == 0 && z == 1) ? o1 : o0;

  const int tid = threadIdx.x;
  const int lane = tid & 63;
  const int lr = lane & 15, lq = lane >> 4;
  const int wid = tid >> 6;
  const int m0 = blockIdx.x * 128;
  const int n0 = blockIdx.y * 128;
  const int wr = (wid >> 1) * 64, wc = (wid & 1) * 64;

  f32x4_t acc[4][4] = {};

  const int o = tid * 16;
  const int srow = o >> 6;
  const int scb = (o & 63) ^ (((srow >> 1) & 3) << 4);  // inverse swizzle on src

  // stage K-chunk at element offset kt into buffer p: 4 gloads/thread
  auto STAGE = [&](int kt, int p) {
#pragma unroll
    for (int r = 0; r < 2; ++r) {
      int row = srow + r * 64;
      int oo = o + r * 4096;
      gld16((const char*)(A  + (size_t)(m0 + row) * K + kt) + scb, (char*)As[p] + oo);
      gld16((const char*)(Bw + (size_t)(n0 + row) * K + kt) + scb, (char*)Bs[p] + oo);
    }
  };

  STAGE(0, 0);
  wait_vm<0>();
  bar(); sbar0();

  int cur = 0;
  for (int kt = 32; kt <= K; kt += 32) {
    if (kt < K) {
      STAGE(kt, cur ^ 1);   // 4 loads in flight across the barrier
      wait_vm<4>();         // tile (kt-32)'s loads complete
    } else {
      wait_vm<0>();
    }
    bar(); sbar0();

    bf16x8_t aF[4], bF[4];
#pragma unroll
    for (int i = 0; i < 4; ++i) {
      int rowA = wr + i * 16 + lr;
      int rowB = wc + i * 16 + lr;
      int ccA = (lq * 16) ^ (((rowA >> 1) & 3) << 4);  // swizzled read
      int ccB = (lq * 16) ^ (((rowB >> 1) & 3) << 4);
      aF[i] = *(const bf16x8_t*)((const char*)As[cur] + rowA * 64 + ccA);
      bF[i] = *(const bf16x8_t*)((const char*)Bs[cur] + rowB * 64 + ccB);
    }
#pragma unroll
    for (int i = 0; i < 4; ++i)
#pragma unroll
      for (int j = 0; j < 4; ++j)
        acc[i][j] = __builtin_amdgcn_mfma_f32_16x16x32_bf16(aF[i], bF[j], acc[i][j], 0, 0, 0);

    bar();   // all waves done reading buf[cur] before next STAGE overwrites it
    cur ^= 1;
  }

#pragma unroll
  for (int i = 0; i < 4; ++i) {
#pragma unroll
    for (int j = 0; j < 4; ++j) {
      int n = n0 + wc + j * 16 + lr;
#pragma unroll
      for (int r = 0; r < 4; ++r) {
        int m = m0 + wr + i * 16 + lq * 4 + r;
        float v = acc[i][j][r];
        if (MODE == 0) {
          // z=0 (Q): fold 1/sqrt(64) AND log2e so QK^T lands in log2 domain
          v = (v + bias[n]) * (z == 0 ? 0.18033688f : 1.0f);
          int b = m >> 11, s = m & 2047, h = n >> 6, d = n & 63;
          obf[(size_t)((b * 16 + h) * 2048 + s) * 64 + d] = f2bf(v);
        } else if (MODE == 2) {
          v = (v + bias[m]) * resid[n];  // resid = EMf, n = b*2048+s
          int b = n >> 11, s = n & 2047;
          obf[(size_t)(b * 1024 + m) * 2048 + s] = f2bf(v);
        } else {
          v = v + bias[n] + resid[(size_t)m * 1024 + n];
          of[(size_t)m * 1024 + n] = v;
        }
      }
    }
  }
}

// ---------------------------------------------------------------------------
// Flash attention, swapped-QK^T 32x32, max-free softmax, QBLK=256, KBLK=128.
// Grid 512, 256 threads (4 waves), wave owns 64 q (2 q-groups of 32).
// Counted-vmcnt pipeline; EM row (4KB) staged once in prologue.
__global__ __launch_bounds__(256, 2) void attn_kernel(
    const unsigned short* __restrict__ Qg, const unsigned short* __restrict__ Kg,
    const unsigned short* __restrict__ Vtg, const unsigned short* __restrict__ EMb,
    unsigned short* __restrict__ ctx)
{
  // smem: K[2][16384] | V[2][16384] | E[4096]; epilogue reuses 0..32K
  __shared__ __align__(16) char smem[69632];

  const int id = blockIdx.x;
  const int swz = (id & 7) * 64 + (id >> 3);  // bijective XCD swizzle (512/8)
  const int bh = swz >> 3, qt = swz & 7;
  const int b = bh >> 4, h = bh & 15;

  const int tid = threadIdx.x, lane = tid & 63, wid = tid >> 6;
  const int l31 = lane & 31, hi = lane >> 5;
  const int q0 = qt * 256 + wid * 64;
  const size_t head = (size_t)bh * (2048 * 64);
  const unsigned short* Kh = Kg + head;
  const unsigned short* Vh = Vtg + (size_t)bh * 64 * 2048;
  const unsigned short* emrow = EMb + (size_t)b * 2048;

  // Q B-fragments: col q = q0 + qg*32 + l31, d = ds*16 + 8*hi + j
  bf16x8_t qf[2][4];
#pragma unroll
  for (int qg = 0; qg < 2; ++qg) {
    const unsigned short* qp = Qg + head + (size_t)(q0 + qg * 32 + l31) * 64 + 8 * hi;
#pragma unroll
    for (int ds = 0; ds < 4; ++ds) qf[qg][ds] = *(const bf16x8_t*)(qp + ds * 16);
  }

  f32x16_t oaccA[2] = {}, oaccB[2] = {};  // O^T[d,q]: d 0-31 / 32-63 per qg
  f32x16_t lacc[2] = {};                  // denominators; read [0] at end

  const int sw_row = (l31 & 7) << 4;

  // stage 128-k chunk t into buffer p: exactly 8 gloads/thread (4 K + 4 V)
  auto STAGE = [&](int t, int p) {
    const int k0 = t * 128;
    char* kd = smem + p * 16384;
    char* vd = smem + 32768 + p * 16384;
#pragma unroll
    for (int r = 0; r < 4; ++r) {
      int oo = tid * 16 + r * 4096;
      {  // K: row = k (stride 128B), inverse swizzle on source
        int row = oo >> 7, cb = oo & 127;
        int scb = cb ^ ((row & 7) << 4);
        gld16((const char*)(Kh + (size_t)(k0 + row) * 64) + scb, kd + oo);
      }
      {  // V: row = d (stride 256B), inverse swizzle on source
        int row = oo >> 8, cb = oo & 255;
        int scb = cb ^ ((row & 7) << 4);
        gld16((const char*)(Vh + (size_t)row * 2048 + k0) + scb, vd + oo);
      }
    }
  };

  // prologue: whole EM row (4KB) + tile 0; full drain once
  gld16((const char*)(emrow + tid * 8), smem + 65536 + tid * 16);
  STAGE(0, 0);
  wait_vm<0>();
  bar(); sbar0();

  for (int t = 0; t < 16; ++t) {
    const int p = t & 1;
    if (t < 15) {
      STAGE(t + 1, p ^ 1);   // 8 loads in flight across the barrier
      wait_vm<8>();          // tile t's loads complete
    } else {
      wait_vm<0>();
    }
    bar(); sbar0();

    const char* kb = smem + p * 16384;
    const char* vb = smem + 32768 + p * 16384;
    const char* eb = smem + 65536 + t * 256;

#pragma unroll
    for (int s = 0; s < 2; ++s) {  // two independent 64-k sub-tiles
      // ---- S^T = K . Q^T (log2 domain): c0 = k 0-31, c1 = k 32-63, per qg
      f32x16_t c0[2] = {}, c1[2] = {};
      {
        const char* kr0 = kb + s * 8192 + l31 * 128;
        const char* kr1 = kb + s * 8192 + (32 + l31) * 128;
        __builtin_amdgcn_s_setprio(1);
#pragma unroll
        for (int ds = 0; ds < 4; ++ds) {
          int cc = (ds * 32 + 16 * hi) ^ sw_row;
          bf16x8_t k0f = *(const bf16x8_t*)(kr0 + cc);
          bf16x8_t k1f = *(const bf16x8_t*)(kr1 + cc);
#pragma unroll
          for (int qg = 0; qg < 2; ++qg) {
            c0[qg] = __builtin_amdgcn_mfma_f32_32x32x16_bf16(k0f, qf[qg][ds], c0[qg], 0, 0, 0);
            c1[qg] = __builtin_amdgcn_mfma_f32_32x32x16_bf16(k1f, qf[qg][ds], c1[qg], 0, 0, 0);
          }
        }
        __builtin_amdgcn_s_setprio(0);
      }

      // ---- P = exp2(c) raw (max-free), pack bf16, permlane partner exchange
      bf16x8_t pf[2][4];
#pragma unroll
      for (int qg = 0; qg < 2; ++qg) {
        uint32_t w0[8], w1[8];
#pragma unroll
        for (int g = 0; g < 8; ++g) {
          const int i4 = (g & 3) * 4;
          if (g < 4) {
            w0[g] = cvtpk(ex2(c0[qg][i4]), ex2(c0[qg][i4 + 1]));
            w1[g] = cvtpk(ex2(c0[qg][i4 + 2]), ex2(c0[qg][i4 + 3]));
          } else {
            w0[g] = cvtpk(ex2(c1[qg][i4]), ex2(c1[qg][i4 + 1]));
            w1[g] = cvtpk(ex2(c1[qg][i4 + 2]), ex2(c1[qg][i4 + 3]));
          }
        }
#pragma unroll
        for (int ks = 0; ks < 4; ++ks) {
          const int gg = ((ks >> 1) << 2) + ((ks & 1) << 1);
          uint32_t a0 = w0[gg], b0 = w0[gg + 1];
          uint32_t a1 = w1[gg], b1 = w1[gg + 1];
          plswap(a0, b0);
          plswap(a1, b1);
          union { uint32_t u[4]; bf16x8_t v; } cv;
          cv.u[0] = a0; cv.u[1] = a1; cv.u[2] = b0; cv.u[3] = b1;
          pf[qg][ks] = cv.v;
        }
      }

      // ---- PV (O^T += Vt.P^T) and l (lacc += EM.P^T), frags shared across qg
      {
        const char* vr0 = vb + l31 * 256 + s * 128;
        const char* vr1 = vb + (32 + l31) * 256 + s * 128;
        const char* ebs = eb + s * 128;
        __builtin_amdgcn_s_setprio(1);
#pragma unroll
        for (int ks = 0; ks < 4; ++ks) {
          bf16x8_t ef = *(const bf16x8_t*)(ebs + ks * 32 + 16 * hi);
          int cc = (ks * 32 + 16 * hi) ^ sw_row;
          bf16x8_t v0f = *(const bf16x8_t*)(vr0 + cc);
          bf16x8_t v1f = *(const bf16x8_t*)(vr1 + cc);
#pragma unroll
          for (int qg = 0; qg < 2; ++qg) {
            oaccA[qg] = __builtin_amdgcn_mfma_f32_32x32x16_bf16(v0f, pf[qg][ks], oaccA[qg], 0, 0, 0);
            oaccB[qg] = __builtin_amdgcn_mfma_f32_32x32x16_bf16(v1f, pf[qg][ks], oaccB[qg], 0, 0, 0);
            lacc[qg]  = __builtin_amdgcn_mfma_f32_32x32x16_bf16(ef,  pf[qg][ks], lacc[qg],  0, 0, 0);
          }
        }
        __builtin_amdgcn_s_setprio(0);
      }
    }
    bar();   // all waves done reading buf p before next STAGE overwrites it
  }

  // ---- epilogue: O^T -> LDS (swizzled) -> coalesced global store
  char* tb = smem + wid * 8192;  // per-wave 64q x 128B, reuses K buffers
#pragma unroll
  for (int qg = 0; qg < 2; ++qg) {
    const float inv = 1.0f / lacc[qg][0];
    char* trow = tb + qg * 4096 + l31 * 128;
    const int swq = (l31 & 7) << 4;
#pragma unroll
    for (int g2 = 0; g2 < 4; ++g2) {
      uint2 a0, a1;
      a0.x = cvtpk(oaccA[qg][4 * g2] * inv, oaccA[qg][4 * g2 + 1] * inv);
      a0.y = cvtpk(oaccA[qg][4 * g2 + 2] * inv, oaccA[qg][4 * g2 + 3] * inv);
      a1.x = cvtpk(oaccB[qg][4 * g2] * inv, oaccB[qg][4 * g2 + 1] * inv);
      a1.y = cvtpk(oaccB[qg][4 * g2 + 2] * inv, oaccB[qg][4 * g2 + 3] * inv);
      int d0 = 16 * g2 + 8 * hi;
      *(uint2*)(trow + ((d0) ^ swq)) = a0;
      *(uint2*)(trow + ((d0 + 64) ^ swq)) = a1;
    }
  }
#pragma unroll
  for (int half = 0; half < 2; ++half) {
    const int qq = half * 32 + (lane >> 1), cp = lane & 1;
    const char* trow = tb + qq * 128;
    const int swr = (qq & 7) << 4;
    unsigned short* op = ctx + ((size_t)(b * 2048 + q0 + qq)) * 1024 + h * 64 + cp * 32;
#pragma unroll
    for (int i = 0; i < 4; ++i) {
      int col = cp * 64 + i * 16;
      u32x4_t val = *(const u32x4_t*)(trow + (col ^ swr));
      *(u32x4_t*)(op + i * 8) = val;
    }
  }
}

// ---------------------------------------------------------------------------
__global__ __launch_bounds__(256) void ln_kernel(
    float* __restrict__ y, const float* __restrict__ g, const float* __restrict__ be)
{
  const int row = blockIdx.x, tid = threadIdx.x;
  float* rp = y + (size_t)row * 1024;
  float4 x = *(const float4*)(rp + tid * 4);
  float s = x.x + x.y + x.z + x.w;
  float sq = x.x * x.x + x.y * x.y + x.z * x.z + x.w * x.w;
#pragma unroll
  for (int msk = 1; msk < 64; msk <<= 1) {
    s  += __shfl_xor(s, msk);
    sq += __shfl_xor(sq, msk);
  }
  __shared__ float red[8];
  const int wid = tid >> 6, lane = tid & 63;
  if (lane == 0) { red[wid] = s; red[4 + wid] = sq; }
  __syncthreads();
  s  = red[0] + red[1] + red[2] + red[3];
  sq = red[4] + red[5] + red[6] + red[7];
  float mu = s * (1.f / 1024.f);
  float var = sq * (1.f / 1024.f) - mu * mu;
  float rs = rsqrtf(var + 1e-12f);
  float4 gw = *(const float4*)(g + tid * 4);
  float4 bw = *(const float4*)(be + tid * 4);
  float4 o2;
  o2.x = (x.x - mu) * rs * gw.x + bw.x;
  o2.y = (x.y - mu) * rs * gw.y + bw.y;
  o2.z = (x.z - mu) * rs * gw.z + bw.z;
  o2.w = (x.w - mu) * rs * gw.w + bw.w;
  *(float4*)(rp + tid * 4) = o2;
}

// ---------------------------------------------------------------------------
extern "C" void kernel_launch(void* const* d_in, const int* in_sizes, int n_in,
                              void* d_out, int out_size, void* d_ws, size_t ws_size,
                              hipStream_t stream)
{
  const float* x    = (const float*)d_in[0];
  const float* mask = (const float*)d_in[1];
  const float* wq   = (const float*)d_in[2];
  const float* bq   = (const float*)d_in[3];
  const float* wk   = (const float*)d_in[4];
  const float* bk   = (const float*)d_in[5];
  const float* wv   = (const float*)d_in[6];
  const float* bv   = (const float*)d_in[7];
  const float* wo   = (const float*)d_in[8];
  const float* bo   = (const float*)d_in[9];
  const float* lnw  = (const float*)d_in[10];
  const float* lnb  = (const float*)d_in[11];
  float* out = (float*)d_out;

  char* ws = (char*)d_ws;
  unsigned short* Xb  = (unsigned short*)(ws);                               // 16 MB
  unsigned short* Wqb = (unsigned short*)(ws + 16777216);                    // 2 MB
  unsigned short* Wkb = (unsigned short*)(ws + 16777216 + 2097152);
  unsigned short* Wvb = (unsigned short*)(ws + 16777216 + 2 * 2097152);
  unsigned short* Wob = (unsigned short*)(ws + 16777216 + 3 * 2097152);
  unsigned short* Qg  = (unsigned short*)(ws + 25165824);                    // [B,H,S,D]
  unsigned short* Kg  = (unsigned short*)(ws + 25165824 + 16777216);         // [B,H,S,D]
  unsigned short* Vtg = (unsigned short*)(ws + 25165824 + 2 * 16777216);     // [B,H,D,S]
  unsigned short* CTX = (unsigned short*)(ws + 25165824 + 3 * 16777216);     // [B,S,E]
  float*          EMf = (float*)(ws + 92274688);                             // 32 KB
  unsigned short* EMb = (unsigned short*)(ws + 92274688 + 32768);            // 16 KB

  cast_all<<<dim3(6148), 256, 0, stream>>>(x, wq, wk, wv, wo, mask,
                                           Xb, Wqb, Wkb, Wvb, Wob, EMf, EMb);
  gemm_bt<0><<<dim3(64, 8, 2), 256, 0, stream>>>(Xb, Wqb, Wkb, bq, bk, nullptr,
                                                 Qg, Kg, nullptr, 8192, 1024, 1024);
  gemm_bt<2><<<dim3(8, 64, 1), 256, 0, stream>>>(Wvb, Xb, nullptr, bv, nullptr, EMf,
                                                 Vtg, nullptr, nullptr, 1024, 8192, 1024);
  attn_kernel<<<dim3(512), 256, 0, stream>>>(Qg, Kg, Vtg, EMb, CTX);
  gemm_bt<3><<<dim3(64, 8, 1), 256, 0, stream>>>(CTX, Wob, nullptr, bo, nullptr, x,
                                                 nullptr, nullptr, out, 8192, 1024, 1024);
  ln_kernel<<<dim3(8192), 256, 0, stream>>>(out, lnw, lnb);
}

// Round 10
// 201.607 us; speedup vs baseline: 2.4263x; 1.0665x over previous
//
#include <hip/hip_runtime.h>
#include <hip/hip_bf16.h>
#include <stdint.h>

// ---------------------------------------------------------------------------
// MultiHeadSelfAttention fused block, MI355X/gfx950, bf16 MFMA pipeline.
// B=4 S=2048 E=1024 H=16 D=64.
// R9: GEMMs rebuilt as 256x128-tile / BK=64 / 8-wave / 3-LDS-buffer lead-2
// pipeline: stage(t+2) -> vmcnt(6) -> bar -> 32 MFMA -> bar. One full
// iteration (~1000 cyc) between issue and use hides HBM latency; vmcnt
// never drains in the main loop (the 2-phase structural stall removed).
// Race-free by construction: staged buffer's last readers completed before
// the previous trailing barrier. Attn/cast/LN untouched.
// ---------------------------------------------------------------------------

typedef short bf16x8_t __attribute__((ext_vector_type(8)));
typedef float f32x4_t __attribute__((ext_vector_type(4)));
typedef float f32x16_t __attribute__((ext_vector_type(16)));
typedef unsigned short u16x8_t __attribute__((ext_vector_type(8)));
typedef uint32_t u32x4_t __attribute__((ext_vector_type(4)));

#define DEV static __device__ __forceinline__

DEV unsigned short f2bf(float f) {  // RNE f32->bf16
  union { float f; uint32_t u; } v; v.f = f;
  uint32_t u = v.u;
  return (unsigned short)((u + 0x7fffu + ((u >> 16) & 1u)) >> 16);
}

DEV uint32_t cvtpk(float a, float b) {  // packed {lo=a, hi=b} bf16, RNE
  uint32_t d;
  asm("v_cvt_pk_bf16_f32 %0, %1, %2" : "=v"(d) : "v"(a), "v"(b));
  return d;
}

// swap: a <- {a.lo_lanes, b.lo_lanes}, b <- {a.hi_lanes, b.hi_lanes}
DEV void plswap(uint32_t& a, uint32_t& b) {
  asm("v_permlane32_swap_b32 %0, %1" : "+v"(a), "+v"(b));
}

DEV float ex2(float x) { return __builtin_amdgcn_exp2f(x); }

template<int N> DEV void wait_vm() {  // counted vmem wait (T4)
  asm volatile("s_waitcnt vmcnt(%0)" :: "n"(N) : "memory");
}
DEV void bar() { __builtin_amdgcn_s_barrier(); }
DEV void sbar0() { __builtin_amdgcn_sched_barrier(0); }

typedef const __attribute__((address_space(1))) void* gp_t;
typedef __attribute__((address_space(3))) void* lp_t;

DEV void gld16(const void* g, void* l) {  // async global->LDS, 16B/lane
  __builtin_amdgcn_global_load_lds((gp_t)g, (lp_t)l, 16, 0, 0);
}

// ---------------------------------------------------------------------------
// Flat exact grid: X 4096 | Wq 512 | Wk 512 | Wv 512 | Wo 512 | mask 4 = 6148
__global__ __launch_bounds__(256) void cast_all(
    const float* __restrict__ x,
    const float* __restrict__ wq, const float* __restrict__ wk,
    const float* __restrict__ wv, const float* __restrict__ wo,
    const float* __restrict__ mask,
    unsigned short* __restrict__ xb,
    unsigned short* __restrict__ wqb, unsigned short* __restrict__ wkb,
    unsigned short* __restrict__ wvb, unsigned short* __restrict__ wob,
    float* __restrict__ emf, unsigned short* __restrict__ emb)
{
  const int cid = blockIdx.x;
  if (cid >= 6144) {  // EM = exp(mask): f32 (Vt fold) + bf16 (l-MFMA A-op)
    int i = ((cid - 6144) * 256 + (int)threadIdx.x) * 8;
    float4 a = *(const float4*)(mask + i);
    float4 b = *(const float4*)(mask + i + 4);
    const float C = 1.44269504f;
    float4 ea, eb;
    ea.x = ex2(a.x * C); ea.y = ex2(a.y * C); ea.z = ex2(a.z * C); ea.w = ex2(a.w * C);
    eb.x = ex2(b.x * C); eb.y = ex2(b.y * C); eb.z = ex2(b.z * C); eb.w = ex2(b.w * C);
    *(float4*)(emf + i) = ea;
    *(float4*)(emf + i + 4) = eb;
    u16x8_t o;
    o[0] = f2bf(ea.x); o[1] = f2bf(ea.y); o[2] = f2bf(ea.z); o[3] = f2bf(ea.w);
    o[4] = f2bf(eb.x); o[5] = f2bf(eb.y); o[6] = f2bf(eb.z); o[7] = f2bf(eb.w);
    *(u16x8_t*)(emb + i) = o;
    return;
  }
  const float* src; unsigned short* dst; int base;
  if (cid < 4096)      { src = x;  dst = xb;  base = cid; }
  else if (cid < 4608) { src = wq; dst = wqb; base = cid - 4096; }
  else if (cid < 5120) { src = wk; dst = wkb; base = cid - 4608; }
  else if (cid < 5632) { src = wv; dst = wvb; base = cid - 5120; }
  else                 { src = wo; dst = wob; base = cid - 5632; }
  int i = (base * 256 + (int)threadIdx.x) * 8;
  float4 a = *(const float4*)(src + i);
  float4 b = *(const float4*)(src + i + 4);
  u16x8_t o;
  o[0] = f2bf(a.x); o[1] = f2bf(a.y); o[2] = f2bf(a.z); o[3] = f2bf(a.w);
  o[4] = f2bf(b.x); o[5] = f2bf(b.y); o[6] = f2bf(b.z); o[7] = f2bf(b.w);
  *(u16x8_t*)(dst + i) = o;
}

// ---------------------------------------------------------------------------
// C[m,n] = sum_k A[m,k]*B[n,k]. 256x128 tile, BK=64, 8 waves (2M x 4N),
// 3-buffer lead-2 counted-vmcnt pipeline, XOR-swizzled LDS (rule-21 both-
// sides: pre-swizzled global source + linear gld16 dest + swizzled reads).
// Per wave: 128x32 output = 8 Mfrags x 2 Nfrags of 16x16.
// MODE 0: QK proj (z=0: Q scaled log2e/8; z=1: K), out bf16 [B,H,S,D]
// MODE 2: Vt (A=Wv rows e, B=X rows (b,s)), out bf16 [B,H,D,S] * EM (resid=EMf)
// MODE 3: WO + bias + residual, out f32 [M,N]
template<int MODE>
__global__ __launch_bounds__(512, 2) void gemm_bt(
    const unsigned short* __restrict__ A,
    const unsigned short* __restrict__ B0, const unsigned short* __restrict__ B1,
    const float* __restrict__ bias0, const float* __restrict__ bias1,
    const float* __restrict__ resid,
    unsigned short* __restrict__ o0, unsigned short* __restrict__ o1,
    float* __restrict__ of,
    int M, int N, int K)
{
  // A[3][32768] | B[3][16384] @ 98304 ; total 147456 B
  __shared__ __align__(16) char smem[147456];

  const int z = blockIdx.z;
  const unsigned short* Bw = (MODE == 0 && z == 1) ? B1 : B0;
  const float* bias = (MODE == 0 && z == 1) ? bias1 : bias0;
  unsigned short* obf = (MODE == 0 && z == 1) ? o1 : o0;

  const int tid = threadIdx.x;
  const int lane = tid & 63;
  const int lr = lane & 15, lq = lane >> 4;
  const int wid = tid >> 6;            // 0..7
  const int wm = wid >> 2, wn = wid & 3;
  const int m0 = blockIdx.x * 256;
  const int n0 = blockIdx.y * 128;

  f32x4_t acc[8][2] = {};

  // stage K-tile kt (elements kt*64 .. +64) into buffer p
  auto STAGE = [&](int kt, int p) {
    char* ad = smem + p * 32768;
    char* bd = smem + 98304 + p * 16384;
    const int ke = kt * 64;
#pragma unroll
    for (int l = 0; l < 4; ++l) {      // A: 256 rows x 128 B
      int oo = tid * 16 + l * 8192;
      int row = oo >> 7, cb = oo & 127;
      int scb = cb ^ ((row & 7) << 4); // inverse swizzle on global source
      gld16((const char*)(A + (size_t)(m0 + row) * K + ke) + scb, ad + oo);
    }
#pragma unroll
    for (int l = 0; l < 2; ++l) {      // B: 128 rows x 128 B
      int oo = tid * 16 + l * 8192;
      int row = oo >> 7, cb = oo & 127;
      int scb = cb ^ ((row & 7) << 4);
      gld16((const char*)(Bw + (size_t)(n0 + row) * K + ke) + scb, bd + oo);
    }
  };

  const int NT = K >> 6;               // 16 for K=1024
  STAGE(0, 0);
  STAGE(1, 1);
  wait_vm<6>();                        // 12 in flight -> tile 0 landed
  bar(); sbar0();

  for (int t = 0; t < NT; ++t) {
    const int p = t % 3;
    if (t + 2 < NT) { STAGE(t + 2, (t + 2) % 3); wait_vm<6>(); }
    else if (t == NT - 1) { wait_vm<0>(); }
    else { wait_vm<6>(); }
    bar(); sbar0();

    const char* ab = smem + p * 32768;
    const char* bb = smem + 98304 + p * 16384;
#pragma unroll
    for (int ks = 0; ks < 2; ++ks) {
      bf16x8_t aF[8], bF[2];
#pragma unroll
      for (int i = 0; i < 8; ++i) {
        int row = wm * 128 + i * 16 + lr;
        int cc = (ks * 64 + lq * 16) ^ ((row & 7) << 4);
        aF[i] = *(const bf16x8_t*)(ab + row * 128 + cc);
      }
#pragma unroll
      for (int j = 0; j < 2; ++j) {
        int row = wn * 32 + j * 16 + lr;
        int cc = (ks * 64 + lq * 16) ^ ((row & 7) << 4);
        bF[j] = *(const bf16x8_t*)(bb + row * 128 + cc);
      }
#pragma unroll
      for (int i = 0; i < 8; ++i)
#pragma unroll
        for (int j = 0; j < 2; ++j)
          acc[i][j] = __builtin_amdgcn_mfma_f32_16x16x32_bf16(aF[i], bF[j], acc[i][j], 0, 0, 0);
    }
    bar();   // all waves done reading buf p before iter t+1 stages into it
  }

#pragma unroll
  for (int i = 0; i < 8; ++i) {
#pragma unroll
    for (int j = 0; j < 2; ++j) {
      int n = n0 + wn * 32 + j * 16 + lr;
#pragma unroll
      for (int r = 0; r < 4; ++r) {
        int m = m0 + wm * 128 + i * 16 + lq * 4 + r;
        float v = acc[i][j][r];
        if (MODE == 0) {
          // z=0 (Q): fold 1/sqrt(64) AND log2e so QK^T lands in log2 domain
          v = (v + bias[n]) * (z == 0 ? 0.18033688f : 1.0f);
          int b = m >> 11, s = m & 2047, h = n >> 6, d = n & 63;
          obf[(size_t)((b * 16 + h) * 2048 + s) * 64 + d] = f2bf(v);
        } else if (MODE == 2) {
          v = (v + bias[m]) * resid[n];  // resid = EMf, n = b*2048+s
          int b = n >> 11, s = n & 2047;
          obf[(size_t)(b * 1024 + m) * 2048 + s] = f2bf(v);
        } else {
          v = v + bias[n] + resid[(size_t)m * 1024 + n];
          of[(size_t)m * 1024 + n] = v;
        }
      }
    }
  }
}

// ---------------------------------------------------------------------------
// Flash attention, swapped-QK^T 32x32, max-free softmax, QBLK=256, KBLK=128.
// Grid 512, 256 threads (4 waves), wave owns 64 q (2 q-groups of 32).
// Counted-vmcnt pipeline; EM row (4KB) staged once in prologue.
__global__ __launch_bounds__(256, 2) void attn_kernel(
    const unsigned short* __restrict__ Qg, const unsigned short* __restrict__ Kg,
    const unsigned short* __restrict__ Vtg, const unsigned short* __restrict__ EMb,
    unsigned short* __restrict__ ctx)
{
  // smem: K[2][16384] | V[2][16384] | E[4096]; epilogue reuses 0..32K
  __shared__ __align__(16) char smem[69632];

  const int id = blockIdx.x;
  const int swz = (id & 7) * 64 + (id >> 3);  // bijective XCD swizzle (512/8)
  const int bh = swz >> 3, qt = swz & 7;
  const int b = bh >> 4, h = bh & 15;

  const int tid = threadIdx.x, lane = tid & 63, wid = tid >> 6;
  const int l31 = lane & 31, hi = lane >> 5;
  const int q0 = qt * 256 + wid * 64;
  const size_t head = (size_t)bh * (2048 * 64);
  const unsigned short* Kh = Kg + head;
  const unsigned short* Vh = Vtg + (size_t)bh * 64 * 2048;
  const unsigned short* emrow = EMb + (size_t)b * 2048;

  // Q B-fragments: col q = q0 + qg*32 + l31, d = ds*16 + 8*hi + j
  bf16x8_t qf[2][4];
#pragma unroll
  for (int qg = 0; qg < 2; ++qg) {
    const unsigned short* qp = Qg + head + (size_t)(q0 + qg * 32 + l31) * 64 + 8 * hi;
#pragma unroll
    for (int ds = 0; ds < 4; ++ds) qf[qg][ds] = *(const bf16x8_t*)(qp + ds * 16);
  }

  f32x16_t oaccA[2] = {}, oaccB[2] = {};  // O^T[d,q]: d 0-31 / 32-63 per qg
  f32x16_t lacc[2] = {};                  // denominators; read [0] at end

  const int sw_row = (l31 & 7) << 4;

  // stage 128-k chunk t into buffer p: exactly 8 gloads/thread (4 K + 4 V)
  auto STAGE = [&](int t, int p) {
    const int k0 = t * 128;
    char* kd = smem + p * 16384;
    char* vd = smem + 32768 + p * 16384;
#pragma unroll
    for (int r = 0; r < 4; ++r) {
      int oo = tid * 16 + r * 4096;
      {  // K: row = k (stride 128B), inverse swizzle on source
        int row = oo >> 7, cb = oo & 127;
        int scb = cb ^ ((row & 7) << 4);
        gld16((const char*)(Kh + (size_t)(k0 + row) * 64) + scb, kd + oo);
      }
      {  // V: row = d (stride 256B), inverse swizzle on source
        int row = oo >> 8, cb = oo & 255;
        int scb = cb ^ ((row & 7) << 4);
        gld16((const char*)(Vh + (size_t)row * 2048 + k0) + scb, vd + oo);
      }
    }
  };

  // prologue: whole EM row (4KB) + tile 0; full drain once
  gld16((const char*)(emrow + tid * 8), smem + 65536 + tid * 16);
  STAGE(0, 0);
  wait_vm<0>();
  bar(); sbar0();

  for (int t = 0; t < 16; ++t) {
    const int p = t & 1;
    if (t < 15) {
      STAGE(t + 1, p ^ 1);   // 8 loads in flight across the barrier
      wait_vm<8>();          // tile t's loads complete
    } else {
      wait_vm<0>();
    }
    bar(); sbar0();

    const char* kb = smem + p * 16384;
    const char* vb = smem + 32768 + p * 16384;
    const char* eb = smem + 65536 + t * 256;

#pragma unroll
    for (int s = 0; s < 2; ++s) {  // two independent 64-k sub-tiles
      // ---- S^T = K . Q^T (log2 domain): c0 = k 0-31, c1 = k 32-63, per qg
      f32x16_t c0[2] = {}, c1[2] = {};
      {
        const char* kr0 = kb + s * 8192 + l31 * 128;
        const char* kr1 = kb + s * 8192 + (32 + l31) * 128;
        __builtin_amdgcn_s_setprio(1);
#pragma unroll
        for (int ds = 0; ds < 4; ++ds) {
          int cc = (ds * 32 + 16 * hi) ^ sw_row;
          bf16x8_t k0f = *(const bf16x8_t*)(kr0 + cc);
          bf16x8_t k1f = *(const bf16x8_t*)(kr1 + cc);
#pragma unroll
          for (int qg = 0; qg < 2; ++qg) {
            c0[qg] = __builtin_amdgcn_mfma_f32_32x32x16_bf16(k0f, qf[qg][ds], c0[qg], 0, 0, 0);
            c1[qg] = __builtin_amdgcn_mfma_f32_32x32x16_bf16(k1f, qf[qg][ds], c1[qg], 0, 0, 0);
          }
        }
        __builtin_amdgcn_s_setprio(0);
      }

      // ---- P = exp2(c) raw (max-free), pack bf16, permlane partner exchange
      bf16x8_t pf[2][4];
#pragma unroll
      for (int qg = 0; qg < 2; ++qg) {
        uint32_t w0[8], w1[8];
#pragma unroll
        for (int g = 0; g < 8; ++g) {
          const int i4 = (g & 3) * 4;
          if (g < 4) {
            w0[g] = cvtpk(ex2(c0[qg][i4]), ex2(c0[qg][i4 + 1]));
            w1[g] = cvtpk(ex2(c0[qg][i4 + 2]), ex2(c0[qg][i4 + 3]));
          } else {
            w0[g] = cvtpk(ex2(c1[qg][i4]), ex2(c1[qg][i4 + 1]));
            w1[g] = cvtpk(ex2(c1[qg][i4 + 2]), ex2(c1[qg][i4 + 3]));
          }
        }
#pragma unroll
        for (int ks = 0; ks < 4; ++ks) {
          const int gg = ((ks >> 1) << 2) + ((ks & 1) << 1);
          uint32_t a0 = w0[gg], b0 = w0[gg + 1];
          uint32_t a1 = w1[gg], b1 = w1[gg + 1];
          plswap(a0, b0);
          plswap(a1, b1);
          union { uint32_t u[4]; bf16x8_t v; } cv;
          cv.u[0] = a0; cv.u[1] = a1; cv.u[2] = b0; cv.u[3] = b1;
          pf[qg][ks] = cv.v;
        }
      }

      // ---- PV (O^T += Vt.P^T) and l (lacc += EM.P^T), frags shared across qg
      {
        const char* vr0 = vb + l31 * 256 + s * 128;
        const char* vr1 = vb + (32 + l31) * 256 + s * 128;
        const char* ebs = eb + s * 128;
        __builtin_amdgcn_s_setprio(1);
#pragma unroll
        for (int ks = 0; ks < 4; ++ks) {
          bf16x8_t ef = *(const bf16x8_t*)(ebs + ks * 32 + 16 * hi);
          int cc = (ks * 32 + 16 * hi) ^ sw_row;
          bf16x8_t v0f = *(const bf16x8_t*)(vr0 + cc);
          bf16x8_t v1f = *(const bf16x8_t*)(vr1 + cc);
#pragma unroll
          for (int qg = 0; qg < 2; ++qg) {
            oaccA[qg] = __builtin_amdgcn_mfma_f32_32x32x16_bf16(v0f, pf[qg][ks], oaccA[qg], 0, 0, 0);
            oaccB[qg] = __builtin_amdgcn_mfma_f32_32x32x16_bf16(v1f, pf[qg][ks], oaccB[qg], 0, 0, 0);
            lacc[qg]  = __builtin_amdgcn_mfma_f32_32x32x16_bf16(ef,  pf[qg][ks], lacc[qg],  0, 0, 0);
          }
        }
        __builtin_amdgcn_s_setprio(0);
      }
    }
    bar();   // all waves done reading buf p before next STAGE overwrites it
  }

  // ---- epilogue: O^T -> LDS (swizzled) -> coalesced global store
  char* tb = smem + wid * 8192;  // per-wave 64q x 128B, reuses K buffers
#pragma unroll
  for (int qg = 0; qg < 2; ++qg) {
    const float inv = 1.0f / lacc[qg][0];
    char* trow = tb + qg * 4096 + l31 * 128;
    const int swq = (l31 & 7) << 4;
#pragma unroll
    for (int g2 = 0; g2 < 4; ++g2) {
      uint2 a0, a1;
      a0.x = cvtpk(oaccA[qg][4 * g2] * inv, oaccA[qg][4 * g2 + 1] * inv);
      a0.y = cvtpk(oaccA[qg][4 * g2 + 2] * inv, oaccA[qg][4 * g2 + 3] * inv);
      a1.x = cvtpk(oaccB[qg][4 * g2] * inv, oaccB[qg][4 * g2 + 1] * inv);
      a1.y = cvtpk(oaccB[qg][4 * g2 + 2] * inv, oaccB[qg][4 * g2 + 3] * inv);
      int d0 = 16 * g2 + 8 * hi;
      *(uint2*)(trow + ((d0) ^ swq)) = a0;
      *(uint2*)(trow + ((d0 + 64) ^ swq)) = a1;
    }
  }
#pragma unroll
  for (int half = 0; half < 2; ++half) {
    const int qq = half * 32 + (lane >> 1), cp = lane & 1;
    const char* trow = tb + qq * 128;
    const int swr = (qq & 7) << 4;
    unsigned short* op = ctx + ((size_t)(b * 2048 + q0 + qq)) * 1024 + h * 64 + cp * 32;
#pragma unroll
    for (int i = 0; i < 4; ++i) {
      int col = cp * 64 + i * 16;
      u32x4_t val = *(const u32x4_t*)(trow + (col ^ swr));
      *(u32x4_t*)(op + i * 8) = val;
    }
  }
}

// ---------------------------------------------------------------------------
__global__ __launch_bounds__(256) void ln_kernel(
    float* __restrict__ y, const float* __restrict__ g, const float* __restrict__ be)
{
  const int row = blockIdx.x, tid = threadIdx.x;
  float* rp = y + (size_t)row * 1024;
  float4 x = *(const float4*)(rp + tid * 4);
  float s = x.x + x.y + x.z + x.w;
  float sq = x.x * x.x + x.y * x.y + x.z * x.z + x.w * x.w;
#pragma unroll
  for (int msk = 1; msk < 64; msk <<= 1) {
    s  += __shfl_xor(s, msk);
    sq += __shfl_xor(sq, msk);
  }
  __shared__ float red[8];
  const int wid = tid >> 6, lane = tid & 63;
  if (lane == 0) { red[wid] = s; red[4 + wid] = sq; }
  __syncthreads();
  s  = red[0] + red[1] + red[2] + red[3];
  sq = red[4] + red[5] + red[6] + red[7];
  float mu = s * (1.f / 1024.f);
  float var = sq * (1.f / 1024.f) - mu * mu;
  float rs = rsqrtf(var + 1e-12f);
  float4 gw = *(const float4*)(g + tid * 4);
  float4 bw = *(const float4*)(be + tid * 4);
  float4 o2;
  o2.x = (x.x - mu) * rs * gw.x + bw.x;
  o2.y = (x.y - mu) * rs * gw.y + bw.y;
  o2.z = (x.z - mu) * rs * gw.z + bw.z;
  o2.w = (x.w - mu) * rs * gw.w + bw.w;
  *(float4*)(rp + tid * 4) = o2;
}

// ---------------------------------------------------------------------------
extern "C" void kernel_launch(void* const* d_in, const int* in_sizes, int n_in,
                              void* d_out, int out_size, void* d_ws, size_t ws_size,
                              hipStream_t stream)
{
  const float* x    = (const float*)d_in[0];
  const float* mask = (const float*)d_in[1];
  const float* wq   = (const float*)d_in[2];
  const float* bq   = (const float*)d_in[3];
  const float* wk   = (const float*)d_in[4];
  const float* bk   = (const float*)d_in[5];
  const float* wv   = (const float*)d_in[6];
  const float* bv   = (const float*)d_in[7];
  const float* wo   = (const float*)d_in[8];
  const float* bo   = (const float*)d_in[9];
  const float* lnw  = (const float*)d_in[10];
  const float* lnb  = (const float*)d_in[11];
  float* out = (float*)d_out;

  char* ws = (char*)d_ws;
  unsigned short* Xb  = (unsigned short*)(ws);                               // 16 MB
  unsigned short* Wqb = (unsigned short*)(ws + 16777216);                    // 2 MB
  unsigned short* Wkb = (unsigned short*)(ws + 16777216 + 2097152);
  unsigned short* Wvb = (unsigned short*)(ws + 16777216 + 2 * 2097152);
  unsigned short* Wob = (unsigned short*)(ws + 16777216 + 3 * 2097152);
  unsigned short* Qg  = (unsigned short*)(ws + 25165824);                    // [B,H,S,D]
  unsigned short* Kg  = (unsigned short*)(ws + 25165824 + 16777216);         // [B,H,S,D]
  unsigned short* Vtg = (unsigned short*)(ws + 25165824 + 2 * 16777216);     // [B,H,D,S]
  unsigned short* CTX = (unsigned short*)(ws + 25165824 + 3 * 16777216);     // [B,S,E]
  float*          EMf = (float*)(ws + 92274688);                             // 32 KB
  unsigned short* EMb = (unsigned short*)(ws + 92274688 + 32768);            // 16 KB

  cast_all<<<dim3(6148), 256, 0, stream>>>(x, wq, wk, wv, wo, mask,
                                           Xb, Wqb, Wkb, Wvb, Wob, EMf, EMb);
  gemm_bt<0><<<dim3(32, 8, 2), 512, 0, stream>>>(Xb, Wqb, Wkb, bq, bk, nullptr,
                                                 Qg, Kg, nullptr, 8192, 1024, 1024);
  gemm_bt<2><<<dim3(4, 64, 1), 512, 0, stream>>>(Wvb, Xb, nullptr, bv, nullptr, EMf,
                                                 Vtg, nullptr, nullptr, 1024, 8192, 1024);
  attn_kernel<<<dim3(512), 256, 0, stream>>>(Qg, Kg, Vtg, EMb, CTX);
  gemm_bt<3><<<dim3(32, 8, 1), 512, 0, stream>>>(CTX, Wob, nullptr, bo, nullptr, x,
                                                 nullptr, nullptr, out, 8192, 1024, 1024);
  ln_kernel<<<dim3(8192), 256, 0, stream>>>(out, lnw, lnb);
}